// Round 3
// baseline (243.649 us; speedup 1.0000x reference)
//
#include <hip/hip_runtime.h>
#include <math.h>

typedef unsigned short ushort_t;
typedef __attribute__((ext_vector_type(8))) short short8v;
typedef __attribute__((ext_vector_type(4))) float f32x4;

#define KCOMP 128
#define DF    1024
#define LF    16
#define NPTS  16384
#define LOG2PI 1.8378770664093453f

// ---------------- full-path ws layout (bytes) ----------------
#define XBF_OFF   ((size_t)0)
#define XBF_BYTES ((size_t)NPTS*DF*2)            // 33,554,432
#define BG_OFF    (XBF_OFF + XBF_BYTES)
#define BG_BYTES  ((size_t)2048*DF*2)            // 4,194,304
#define BSK_OFF   (BG_OFF + BG_BYTES)
#define BSK_BYTES ((size_t)KCOMP*2*DF*2)         // 524,288
#define PACK_OFF  (BSK_OFF + BSK_BYTES)
#define PACK_BYTES ((size_t)KCOMP*288*4)         // 147,456
#define CSK_OFF   (PACK_OFF + PACK_BYTES)
#define FULL_NEED (CSK_OFF + 512)

__device__ __forceinline__ ushort_t f2bf(float f) {
  union { float f; unsigned u; } v; v.f = f;
  unsigned u = v.u;
  return (ushort_t)((u + 0x7FFFu + ((u >> 16) & 1u)) >> 16);
}
__device__ __forceinline__ float bf2f(ushort_t h) {
  union { unsigned u; float f; } v; v.u = ((unsigned)h) << 16;
  return v.f;
}

#define GLOAD16(gp, lp) __builtin_amdgcn_global_load_lds( \
  (const __attribute__((address_space(1))) unsigned int*)(gp), \
  (__attribute__((address_space(3))) unsigned int*)(lp), 16, 0, 0)

// ---------------------------------------------------------------------------
// xconv: x fp32 -> xbf bf16 (plain row-major)
// ---------------------------------------------------------------------------
__global__ __launch_bounds__(256) void mfa_xconv(
    const float* __restrict__ x, ushort_t* __restrict__ xbf)
{
  int i = blockIdx.x * 256 + threadIdx.x;   // group of 8 elems
  const float4 v0 = ((const float4*)x)[(size_t)i*2];
  const float4 v1 = ((const float4*)x)[(size_t)i*2 + 1];
  float e[8] = {v0.x,v0.y,v0.z,v0.w,v1.x,v1.y,v1.z,v1.w};
  short8v o;
  #pragma unroll
  for (int j = 0; j < 8; ++j) o[j] = (short)f2bf(e[j]);
  *(short8v*)&xbf[(size_t)i*8] = o;
}

// ---------------------------------------------------------------------------
// pre1: per-k Lm = I + A^T iD A ; chol ; z ; csk = cst - 0.5*muh ; pack R/rinv/z
// ---------------------------------------------------------------------------
__global__ __launch_bounds__(256) void mfa_pre1(
    const float* __restrict__ PI, const float* __restrict__ MU,
    const float* __restrict__ A, const float* __restrict__ Dm,
    float* __restrict__ pack, float* __restrict__ csk)
{
  const int k = blockIdx.x, t = threadIdx.x;
  const int tl = t >> 4, tm = t & 15;
  __shared__ float As[64][16];
  __shared__ float iD64[64], MU64[64];
  __shared__ float R[16][17];
  __shared__ float rinv_s[16], zsh[16], bsh[16];
  __shared__ float red[64];
  __shared__ float sc_sumlog, sc_c3;

  float accL = 0.f, accb = 0.f, c3p = 0.f, slogp = 0.f;
  for (int ch = 0; ch < 16; ++ch) {
    __syncthreads();
    ((float4*)&As[0][0])[t] =
        ((const float4*)(A + (size_t)k*DF*LF + (size_t)ch*1024))[t];
    if (t < 64) {
      float dv = Dm[k*DF + ch*64 + t];
      iD64[t] = 1.f/(dv*dv);
      MU64[t] = MU[k*DF + ch*64 + t];
    }
    __syncthreads();
    #pragma unroll 4
    for (int dd = 0; dd < 64; ++dd)
      accL = fmaf(As[dd][tl]*iD64[dd], As[dd][tm], accL);
    if (tm == 0)
      for (int dd = 0; dd < 64; ++dd)
        accb = fmaf(iD64[dd]*MU64[dd], As[dd][tl], accb);
    if (t < 64) {
      c3p = fmaf(iD64[t]*MU64[t], MU64[t], c3p);
      slogp += logf(iD64[t]);
    }
  }
  __syncthreads();
  R[tl][tm] = accL + (tl == tm ? 1.f : 0.f);
  if (tm == 0) bsh[tl] = accb;
  if (t < 64) red[t] = slogp;
  __syncthreads();
  if (t == 0) { float s = 0.f; for (int i = 0; i < 64; ++i) s += red[i]; sc_sumlog = s; }
  __syncthreads();
  if (t < 64) red[t] = c3p;
  __syncthreads();
  if (t == 0) { float s = 0.f; for (int i = 0; i < 64; ++i) s += red[i]; sc_c3 = s; }

  // Cholesky (lower), diag-dominant SPD
  for (int j = 0; j < 16; ++j) {
    __syncthreads();
    if (t == j) {
      float s = R[j][j];
      for (int i = 0; i < j; ++i) s -= R[j][i]*R[j][i];
      float rj = sqrtf(s);
      R[j][j] = rj; rinv_s[j] = 1.f/rj;
    }
    __syncthreads();
    if (t < 16 && t > j) {
      float s = R[t][j];
      for (int i = 0; i < j; ++i) s -= R[t][i]*R[j][i];
      R[t][j] = s * rinv_s[j];
    }
  }
  __syncthreads();
  if (t == 0) {
    float ldet = 0.f;
    for (int j = 0; j < 16; ++j) ldet += 2.f*logf(R[j][j]);
    float w[16], z[16];
    for (int j = 0; j < 16; ++j) {
      float s = bsh[j];
      for (int i = 0; i < j; ++i) s -= R[j][i]*w[i];
      w[j] = s*rinv_s[j];
    }
    for (int j = 15; j >= 0; --j) {
      float s = w[j];
      for (int i = j+1; i < 16; ++i) s -= R[i][j]*z[i];
      z[j] = s*rinv_s[j];
      zsh[j] = z[j];
    }
    float muh = sc_c3;
    for (int l = 0; l < 16; ++l) muh -= bsh[l]*zsh[l];
    csk[k] = PI[k] - 0.5f*((float)DF*LOG2PI + ldet - sc_sumlog) - 0.5f*muh;
  }
  __syncthreads();
  pack[(size_t)k*288 + t] = R[tl][tm];
  if (t < 16) {
    pack[(size_t)k*288 + 256 + t] = rinv_s[t];
    pack[(size_t)k*288 + 272 + t] = zsh[t];
  }
}

// ---------------------------------------------------------------------------
// pre2: G = iDA L^{-T}, h = iD*mu - iDA z ; write Bg (bf16) and Bsk [-2h; iD]
// ---------------------------------------------------------------------------
__global__ __launch_bounds__(256) void mfa_pre2(
    const float* __restrict__ MU, const float* __restrict__ A,
    const float* __restrict__ Dm, const float* __restrict__ pack,
    ushort_t* __restrict__ Bg, ushort_t* __restrict__ Bsk)
{
  const int k = blockIdx.x >> 2;
  const int t = threadIdx.x;
  const int d = (blockIdx.x & 3) * 256 + t;
  __shared__ float Rl[16][16], ri[16], zl[16];
  ((float*)Rl)[t] = pack[(size_t)k*288 + t];
  if (t < 16) { ri[t] = pack[(size_t)k*288+256+t]; zl[t] = pack[(size_t)k*288+272+t]; }
  __syncthreads();
  float dv = Dm[k*DF + d];
  float iD = 1.f/(dv*dv);
  float mu = MU[k*DF + d];
  float v[16], gg[16];
  #pragma unroll
  for (int l = 0; l < 16; ++l) v[l] = iD * A[((size_t)k*DF + d)*LF + l];
  #pragma unroll
  for (int j = 0; j < 16; ++j) {
    float s = v[j];
    #pragma unroll
    for (int i = 0; i < 16; ++i) if (i < j) s -= Rl[j][i]*gg[i];
    gg[j] = s * ri[j];
  }
  float h = iD*mu;
  #pragma unroll
  for (int l = 0; l < 16; ++l) h -= v[l]*zl[l];
  #pragma unroll
  for (int l = 0; l < 16; ++l)
    Bg[(size_t)(k*16 + l)*DF + d] = f2bf(gg[l]);
  Bsk[(size_t)k*2*DF + d]      = f2bf(-2.f*h);
  Bsk[(size_t)k*2*DF + DF + d] = f2bf(iD);
}

// ---------------------------------------------------------------------------
// sk: out[n,c] = csk[c] - 0.5 * ( [x|x^2] . Bsk[c] )    (16384 x 128, K=2048)
// block = 64 rows x 128 cols, 4 waves (2r x 2c), wave 32x64 = 2x4 16x16 tiles
// ---------------------------------------------------------------------------
__global__ __launch_bounds__(256, 4) void mfa_sk(
    const ushort_t* __restrict__ xbf, const ushort_t* __restrict__ Bsk,
    const float* __restrict__ csk, float* __restrict__ out)
{
  __shared__ ushort_t smem[6144];   // xs 2048 + bs 4096 ushorts
  const int t = threadIdx.x;
  const int lane = t & 63, wid = t >> 6;
  const int wr = wid & 1, wc = wid >> 1;
  const int lr = lane & 15, lh = lane >> 4;
  const int n0 = blockIdx.x * 64;
  const int sq_ = lane >> 2, sc_ = lane & 3;

  f32x4 acc[2][4] = {};
  const int xsw = (lh ^ (lr & 3)) * 8;
  const int a_base = (wr*32 + lr)*32 + xsw;
  const int b_base = 2048 + (wc*64 + lr)*32 + xsw;

  for (int it = 0; it < 64; ++it) {
    const int d0 = it * 32;
    __syncthreads();
    if (d0 < 1024) {
      int r = wid * 16 + sq_;
      const ushort_t* g = xbf + (size_t)(n0 + r)*DF + d0 + ((sc_ ^ (r & 3)) * 8);
      GLOAD16(g, smem + wid * 512);
    } else {
      int row = t >> 2, ch = t & 3;
      const short8v xv = *(const short8v*)&xbf[(size_t)(n0 + row)*DF + (d0 - 1024) + ch*8];
      short8v qv;
      #pragma unroll
      for (int i = 0; i < 8; ++i) {
        float f = bf2f((ushort_t)xv[i]);
        qv[i] = (short)f2bf(f * f);
      }
      *(short8v*)&smem[row*32 + ((ch ^ (row & 3)) * 8)] = qv;
    }
    #pragma unroll
    for (int i = 0; i < 2; ++i) {
      int id = wid * 2 + i;
      int c = id * 16 + sq_;
      const ushort_t* g = Bsk + (size_t)c*(2*DF) + d0 + ((sc_ ^ (c & 3)) * 8);
      GLOAD16(g, smem + 2048 + id * 512);
    }
    __syncthreads();
    short8v a[2], b[4];
    #pragma unroll
    for (int rt = 0; rt < 2; ++rt) a[rt] = *(const short8v*)&smem[a_base + rt*512];
    #pragma unroll
    for (int ct = 0; ct < 4; ++ct) b[ct] = *(const short8v*)&smem[b_base + ct*512];
    #pragma unroll
    for (int ct = 0; ct < 4; ++ct)
      #pragma unroll
      for (int rt = 0; rt < 2; ++rt)
        acc[rt][ct] = __builtin_amdgcn_mfma_f32_16x16x32_bf16(a[rt], b[ct], acc[rt][ct], 0, 0, 0);
  }

  #pragma unroll
  for (int ct = 0; ct < 4; ++ct) {
    const int comp = wc*64 + ct*16 + lr;
    const float ck = csk[comp];
    #pragma unroll
    for (int rt = 0; rt < 2; ++rt)
      #pragma unroll
      for (int j = 0; j < 4; ++j) {
        int row = wr*32 + rt*16 + lh*4 + j;
        out[(size_t)(n0 + row)*KCOMP + comp] = ck - 0.5f*acc[rt][ct][j];
      }
  }
}

// ---------------------------------------------------------------------------
// main GEMM: out[n,comp] += 0.5 * sum_l (x . G_l)^2   (16384 x 2048 x 1024)
// block = 256 rows x 128 cols, 4 waves (2r x 2c), wave 128x64 = 8x4 tiles.
// Double-buffered global_load_lds, XOR-swizzled source + swizzled ds_read.
// ---------------------------------------------------------------------------
__global__ __launch_bounds__(256, 2) void mfa_gemm(
    const ushort_t* __restrict__ xbf, const ushort_t* __restrict__ Bg,
    float* __restrict__ out)
{
  __shared__ ushort_t smem[2*12288];   // per buf: xs 8192 + bs 4096 ushorts
  const int t = threadIdx.x;
  const int lane = t & 63, wid = t >> 6;
  const int wr = wid & 1, wc = wid >> 1;
  const int lr = lane & 15, lh = lane >> 4;
  const int sq_ = lane >> 2, sc_ = lane & 3;

  const int bid = blockIdx.x;
  const int swz = (bid & 7) * 128 + (bid >> 3);   // XCD-bijective (1024 % 8 == 0)
  const int rb = swz >> 4, cb = swz & 15;
  const int n0 = rb * 256, c0 = cb * 128;

  f32x4 acc[8][4] = {};
  const int xsw = (lh ^ (lr & 3)) * 8;
  const int a_base = (wr*128 + lr)*32 + xsw;           // ushort units, +rt*512
  const int b_base = 8192 + (wc*64 + lr)*32 + xsw;     // +ct*512

  // stage 24 x 1KB issues (6 per wave): ids 0..15 -> xs rows, 16..23 -> bs cols
  auto stage = [&](int buf, int it) {
    const int d0 = it * 32;
    ushort_t* lb = smem + buf * 12288;
    #pragma unroll
    for (int i = 0; i < 6; ++i) {
      int id = wid * 6 + i;
      if (id < 16) {
        int r = id * 16 + sq_;
        const ushort_t* g = xbf + (size_t)(n0 + r)*DF + d0 + ((sc_ ^ (r & 3)) * 8);
        GLOAD16(g, lb + id * 512);
      } else {
        int c = (id - 16) * 16 + sq_;
        const ushort_t* g = Bg + (size_t)(c0 + c)*DF + d0 + ((sc_ ^ (c & 3)) * 8);
        GLOAD16(g, lb + 8192 + (id - 16) * 512);
      }
    }
  };

  stage(0, 0);
  __syncthreads();
  int cur = 0;
  for (int it = 0; it < 32; ++it) {
    if (it + 1 < 32) stage(cur ^ 1, it + 1);
    const ushort_t* lb = smem + cur * 12288;
    short8v a[8], b[4];
    #pragma unroll
    for (int rt = 0; rt < 8; ++rt) a[rt] = *(const short8v*)&lb[a_base + rt*512];
    #pragma unroll
    for (int ct = 0; ct < 4; ++ct) b[ct] = *(const short8v*)&lb[b_base + ct*512];
    #pragma unroll
    for (int ct = 0; ct < 4; ++ct)
      #pragma unroll
      for (int rt = 0; rt < 8; ++rt)
        acc[rt][ct] = __builtin_amdgcn_mfma_f32_16x16x32_bf16(a[rt], b[ct], acc[rt][ct], 0, 0, 0);
    __syncthreads();
    cur ^= 1;
  }

  // epilogue: per tile = exactly one component (16 cols)
  #pragma unroll
  for (int ct = 0; ct < 4; ++ct) {
    const int comp = cb*8 + wc*4 + ct;
    #pragma unroll
    for (int rt = 0; rt < 8; ++rt) {
      #pragma unroll
      for (int j = 0; j < 4; ++j) {
        float v = acc[rt][ct][j];
        float sq = v * v;
        sq += __shfl_xor(sq, 1);
        sq += __shfl_xor(sq, 2);
        sq += __shfl_xor(sq, 4);
        sq += __shfl_xor(sq, 8);
        if (lr == 0) {
          int row = n0 + wr*128 + rt*16 + lh*4 + j;
          size_t idx = (size_t)row * KCOMP + comp;
          out[idx] = out[idx] + 0.5f * sq;
        }
      }
    }
  }
}

// ===========================================================================
// Fallback path (round-2 kernels, needs ~4.8 MB ws) — used if ws too small
// ===========================================================================
#define FB_NG 8
#define FB_CG 288
#define FB_BN 128
#define FB_DT 32
#define FB_PITCH 40
#define FB_BMAT_ELEMS ((size_t)(FB_NG*FB_CG)*DF)
#define FB_CST_OFF (FB_BMAT_ELEMS*2)
#define FB_MUH_OFF (FB_CST_OFF + 512)

__global__ __launch_bounds__(256) void fb_pre(
    const float* __restrict__ PI, const float* __restrict__ MU,
    const float* __restrict__ A, const float* __restrict__ Dm,
    ushort_t* __restrict__ Bmat, float* __restrict__ cst, float* __restrict__ muh)
{
  const int k = blockIdx.x, t = threadIdx.x;
  const int tl = t >> 4, tm = t & 15;
  __shared__ float As[16][16], iDsh[16], MUsh[16];
  __shared__ float R[16][17], rinv[16], zsh[16], bsh[16];
  __shared__ float red[256];

  float accL = 0.f, accb = 0.f, slog = 0.f;
  for (int d0 = 0; d0 < DF; d0 += 16) {
    __syncthreads();
    As[tl][tm] = A[((size_t)k*DF + d0 + tl)*LF + tm];
    if (t < 16) {
      float dv = Dm[k*DF + d0 + t];
      iDsh[t] = 1.f/(dv*dv);
      MUsh[t] = MU[k*DF + d0 + t];
    }
    __syncthreads();
    #pragma unroll
    for (int dd = 0; dd < 16; ++dd)
      accL = fmaf(As[dd][tl]*iDsh[dd], As[dd][tm], accL);
    if (tm == 0) {
      #pragma unroll
      for (int dd = 0; dd < 16; ++dd)
        accb = fmaf(iDsh[dd]*MUsh[dd], As[dd][tl], accb);
    }
    if (t < 16) slog += logf(iDsh[t]);
  }
  __syncthreads();
  R[tl][tm] = accL + (tl == tm ? 1.f : 0.f);
  if (tm == 0) bsh[tl] = accb;
  red[t] = (t < 16) ? slog : 0.f;
  __syncthreads();
  float sumlogiD = 0.f;
  if (t == 0) { for (int i = 0; i < 16; ++i) sumlogiD += red[i]; }

  for (int j = 0; j < 16; ++j) {
    if (t == j) {
      float s = R[j][j];
      for (int i = 0; i < j; ++i) s -= R[j][i]*R[j][i];
      float rj = sqrtf(s);
      R[j][j] = rj; rinv[j] = 1.f/rj;
    }
    __syncthreads();
    if (t < 16 && t > j) {
      float s = R[t][j];
      for (int i = 0; i < j; ++i) s -= R[t][i]*R[j][i];
      R[t][j] = s * rinv[j];
    }
    __syncthreads();
  }

  float ldet = 0.f;
  if (t == 0) {
    #pragma unroll
    for (int j = 0; j < 16; ++j) ldet += 2.f*logf(R[j][j]);
    float w[16], z[16];
    #pragma unroll
    for (int j = 0; j < 16; ++j) {
      float s = bsh[j];
      #pragma unroll
      for (int i = 0; i < 16; ++i) if (i < j) s -= R[j][i]*w[i];
      w[j] = s*rinv[j];
    }
    #pragma unroll
    for (int j = 15; j >= 0; --j) {
      float s = w[j];
      #pragma unroll
      for (int i = 0; i < 16; ++i) if (i > j) s -= R[i][j]*z[i];
      z[j] = s*rinv[j];
      zsh[j] = z[j];
    }
  }
  __syncthreads();

  const int g = k >> 4, kl = k & 15;
  ushort_t* Bgp = Bmat + (size_t)g*FB_CG*DF;
  float muhp = 0.f;
  for (int itr = 0; itr < 4; ++itr) {
    int d = t + itr*256;
    float dv = Dm[k*DF + d];
    float iD = 1.f/(dv*dv);
    float mu = MU[k*DF + d];
    float v[16], gg[16];
    #pragma unroll
    for (int l = 0; l < 16; ++l) v[l] = iD * A[((size_t)k*DF + d)*LF + l];
    #pragma unroll
    for (int j = 0; j < 16; ++j) {
      float s = v[j];
      #pragma unroll
      for (int i = 0; i < 16; ++i) if (i < j) s -= R[j][i]*gg[i];
      gg[j] = s * rinv[j];
    }
    float h = iD*mu;
    #pragma unroll
    for (int l = 0; l < 16; ++l) h -= v[l]*zsh[l];
    muhp = fmaf(mu, h, muhp);
    #pragma unroll
    for (int l = 0; l < 16; ++l)
      Bgp[(size_t)(kl*16 + l)*DF + d] = f2bf(gg[l]);
    Bgp[(size_t)(256 + kl)*DF + d] = f2bf(h);
    Bgp[(size_t)(272 + kl)*DF + d] = f2bf(iD);
  }
  red[t] = muhp;
  __syncthreads();
  for (int s = 128; s > 0; s >>= 1) {
    if (t < s) red[t] += red[t + s];
    __syncthreads();
  }
  if (t == 0) {
    muh[k] = red[0];
    cst[k] = PI[k] - 0.5f*((float)DF*LOG2PI + ldet - sumlogiD);
  }
}

__global__ __launch_bounds__(512, 2) void fb_main(
    const float* __restrict__ x, const ushort_t* __restrict__ Bmat,
    const float* __restrict__ cst, const float* __restrict__ muh,
    float* __restrict__ out)
{
  __shared__ __align__(16) ushort_t smem[2*FB_BN*FB_PITCH + FB_CG*FB_PITCH];
  ushort_t* xs  = smem;
  ushort_t* x2s = smem + FB_BN*FB_PITCH;
  ushort_t* Bs  = smem + 2*FB_BN*FB_PITCH;

  const int t = threadIdx.x;
  const int lane = t & 63, wid = t >> 6;
  const int wr = wid & 3, wc = wid >> 2;
  const int lr = lane & 15, lh = lane >> 4;
  const int n0 = blockIdx.x * FB_BN;
  const int g  = blockIdx.y;

  f32x4 acc[2][9] = {};
  const int srow = t >> 2, sc = t & 3;

  int xoff[2];
  #pragma unroll
  for (int rt = 0; rt < 2; ++rt)
    xoff[rt] = (wr*32 + rt*16 + lr)*FB_PITCH + lh*8;
  int boff[9];
  #pragma unroll
  for (int ct = 0; ct < 9; ++ct)
    boff[ct] = (wc*144 + ct*16 + lr)*FB_PITCH + lh*8;

  for (int d0 = 0; d0 < DF; d0 += FB_DT) {
    __syncthreads();
    {
      const float* xp = x + (size_t)(n0 + srow)*DF + d0 + sc*8;
      float4 v0 = *(const float4*)xp;
      float4 v1 = *(const float4*)(xp + 4);
      float e[8] = {v0.x,v0.y,v0.z,v0.w,v1.x,v1.y,v1.z,v1.w};
      short8v xv, qv;
      #pragma unroll
      for (int i = 0; i < 8; ++i) {
        xv[i] = (short)f2bf(e[i]);
        qv[i] = (short)f2bf(e[i]*e[i]);
      }
      *(short8v*)&xs[srow*FB_PITCH + sc*8]  = xv;
      *(short8v*)&x2s[srow*FB_PITCH + sc*8] = qv;
    }
    for (int u = t; u < FB_CG*4; u += 512) {
      int col = u >> 2, c = u & 3;
      *(short8v*)&Bs[col*FB_PITCH + c*8] =
        *(const short8v*)&Bmat[((size_t)(g*FB_CG + col))*DF + d0 + c*8];
    }
    __syncthreads();

    short8v xf[2];
    #pragma unroll
    for (int rt = 0; rt < 2; ++rt) xf[rt] = *(short8v*)&xs[xoff[rt]];
    #pragma unroll
    for (int ct = 0; ct < 8; ++ct) {
      short8v bf = *(short8v*)&Bs[boff[ct]];
      #pragma unroll
      for (int rt = 0; rt < 2; ++rt)
        acc[rt][ct] = __builtin_amdgcn_mfma_f32_16x16x32_bf16(xf[rt], bf, acc[rt][ct], 0, 0, 0);
    }
    {
      short8v bf = *(short8v*)&Bs[boff[8]];
      short8v a0 = xf[0], a1 = xf[1];
      if (wc) {
        a0 = *(short8v*)&x2s[xoff[0]];
        a1 = *(short8v*)&x2s[xoff[1]];
      }
      acc[0][8] = __builtin_amdgcn_mfma_f32_16x16x32_bf16(a0, bf, acc[0][8], 0, 0, 0);
      acc[1][8] = __builtin_amdgcn_mfma_f32_16x16x32_bf16(a1, bf, acc[1][8], 0, 0, 0);
    }
  }

  __syncthreads();
  float* s1v = (float*)smem;
  float* s2h = s1v + FB_BN*17;
  if (wc == 1) {
    #pragma unroll
    for (int rt = 0; rt < 2; ++rt)
      #pragma unroll
      for (int j = 0; j < 4; ++j) {
        int row = wr*32 + rt*16 + lh*4 + j;
        s2h[row*17 + lr] = acc[rt][7][j];
        s1v[row*17 + lr] = acc[rt][8][j];
      }
  }
  __syncthreads();

  const int nyt = wc ? 7 : 9;
  #pragma unroll
  for (int ct = 0; ct < 9; ++ct) {
    if (ct < nyt) {
      int comp = wc*9 + ct;
      int kk = g*16 + comp;
      float cstk = cst[kk], muhk = muh[kk];
      #pragma unroll
      for (int rt = 0; rt < 2; ++rt)
        #pragma unroll
        for (int j = 0; j < 4; ++j) {
          float yv = acc[rt][ct][j];
          float sq = yv*yv;
          sq += __shfl_xor(sq, 1);
          sq += __shfl_xor(sq, 2);
          sq += __shfl_xor(sq, 4);
          sq += __shfl_xor(sq, 8);
          int row = wr*32 + rt*16 + lh*4 + j;
          float s1 = s1v[row*17 + comp];
          float s2 = s2h[row*17 + comp];
          float res = cstk - 0.5f*(s1 - sq - 2.f*s2 + muhk);
          if (lr == 0) out[(size_t)(n0 + row)*KCOMP + kk] = res;
        }
    }
  }
}

// ===========================================================================
extern "C" void kernel_launch(void* const* d_in, const int* in_sizes, int n_in,
                              void* d_out, int out_size, void* d_ws, size_t ws_size,
                              hipStream_t stream) {
  const float* x  = (const float*)d_in[0];
  const float* PI = (const float*)d_in[1];
  const float* MU = (const float*)d_in[2];
  const float* A  = (const float*)d_in[3];
  const float* Dm = (const float*)d_in[4];
  float* out = (float*)d_out;

  if (ws_size >= FULL_NEED) {
    ushort_t* xbf = (ushort_t*)((char*)d_ws + XBF_OFF);
    ushort_t* Bg  = (ushort_t*)((char*)d_ws + BG_OFF);
    ushort_t* Bsk = (ushort_t*)((char*)d_ws + BSK_OFF);
    float* pack   = (float*)((char*)d_ws + PACK_OFF);
    float* csk    = (float*)((char*)d_ws + CSK_OFF);

    mfa_xconv<<<dim3(NPTS*DF/8/256), dim3(256), 0, stream>>>(x, xbf);
    mfa_pre1<<<dim3(KCOMP), dim3(256), 0, stream>>>(PI, MU, A, Dm, pack, csk);
    mfa_pre2<<<dim3(KCOMP*4), dim3(256), 0, stream>>>(MU, A, Dm, pack, Bg, Bsk);
    mfa_sk<<<dim3(NPTS/64), dim3(256), 0, stream>>>(xbf, Bsk, csk, out);
    mfa_gemm<<<dim3((NPTS/256)*(2048/128)), dim3(256), 0, stream>>>(xbf, Bg, out);
  } else {
    ushort_t* Bmat = (ushort_t*)d_ws;
    float* cstp = (float*)((char*)d_ws + FB_CST_OFF);
    float* muhp = (float*)((char*)d_ws + FB_MUH_OFF);
    fb_pre<<<dim3(KCOMP), dim3(256), 0, stream>>>(PI, MU, A, Dm, Bmat, cstp, muhp);
    fb_main<<<dim3(NPTS/FB_BN, FB_NG), dim3(512), 0, stream>>>(x, Bmat, cstp, muhp, out);
  }
}

// Round 4
// 220.656 us; speedup vs baseline: 1.1042x; 1.1042x over previous
//
#include <hip/hip_runtime.h>
#include <math.h>

typedef unsigned short ushort_t;
typedef __attribute__((ext_vector_type(8))) short short8v;
typedef __attribute__((ext_vector_type(4))) float f32x4;

#define KCOMP 128
#define DF    1024
#define LF    16
#define NPTS  16384
#define LOG2PI 1.8378770664093453f

// ---------------- full-path ws layout (bytes) ----------------
#define XBF_OFF   ((size_t)0)
#define XBF_BYTES ((size_t)NPTS*DF*2)            // 33,554,432
#define BG_OFF    (XBF_OFF + XBF_BYTES)
#define BG_BYTES  ((size_t)2048*DF*2)            // 4,194,304
#define BSK_OFF   (BG_OFF + BG_BYTES)
#define BSK_BYTES ((size_t)KCOMP*2*DF*2)         // 524,288
#define PACK_OFF  (BSK_OFF + BSK_BYTES)
#define PACK_BYTES ((size_t)KCOMP*288*4)         // 147,456
#define CSK_OFF   (PACK_OFF + PACK_BYTES)
#define FULL_NEED (CSK_OFF + 512)

__device__ __forceinline__ ushort_t f2bf(float f) {
  union { float f; unsigned u; } v; v.f = f;
  unsigned u = v.u;
  return (ushort_t)((u + 0x7FFFu + ((u >> 16) & 1u)) >> 16);
}

#define GLOAD16(gp, lp) __builtin_amdgcn_global_load_lds( \
  (const __attribute__((address_space(1))) unsigned int*)(gp), \
  (__attribute__((address_space(3))) unsigned int*)(lp), 16, 0, 0)

#define DSR(dst, addr) asm volatile("ds_read_b128 %0, %1" : "=&v"(dst) : "v"(addr))

// ---------------------------------------------------------------------------
// pre1: per-k Lm = I + A^T iD A ; chol ; z ; csk = cst - 0.5*muh ; pack R/rinv/z
// ---------------------------------------------------------------------------
__global__ __launch_bounds__(256) void mfa_pre1(
    const float* __restrict__ PI, const float* __restrict__ MU,
    const float* __restrict__ A, const float* __restrict__ Dm,
    float* __restrict__ pack, float* __restrict__ csk)
{
  const int k = blockIdx.x, t = threadIdx.x;
  const int tl = t >> 4, tm = t & 15;
  __shared__ float As[64][16];
  __shared__ float iD64[64], MU64[64];
  __shared__ float R[16][17];
  __shared__ float rinv_s[16], zsh[16], bsh[16];
  __shared__ float red[64];
  __shared__ float sc_sumlog, sc_c3;

  float accL = 0.f, accb = 0.f, c3p = 0.f, slogp = 0.f;
  for (int ch = 0; ch < 16; ++ch) {
    __syncthreads();
    ((float4*)&As[0][0])[t] =
        ((const float4*)(A + (size_t)k*DF*LF + (size_t)ch*1024))[t];
    if (t < 64) {
      float dv = Dm[k*DF + ch*64 + t];
      iD64[t] = 1.f/(dv*dv);
      MU64[t] = MU[k*DF + ch*64 + t];
    }
    __syncthreads();
    #pragma unroll 4
    for (int dd = 0; dd < 64; ++dd)
      accL = fmaf(As[dd][tl]*iD64[dd], As[dd][tm], accL);
    if (tm == 0)
      for (int dd = 0; dd < 64; ++dd)
        accb = fmaf(iD64[dd]*MU64[dd], As[dd][tl], accb);
    if (t < 64) {
      c3p = fmaf(iD64[t]*MU64[t], MU64[t], c3p);
      slogp += logf(iD64[t]);
    }
  }
  __syncthreads();
  R[tl][tm] = accL + (tl == tm ? 1.f : 0.f);
  if (tm == 0) bsh[tl] = accb;
  if (t < 64) red[t] = slogp;
  __syncthreads();
  if (t == 0) { float s = 0.f; for (int i = 0; i < 64; ++i) s += red[i]; sc_sumlog = s; }
  __syncthreads();
  if (t < 64) red[t] = c3p;
  __syncthreads();
  if (t == 0) { float s = 0.f; for (int i = 0; i < 64; ++i) s += red[i]; sc_c3 = s; }

  for (int j = 0; j < 16; ++j) {
    __syncthreads();
    if (t == j) {
      float s = R[j][j];
      for (int i = 0; i < j; ++i) s -= R[j][i]*R[j][i];
      float rj = sqrtf(s);
      R[j][j] = rj; rinv_s[j] = 1.f/rj;
    }
    __syncthreads();
    if (t < 16 && t > j) {
      float s = R[t][j];
      for (int i = 0; i < j; ++i) s -= R[t][i]*R[j][i];
      R[t][j] = s * rinv_s[j];
    }
  }
  __syncthreads();
  if (t == 0) {
    float ldet = 0.f;
    for (int j = 0; j < 16; ++j) ldet += 2.f*logf(R[j][j]);
    float w[16], z[16];
    for (int j = 0; j < 16; ++j) {
      float s = bsh[j];
      for (int i = 0; i < j; ++i) s -= R[j][i]*w[i];
      w[j] = s*rinv_s[j];
    }
    for (int j = 15; j >= 0; --j) {
      float s = w[j];
      for (int i = j+1; i < 16; ++i) s -= R[i][j]*z[i];
      z[j] = s*rinv_s[j];
      zsh[j] = z[j];
    }
    float muh = sc_c3;
    for (int l = 0; l < 16; ++l) muh -= bsh[l]*zsh[l];
    csk[k] = PI[k] - 0.5f*((float)DF*LOG2PI + ldet - sc_sumlog) - 0.5f*muh;
  }
  __syncthreads();
  pack[(size_t)k*288 + t] = R[tl][tm];
  if (t < 16) {
    pack[(size_t)k*288 + 256 + t] = rinv_s[t];
    pack[(size_t)k*288 + 272 + t] = zsh[t];
  }
}

// ---------------------------------------------------------------------------
// pre2: G = iDA L^{-T}, h = iD*mu - iDA z ; write Bg (bf16) and Bsk [-2h; iD]
// ---------------------------------------------------------------------------
__global__ __launch_bounds__(256) void mfa_pre2(
    const float* __restrict__ MU, const float* __restrict__ A,
    const float* __restrict__ Dm, const float* __restrict__ pack,
    ushort_t* __restrict__ Bg, ushort_t* __restrict__ Bsk)
{
  const int k = blockIdx.x >> 2;
  const int t = threadIdx.x;
  const int d = (blockIdx.x & 3) * 256 + t;
  __shared__ float Rl[16][16], ri[16], zl[16];
  ((float*)Rl)[t] = pack[(size_t)k*288 + t];
  if (t < 16) { ri[t] = pack[(size_t)k*288+256+t]; zl[t] = pack[(size_t)k*288+272+t]; }
  __syncthreads();
  float dv = Dm[k*DF + d];
  float iD = 1.f/(dv*dv);
  float mu = MU[k*DF + d];
  float v[16], gg[16];
  #pragma unroll
  for (int l = 0; l < 16; ++l) v[l] = iD * A[((size_t)k*DF + d)*LF + l];
  #pragma unroll
  for (int j = 0; j < 16; ++j) {
    float s = v[j];
    #pragma unroll
    for (int i = 0; i < 16; ++i) if (i < j) s -= Rl[j][i]*gg[i];
    gg[j] = s * ri[j];
  }
  float h = iD*mu;
  #pragma unroll
  for (int l = 0; l < 16; ++l) h -= v[l]*zl[l];
  #pragma unroll
  for (int l = 0; l < 16; ++l)
    Bg[(size_t)(k*16 + l)*DF + d] = f2bf(gg[l]);
  Bsk[(size_t)k*2*DF + d]      = f2bf(-2.f*h);
  Bsk[(size_t)k*2*DF + DF + d] = f2bf(iD);
}

// ---------------------------------------------------------------------------
// sk2: per 64-row tile: convert x->bf16 (write xbf plane), build x^2 in LDS,
// compute out[n,c] = csk[c] - 0.5*( x.(-2h) + x^2.iD ) over K=1024 each.
// 256 thr = 4 col-waves; wave: 64 rows x 32 comps (4x2 frags, both parts).
// ---------------------------------------------------------------------------
__global__ __launch_bounds__(256) void mfa_sk2(
    const float* __restrict__ x, const ushort_t* __restrict__ Bsk,
    const float* __restrict__ csk, ushort_t* __restrict__ xbf,
    float* __restrict__ out)
{
  __shared__ ushort_t xs[4096];     // [64][64] swizzled
  __shared__ ushort_t x2s[4096];
  __shared__ ushort_t Bs[16384];    // [256 vcols][64] swizzled (0-127 h, 128-255 iD)
  const int t = threadIdx.x, lane = t & 63, wid = t >> 6;
  const int wc = wid;
  const int lr = lane & 15, lh = lane >> 4;
  const int n0 = blockIdx.x * 64;
  const int xr = t >> 2, xc = t & 3;

  f32x4 acc[4][2] = {};

  for (int tt = 0; tt < 16; ++tt) {
    const int d0 = tt * 64;
    __syncthreads();
    // ---- stage x (fp32 -> bf16 + bf16^2), write xbf plane ----
    {
      const float* xp = x + (size_t)(n0 + xr)*DF + d0 + xc*16;
      float4 v0 = ((const float4*)xp)[0];
      float4 v1 = ((const float4*)xp)[1];
      float4 v2 = ((const float4*)xp)[2];
      float4 v3 = ((const float4*)xp)[3];
      float e[16] = {v0.x,v0.y,v0.z,v0.w, v1.x,v1.y,v1.z,v1.w,
                     v2.x,v2.y,v2.z,v2.w, v3.x,v3.y,v3.z,v3.w};
      short8v b0, b1, q0, q1;
      #pragma unroll
      for (int i = 0; i < 8; ++i) {
        b0[i] = (short)f2bf(e[i]);     q0[i] = (short)f2bf(e[i]*e[i]);
        b1[i] = (short)f2bf(e[8+i]);   q1[i] = (short)f2bf(e[8+i]*e[8+i]);
      }
      const int ch0 = (xc*2) ^ (xr & 7), ch1 = (xc*2+1) ^ (xr & 7);
      *(short8v*)&xs[xr*64 + ch0*8]  = b0;
      *(short8v*)&xs[xr*64 + ch1*8]  = b1;
      *(short8v*)&x2s[xr*64 + ch0*8] = q0;
      *(short8v*)&x2s[xr*64 + ch1*8] = q1;
      *(short8v*)&xbf[(size_t)(n0 + xr)*DF + d0 + xc*16]     = b0;
      *(short8v*)&xbf[(size_t)(n0 + xr)*DF + d0 + xc*16 + 8] = b1;
    }
    // ---- stage B (both parts) via global_load_lds ----
    #pragma unroll
    for (int j = 0; j < 8; ++j) {
      int v = (wid*8 + j)*8 + (lane >> 3);
      int g = (lane & 7) ^ (v & 7);
      const ushort_t* src = (v < 128)
        ? Bsk + (size_t)v*(2*DF) + d0 + g*8
        : Bsk + (size_t)(v - 128)*(2*DF) + DF + d0 + g*8;
      GLOAD16(src, (char*)Bs + (wid*8 + j)*1024);
    }
    __syncthreads();
    // ---- compute ----
    #pragma unroll
    for (int ks = 0; ks < 2; ++ks) {
      const int cterm = ((ks*4 + lh) ^ (lr & 7)) * 8;
      short8v a_[4], a2_[4], bh[2], bi[2];
      #pragma unroll
      for (int rb = 0; rb < 4; ++rb) {
        a_[rb]  = *(const short8v*)&xs[(rb*16 + lr)*64 + cterm];
        a2_[rb] = *(const short8v*)&x2s[(rb*16 + lr)*64 + cterm];
      }
      #pragma unroll
      for (int cb = 0; cb < 2; ++cb) {
        int vh = wc*32 + cb*16 + lr;
        bh[cb] = *(const short8v*)&Bs[vh*64 + cterm];
        bi[cb] = *(const short8v*)&Bs[(128 + vh)*64 + cterm];
      }
      #pragma unroll
      for (int cb = 0; cb < 2; ++cb)
        #pragma unroll
        for (int rb = 0; rb < 4; ++rb) {
          acc[rb][cb] = __builtin_amdgcn_mfma_f32_16x16x32_bf16(a_[rb],  bh[cb], acc[rb][cb], 0,0,0);
          acc[rb][cb] = __builtin_amdgcn_mfma_f32_16x16x32_bf16(a2_[rb], bi[cb], acc[rb][cb], 0,0,0);
        }
    }
  }
  // ---- epilogue: out = csk - 0.5*dot ----
  #pragma unroll
  for (int cb = 0; cb < 2; ++cb) {
    int comp = wc*32 + cb*16 + lr;
    float ck = csk[comp];
    #pragma unroll
    for (int rb = 0; rb < 4; ++rb)
      #pragma unroll
      for (int j = 0; j < 4; ++j) {
        int row = n0 + rb*16 + lh*4 + j;
        out[(size_t)row*KCOMP + comp] = ck - 0.5f*acc[rb][cb][j];
      }
  }
}

// ---------------------------------------------------------------------------
// gemm8: out[n,comp] += 0.5 * sum_l y_l^2, y = xbf . Bg^T (16384x2048x1024)
// 256x256 tile, BK=64, 512 thr = 8 waves (2Mx4N), 128 KiB LDS (2 K-tile slots),
// 4 phases/K-tile, counted vmcnt(8) gate, asm ds_read, setprio on MFMA.
// ---------------------------------------------------------------------------
#define DO_MFMA16(R0) do { \
  _Pragma("unroll") \
  for (int cb = 0; cb < 4; ++cb) { \
    _Pragma("unroll") \
    for (int rb = 0; rb < 4; ++rb) \
      acc[(R0)+rb][cb] = __builtin_amdgcn_mfma_f32_16x16x32_bf16(af[rb], bf[cb], acc[(R0)+rb][cb], 0,0,0); \
  } } while (0)

__global__ __launch_bounds__(512, 2) void mfa_gemm8(
    const ushort_t* __restrict__ xbf, const ushort_t* __restrict__ Bg,
    float* __restrict__ out)
{
  __shared__ ushort_t smem[65536];   // 128 KiB: [slot][A 32KB | B 32KB]
  char* sbase = (char*)smem;
  const int t = threadIdx.x, lane = t & 63, wid = t >> 6;
  const int wm = wid & 1, wn = wid >> 1;
  const int lr = lane & 15, lh = lane >> 4;

  const int bid = blockIdx.x;                    // 512 = 64 rb x 8 cb
  const int swz = (bid & 7) * 64 + (bid >> 3);   // XCD-bijective (512 % 8 == 0)
  const int n0 = (swz >> 3) * 256, c0 = (swz & 7) * 256;

  // staging constants: instr j covers 8 rows x 128B; chunk-swizzled source
  const ushort_t* srcA[4];
  const ushort_t* srcB[4];
  int dstA[4], dstB[4];
  #pragma unroll
  for (int j = 0; j < 4; ++j) {
    int r = (wid*4 + j)*8 + (lane >> 3);
    int g = (lane & 7) ^ (r & 7);
    srcA[j] = xbf + (size_t)(n0 + r)*DF + g*8;
    srcB[j] = Bg  + (size_t)(c0 + r)*DF + g*8;
    dstA[j] = (wid*4 + j)*1024;
    dstB[j] = 32768 + (wid*4 + j)*1024;
  }
  const int aBase = (wm*128 + lr)*128;           // byte offsets
  const int bBase = 32768 + (wn*64 + lr)*128;
  const int ct0 = ((0 + lh) ^ (lr & 7))*16;
  const int ct1 = ((4 + lh) ^ (lr & 7))*16;

  f32x4 acc[8][4] = {};

  auto STAGE = [&](int slot, int tt_) {
    char* lb = sbase + slot*65536;
    #pragma unroll
    for (int j = 0; j < 4; ++j) GLOAD16(srcA[j] + tt_*64, lb + dstA[j]);
    #pragma unroll
    for (int j = 0; j < 4; ++j) GLOAD16(srcB[j] + tt_*64, lb + dstB[j]);
  };

  STAGE(0, 0);
  STAGE(1, 1);

  for (int tt = 0; tt < 16; ++tt) {
    const int sb = (tt & 1) * 65536;
    short8v af[4], bf[4];

    // ---- gate: tile tt resident (never drain younger prefetch) ----
    if (tt < 15) asm volatile("s_waitcnt vmcnt(8)" ::: "memory");
    else         asm volatile("s_waitcnt vmcnt(0)" ::: "memory");
    __builtin_amdgcn_s_barrier();
    __builtin_amdgcn_sched_barrier(0);

    // ---- q0: rows 0-3 @ks0 (+B ks0) ----
    #pragma unroll
    for (int rb = 0; rb < 4; ++rb) DSR(af[rb], sb + aBase + rb*2048 + ct0);
    #pragma unroll
    for (int cb = 0; cb < 4; ++cb) DSR(bf[cb], sb + bBase + cb*2048 + ct0);
    __builtin_amdgcn_s_barrier();
    asm volatile("s_waitcnt lgkmcnt(0)" ::: "memory");
    __builtin_amdgcn_sched_barrier(0);
    __builtin_amdgcn_s_setprio(1);
    DO_MFMA16(0);
    __builtin_amdgcn_s_setprio(0);
    __builtin_amdgcn_s_barrier();

    // ---- q1: rows 4-7 @ks0 ----
    #pragma unroll
    for (int rb = 0; rb < 4; ++rb) DSR(af[rb], sb + aBase + (4+rb)*2048 + ct0);
    __builtin_amdgcn_s_barrier();
    asm volatile("s_waitcnt lgkmcnt(0)" ::: "memory");
    __builtin_amdgcn_sched_barrier(0);
    __builtin_amdgcn_s_setprio(1);
    DO_MFMA16(4);
    __builtin_amdgcn_s_setprio(0);
    __builtin_amdgcn_s_barrier();

    // ---- q2: rows 0-3 @ks1 (+B ks1) ----
    #pragma unroll
    for (int rb = 0; rb < 4; ++rb) DSR(af[rb], sb + aBase + rb*2048 + ct1);
    #pragma unroll
    for (int cb = 0; cb < 4; ++cb) DSR(bf[cb], sb + bBase + cb*2048 + ct1);
    __builtin_amdgcn_s_barrier();
    asm volatile("s_waitcnt lgkmcnt(0)" ::: "memory");
    __builtin_amdgcn_sched_barrier(0);
    __builtin_amdgcn_s_setprio(1);
    DO_MFMA16(0);
    __builtin_amdgcn_s_setprio(0);
    __builtin_amdgcn_s_barrier();

    // ---- q3: rows 4-7 @ks1 ; restage slot with tile tt+2 ----
    #pragma unroll
    for (int rb = 0; rb < 4; ++rb) DSR(af[rb], sb + aBase + (4+rb)*2048 + ct1);
    asm volatile("s_waitcnt lgkmcnt(0)" ::: "memory");
    __builtin_amdgcn_sched_barrier(0);
    __builtin_amdgcn_s_barrier();       // all waves done reading this slot
    __builtin_amdgcn_sched_barrier(0);
    if (tt <= 13) STAGE(tt & 1, tt + 2);
    __builtin_amdgcn_s_setprio(1);
    DO_MFMA16(4);
    __builtin_amdgcn_s_setprio(0);
    __builtin_amdgcn_s_barrier();
  }

  // ---- epilogue: squared-column reduce, out += 0.5*sum ----
  #pragma unroll
  for (int cb = 0; cb < 4; ++cb) {
    const int comp = (c0 >> 4) + wn*4 + cb;
    #pragma unroll
    for (int rb = 0; rb < 8; ++rb) {
      #pragma unroll
      for (int j = 0; j < 4; ++j) {
        float v = acc[rb][cb][j];
        float sq = v*v;
        sq += __shfl_xor(sq, 1);
        sq += __shfl_xor(sq, 2);
        sq += __shfl_xor(sq, 4);
        sq += __shfl_xor(sq, 8);
        if (lr == 0) {
          int row = n0 + wm*128 + rb*16 + lh*4 + j;
          size_t idx = (size_t)row * KCOMP + comp;
          out[idx] = out[idx] + 0.5f*sq;
        }
      }
    }
  }
}

// ===========================================================================
// Fallback path (round-2 kernels, needs ~4.8 MB ws) — used if ws too small
// ===========================================================================
#define FB_NG 8
#define FB_CG 288
#define FB_BN 128
#define FB_DT 32
#define FB_PITCH 40
#define FB_BMAT_ELEMS ((size_t)(FB_NG*FB_CG)*DF)
#define FB_CST_OFF (FB_BMAT_ELEMS*2)
#define FB_MUH_OFF (FB_CST_OFF + 512)

__global__ __launch_bounds__(256) void fb_pre(
    const float* __restrict__ PI, const float* __restrict__ MU,
    const float* __restrict__ A, const float* __restrict__ Dm,
    ushort_t* __restrict__ Bmat, float* __restrict__ cst, float* __restrict__ muh)
{
  const int k = blockIdx.x, t = threadIdx.x;
  const int tl = t >> 4, tm = t & 15;
  __shared__ float As[16][16], iDsh[16], MUsh[16];
  __shared__ float R[16][17], rinv[16], zsh[16], bsh[16];
  __shared__ float red[256];

  float accL = 0.f, accb = 0.f, slog = 0.f;
  for (int d0 = 0; d0 < DF; d0 += 16) {
    __syncthreads();
    As[tl][tm] = A[((size_t)k*DF + d0 + tl)*LF + tm];
    if (t < 16) {
      float dv = Dm[k*DF + d0 + t];
      iDsh[t] = 1.f/(dv*dv);
      MUsh[t] = MU[k*DF + d0 + t];
    }
    __syncthreads();
    #pragma unroll
    for (int dd = 0; dd < 16; ++dd)
      accL = fmaf(As[dd][tl]*iDsh[dd], As[dd][tm], accL);
    if (tm == 0) {
      #pragma unroll
      for (int dd = 0; dd < 16; ++dd)
        accb = fmaf(iDsh[dd]*MUsh[dd], As[dd][tl], accb);
    }
    if (t < 16) slog += logf(iDsh[t]);
  }
  __syncthreads();
  R[tl][tm] = accL + (tl == tm ? 1.f : 0.f);
  if (tm == 0) bsh[tl] = accb;
  red[t] = (t < 16) ? slog : 0.f;
  __syncthreads();
  float sumlogiD = 0.f;
  if (t == 0) { for (int i = 0; i < 16; ++i) sumlogiD += red[i]; }

  for (int j = 0; j < 16; ++j) {
    if (t == j) {
      float s = R[j][j];
      for (int i = 0; i < j; ++i) s -= R[j][i]*R[j][i];
      float rj = sqrtf(s);
      R[j][j] = rj; rinv[j] = 1.f/rj;
    }
    __syncthreads();
    if (t < 16 && t > j) {
      float s = R[t][j];
      for (int i = 0; i < j; ++i) s -= R[t][i]*R[j][i];
      R[t][j] = s * rinv[j];
    }
    __syncthreads();
  }

  float ldet = 0.f;
  if (t == 0) {
    #pragma unroll
    for (int j = 0; j < 16; ++j) ldet += 2.f*logf(R[j][j]);
    float w[16], z[16];
    #pragma unroll
    for (int j = 0; j < 16; ++j) {
      float s = bsh[j];
      #pragma unroll
      for (int i = 0; i < 16; ++i) if (i < j) s -= R[j][i]*w[i];
      w[j] = s*rinv[j];
    }
    #pragma unroll
    for (int j = 15; j >= 0; --j) {
      float s = w[j];
      #pragma unroll
      for (int i = 0; i < 16; ++i) if (i > j) s -= R[i][j]*z[i];
      z[j] = s*rinv[j];
      zsh[j] = z[j];
    }
  }
  __syncthreads();

  const int g = k >> 4, kl = k & 15;
  ushort_t* Bgp = Bmat + (size_t)g*FB_CG*DF;
  float muhp = 0.f;
  for (int itr = 0; itr < 4; ++itr) {
    int d = t + itr*256;
    float dv = Dm[k*DF + d];
    float iD = 1.f/(dv*dv);
    float mu = MU[k*DF + d];
    float v[16], gg[16];
    #pragma unroll
    for (int l = 0; l < 16; ++l) v[l] = iD * A[((size_t)k*DF + d)*LF + l];
    #pragma unroll
    for (int j = 0; j < 16; ++j) {
      float s = v[j];
      #pragma unroll
      for (int i = 0; i < 16; ++i) if (i < j) s -= R[j][i]*gg[i];
      gg[j] = s * rinv[j];
    }
    float h = iD*mu;
    #pragma unroll
    for (int l = 0; l < 16; ++l) h -= v[l]*zsh[l];
    muhp = fmaf(mu, h, muhp);
    #pragma unroll
    for (int l = 0; l < 16; ++l)
      Bgp[(size_t)(kl*16 + l)*DF + d] = f2bf(gg[l]);
    Bgp[(size_t)(256 + kl)*DF + d] = f2bf(h);
    Bgp[(size_t)(272 + kl)*DF + d] = f2bf(iD);
  }
  red[t] = muhp;
  __syncthreads();
  for (int s = 128; s > 0; s >>= 1) {
    if (t < s) red[t] += red[t + s];
    __syncthreads();
  }
  if (t == 0) {
    muh[k] = red[0];
    cst[k] = PI[k] - 0.5f*((float)DF*LOG2PI + ldet - sumlogiD);
  }
}

__global__ __launch_bounds__(512, 2) void fb_main(
    const float* __restrict__ x, const ushort_t* __restrict__ Bmat,
    const float* __restrict__ cst, const float* __restrict__ muh,
    float* __restrict__ out)
{
  __shared__ __align__(16) ushort_t smem[2*FB_BN*FB_PITCH + FB_CG*FB_PITCH];
  ushort_t* xs  = smem;
  ushort_t* x2s = smem + FB_BN*FB_PITCH;
  ushort_t* Bs  = smem + 2*FB_BN*FB_PITCH;

  const int t = threadIdx.x;
  const int lane = t & 63, wid = t >> 6;
  const int wr = wid & 3, wc = wid >> 2;
  const int lr = lane & 15, lh = lane >> 4;
  const int n0 = blockIdx.x * FB_BN;
  const int g  = blockIdx.y;

  f32x4 acc[2][9] = {};
  const int srow = t >> 2, sc = t & 3;

  int xoff[2];
  #pragma unroll
  for (int rt = 0; rt < 2; ++rt)
    xoff[rt] = (wr*32 + rt*16 + lr)*FB_PITCH + lh*8;
  int boff[9];
  #pragma unroll
  for (int ct = 0; ct < 9; ++ct)
    boff[ct] = (wc*144 + ct*16 + lr)*FB_PITCH + lh*8;

  for (int d0 = 0; d0 < DF; d0 += FB_DT) {
    __syncthreads();
    {
      const float* xp = x + (size_t)(n0 + srow)*DF + d0 + sc*8;
      float4 v0 = *(const float4*)xp;
      float4 v1 = *(const float4*)(xp + 4);
      float e[8] = {v0.x,v0.y,v0.z,v0.w,v1.x,v1.y,v1.z,v1.w};
      short8v xv, qv;
      #pragma unroll
      for (int i = 0; i < 8; ++i) {
        xv[i] = (short)f2bf(e[i]);
        qv[i] = (short)f2bf(e[i]*e[i]);
      }
      *(short8v*)&xs[srow*FB_PITCH + sc*8]  = xv;
      *(short8v*)&x2s[srow*FB_PITCH + sc*8] = qv;
    }
    for (int u = t; u < FB_CG*4; u += 512) {
      int col = u >> 2, c = u & 3;
      *(short8v*)&Bs[col*FB_PITCH + c*8] =
        *(const short8v*)&Bmat[((size_t)(g*FB_CG + col))*DF + d0 + c*8];
    }
    __syncthreads();

    short8v xf[2];
    #pragma unroll
    for (int rt = 0; rt < 2; ++rt) xf[rt] = *(short8v*)&xs[xoff[rt]];
    #pragma unroll
    for (int ct = 0; ct < 8; ++ct) {
      short8v bfr = *(short8v*)&Bs[boff[ct]];
      #pragma unroll
      for (int rt = 0; rt < 2; ++rt)
        acc[rt][ct] = __builtin_amdgcn_mfma_f32_16x16x32_bf16(xf[rt], bfr, acc[rt][ct], 0, 0, 0);
    }
    {
      short8v bfr = *(short8v*)&Bs[boff[8]];
      short8v a0 = xf[0], a1 = xf[1];
      if (wc) {
        a0 = *(short8v*)&x2s[xoff[0]];
        a1 = *(short8v*)&x2s[xoff[1]];
      }
      acc[0][8] = __builtin_amdgcn_mfma_f32_16x16x32_bf16(a0, bfr, acc[0][8], 0, 0, 0);
      acc[1][8] = __builtin_amdgcn_mfma_f32_16x16x32_bf16(a1, bfr, acc[1][8], 0, 0, 0);
    }
  }

  __syncthreads();
  float* s1v = (float*)smem;
  float* s2h = s1v + FB_BN*17;
  if (wc == 1) {
    #pragma unroll
    for (int rt = 0; rt < 2; ++rt)
      #pragma unroll
      for (int j = 0; j < 4; ++j) {
        int row = wr*32 + rt*16 + lh*4 + j;
        s2h[row*17 + lr] = acc[rt][7][j];
        s1v[row*17 + lr] = acc[rt][8][j];
      }
  }
  __syncthreads();

  const int nyt = wc ? 7 : 9;
  #pragma unroll
  for (int ct = 0; ct < 9; ++ct) {
    if (ct < nyt) {
      int comp = wc*9 + ct;
      int kk = g*16 + comp;
      float cstk = cst[kk], muhk = muh[kk];
      #pragma unroll
      for (int rt = 0; rt < 2; ++rt)
        #pragma unroll
        for (int j = 0; j < 4; ++j) {
          float yv = acc[rt][ct][j];
          float sq = yv*yv;
          sq += __shfl_xor(sq, 1);
          sq += __shfl_xor(sq, 2);
          sq += __shfl_xor(sq, 4);
          sq += __shfl_xor(sq, 8);
          int row = wr*32 + rt*16 + lh*4 + j;
          float s1 = s1v[row*17 + comp];
          float s2 = s2h[row*17 + comp];
          float res = cstk - 0.5f*(s1 - sq - 2.f*s2 + muhk);
          if (lr == 0) out[(size_t)(n0 + row)*KCOMP + kk] = res;
        }
    }
  }
}

// ===========================================================================
extern "C" void kernel_launch(void* const* d_in, const int* in_sizes, int n_in,
                              void* d_out, int out_size, void* d_ws, size_t ws_size,
                              hipStream_t stream) {
  const float* x  = (const float*)d_in[0];
  const float* PI = (const float*)d_in[1];
  const float* MU = (const float*)d_in[2];
  const float* A  = (const float*)d_in[3];
  const float* Dm = (const float*)d_in[4];
  float* out = (float*)d_out;

  if (ws_size >= FULL_NEED) {
    ushort_t* xbf = (ushort_t*)((char*)d_ws + XBF_OFF);
    ushort_t* Bg  = (ushort_t*)((char*)d_ws + BG_OFF);
    ushort_t* Bsk = (ushort_t*)((char*)d_ws + BSK_OFF);
    float* pack   = (float*)((char*)d_ws + PACK_OFF);
    float* csk    = (float*)((char*)d_ws + CSK_OFF);

    mfa_pre1<<<dim3(KCOMP), dim3(256), 0, stream>>>(PI, MU, A, Dm, pack, csk);
    mfa_pre2<<<dim3(KCOMP*4), dim3(256), 0, stream>>>(MU, A, Dm, pack, Bg, Bsk);
    mfa_sk2<<<dim3(NPTS/64), dim3(256), 0, stream>>>(x, Bsk, csk, xbf, out);
    mfa_gemm8<<<dim3((NPTS/256)*(2048/256)), dim3(512), 0, stream>>>(xbf, Bg, out);
  } else {
    ushort_t* Bmat = (ushort_t*)d_ws;
    float* cstp = (float*)((char*)d_ws + FB_CST_OFF);
    float* muhp = (float*)((char*)d_ws + FB_MUH_OFF);
    fb_pre<<<dim3(KCOMP), dim3(256), 0, stream>>>(PI, MU, A, Dm, Bmat, cstp, muhp);
    fb_main<<<dim3(NPTS/FB_BN, FB_NG), dim3(512), 0, stream>>>(x, Bmat, cstp, muhp, out);
  }
}

// Round 5
// 175.134 us; speedup vs baseline: 1.3912x; 1.2599x over previous
//
#include <hip/hip_runtime.h>
#include <math.h>

typedef unsigned short ushort_t;
typedef __attribute__((ext_vector_type(8))) short short8v;
typedef __attribute__((ext_vector_type(4))) float f32x4;

#define KCOMP 128
#define DF    1024
#define LF    16
#define NPTS  16384
#define LOG2PI 1.8378770664093453f

// ---------------- full-path ws layout (bytes) ----------------
#define XBF_OFF   ((size_t)0)
#define XBF_BYTES ((size_t)NPTS*DF*2)            // 33,554,432
#define BG_OFF    (XBF_OFF + XBF_BYTES)
#define BG_BYTES  ((size_t)2048*DF*2)            // 4,194,304
#define BSK_OFF   (BG_OFF + BG_BYTES)
#define BSK_BYTES ((size_t)KCOMP*2*DF*2)         // 524,288
#define PACK_OFF  (BSK_OFF + BSK_BYTES)
#define PACK_BYTES ((size_t)KCOMP*288*4)         // 147,456
#define CSK_OFF   (PACK_OFF + PACK_BYTES)
#define FULL_NEED (CSK_OFF + 512)

__device__ __forceinline__ ushort_t f2bf(float f) {
  union { float f; unsigned u; } v; v.f = f;
  unsigned u = v.u;
  return (ushort_t)((u + 0x7FFFu + ((u >> 16) & 1u)) >> 16);
}
__device__ __forceinline__ float bf2f(ushort_t h) {
  union { unsigned u; float f; } v; v.u = ((unsigned)h) << 16;
  return v.f;
}

#define GLOAD16(gp, lp) __builtin_amdgcn_global_load_lds( \
  (const __attribute__((address_space(1))) unsigned int*)(gp), \
  (__attribute__((address_space(3))) unsigned int*)(lp), 16, 0, 0)

// DPP reduce-add within 16-lane rows (VALU only, no LDS)
#define DPPADD(x, ctrl) do { \
  int _yi = __builtin_amdgcn_update_dpp(0, __float_as_int(x), ctrl, 0xF, 0xF, true); \
  (x) += __int_as_float(_yi); } while (0)

// ---------------------------------------------------------------------------
// pre1: per-k Lm = I + A^T iD A ; chol ; z ; csk = cst - 0.5*muh ; pack R/rinv/z
// ---------------------------------------------------------------------------
__global__ __launch_bounds__(256) void mfa_pre1(
    const float* __restrict__ PI, const float* __restrict__ MU,
    const float* __restrict__ A, const float* __restrict__ Dm,
    float* __restrict__ pack, float* __restrict__ csk)
{
  const int k = blockIdx.x, t = threadIdx.x;
  const int tl = t >> 4, tm = t & 15;
  __shared__ float As[64][16];
  __shared__ float iD64[64], MU64[64];
  __shared__ float R[16][17];
  __shared__ float rinv_s[16], zsh[16], bsh[16];
  __shared__ float red[64];
  __shared__ float sc_sumlog, sc_c3;

  float accL = 0.f, accb = 0.f, c3p = 0.f, slogp = 0.f;
  for (int ch = 0; ch < 16; ++ch) {
    __syncthreads();
    ((float4*)&As[0][0])[t] =
        ((const float4*)(A + (size_t)k*DF*LF + (size_t)ch*1024))[t];
    if (t < 64) {
      float dv = Dm[k*DF + ch*64 + t];
      iD64[t] = 1.f/(dv*dv);
      MU64[t] = MU[k*DF + ch*64 + t];
    }
    __syncthreads();
    #pragma unroll 4
    for (int dd = 0; dd < 64; ++dd)
      accL = fmaf(As[dd][tl]*iD64[dd], As[dd][tm], accL);
    if (tm == 0)
      for (int dd = 0; dd < 64; ++dd)
        accb = fmaf(iD64[dd]*MU64[dd], As[dd][tl], accb);
    if (t < 64) {
      c3p = fmaf(iD64[t]*MU64[t], MU64[t], c3p);
      slogp += logf(iD64[t]);
    }
  }
  __syncthreads();
  R[tl][tm] = accL + (tl == tm ? 1.f : 0.f);
  if (tm == 0) bsh[tl] = accb;
  if (t < 64) red[t] = slogp;
  __syncthreads();
  if (t == 0) { float s = 0.f; for (int i = 0; i < 64; ++i) s += red[i]; sc_sumlog = s; }
  __syncthreads();
  if (t < 64) red[t] = c3p;
  __syncthreads();
  if (t == 0) { float s = 0.f; for (int i = 0; i < 64; ++i) s += red[i]; sc_c3 = s; }

  for (int j = 0; j < 16; ++j) {
    __syncthreads();
    if (t == j) {
      float s = R[j][j];
      for (int i = 0; i < j; ++i) s -= R[j][i]*R[j][i];
      float rj = sqrtf(s);
      R[j][j] = rj; rinv_s[j] = 1.f/rj;
    }
    __syncthreads();
    if (t < 16 && t > j) {
      float s = R[t][j];
      for (int i = 0; i < j; ++i) s -= R[t][i]*R[j][i];
      R[t][j] = s * rinv_s[j];
    }
  }
  __syncthreads();
  if (t == 0) {
    float ldet = 0.f;
    for (int j = 0; j < 16; ++j) ldet += 2.f*logf(R[j][j]);
    float w[16], z[16];
    for (int j = 0; j < 16; ++j) {
      float s = bsh[j];
      for (int i = 0; i < j; ++i) s -= R[j][i]*w[i];
      w[j] = s*rinv_s[j];
    }
    for (int j = 15; j >= 0; --j) {
      float s = w[j];
      for (int i = j+1; i < 16; ++i) s -= R[i][j]*z[i];
      z[j] = s*rinv_s[j];
      zsh[j] = z[j];
    }
    float muh = sc_c3;
    for (int l = 0; l < 16; ++l) muh -= bsh[l]*zsh[l];
    csk[k] = PI[k] - 0.5f*((float)DF*LOG2PI + ldet - sc_sumlog) - 0.5f*muh;
  }
  __syncthreads();
  pack[(size_t)k*288 + t] = R[tl][tm];
  if (t < 16) {
    pack[(size_t)k*288 + 256 + t] = rinv_s[t];
    pack[(size_t)k*288 + 272 + t] = zsh[t];
  }
}

// ---------------------------------------------------------------------------
// pre2: G = iDA L^{-T}, h = iD*mu - iDA z ; write Bg (bf16) and Bsk [-2h; iD]
// ---------------------------------------------------------------------------
__global__ __launch_bounds__(256) void mfa_pre2(
    const float* __restrict__ MU, const float* __restrict__ A,
    const float* __restrict__ Dm, const float* __restrict__ pack,
    ushort_t* __restrict__ Bg, ushort_t* __restrict__ Bsk)
{
  const int k = blockIdx.x >> 2;
  const int t = threadIdx.x;
  const int d = (blockIdx.x & 3) * 256 + t;
  __shared__ float Rl[16][16], ri[16], zl[16];
  ((float*)Rl)[t] = pack[(size_t)k*288 + t];
  if (t < 16) { ri[t] = pack[(size_t)k*288+256+t]; zl[t] = pack[(size_t)k*288+272+t]; }
  __syncthreads();
  float dv = Dm[k*DF + d];
  float iD = 1.f/(dv*dv);
  float mu = MU[k*DF + d];
  float v[16], gg[16];
  #pragma unroll
  for (int l = 0; l < 16; ++l) v[l] = iD * A[((size_t)k*DF + d)*LF + l];
  #pragma unroll
  for (int j = 0; j < 16; ++j) {
    float s = v[j];
    #pragma unroll
    for (int i = 0; i < 16; ++i) if (i < j) s -= Rl[j][i]*gg[i];
    gg[j] = s * ri[j];
  }
  float h = iD*mu;
  #pragma unroll
  for (int l = 0; l < 16; ++l) h -= v[l]*zl[l];
  #pragma unroll
  for (int l = 0; l < 16; ++l)
    Bg[(size_t)(k*16 + l)*DF + d] = f2bf(gg[l]);
  Bsk[(size_t)k*2*DF + d]      = f2bf(-2.f*h);
  Bsk[(size_t)k*2*DF + DF + d] = f2bf(iD);
}

// ---------------------------------------------------------------------------
// sk2: per 64-row tile: convert x->bf16 (write xbf plane), build x^2 in LDS,
// compute out[n,c] = csk[c] - 0.5*( x.(-2h) + x^2.iD ) over K=1024 each.
// ---------------------------------------------------------------------------
__global__ __launch_bounds__(256) void mfa_sk2(
    const float* __restrict__ x, const ushort_t* __restrict__ Bsk,
    const float* __restrict__ csk, ushort_t* __restrict__ xbf,
    float* __restrict__ out)
{
  __shared__ ushort_t xs[4096];     // [64][64] swizzled
  __shared__ ushort_t x2s[4096];
  __shared__ ushort_t Bs[16384];    // [256 vcols][64] swizzled (0-127 h, 128-255 iD)
  const int t = threadIdx.x, lane = t & 63, wid = t >> 6;
  const int wc = wid;
  const int lr = lane & 15, lh = lane >> 4;
  const int n0 = blockIdx.x * 64;
  const int xr = t >> 2, xc = t & 3;

  f32x4 acc[4][2] = {};

  for (int tt = 0; tt < 16; ++tt) {
    const int d0 = tt * 64;
    __syncthreads();
    // ---- stage x (fp32 -> bf16 + bf16^2), write xbf plane ----
    {
      const float* xp = x + (size_t)(n0 + xr)*DF + d0 + xc*16;
      float4 v0 = ((const float4*)xp)[0];
      float4 v1 = ((const float4*)xp)[1];
      float4 v2 = ((const float4*)xp)[2];
      float4 v3 = ((const float4*)xp)[3];
      float e[16] = {v0.x,v0.y,v0.z,v0.w, v1.x,v1.y,v1.z,v1.w,
                     v2.x,v2.y,v2.z,v2.w, v3.x,v3.y,v3.z,v3.w};
      short8v b0, b1, q0, q1;
      #pragma unroll
      for (int i = 0; i < 8; ++i) {
        b0[i] = (short)f2bf(e[i]);     q0[i] = (short)f2bf(e[i]*e[i]);
        b1[i] = (short)f2bf(e[8+i]);   q1[i] = (short)f2bf(e[8+i]*e[8+i]);
      }
      const int ch0 = (xc*2) ^ (xr & 7), ch1 = (xc*2+1) ^ (xr & 7);
      *(short8v*)&xs[xr*64 + ch0*8]  = b0;
      *(short8v*)&xs[xr*64 + ch1*8]  = b1;
      *(short8v*)&x2s[xr*64 + ch0*8] = q0;
      *(short8v*)&x2s[xr*64 + ch1*8] = q1;
      *(short8v*)&xbf[(size_t)(n0 + xr)*DF + d0 + xc*16]     = b0;
      *(short8v*)&xbf[(size_t)(n0 + xr)*DF + d0 + xc*16 + 8] = b1;
    }
    // ---- stage B (both parts) via global_load_lds ----
    #pragma unroll
    for (int j = 0; j < 8; ++j) {
      int v = (wid*8 + j)*8 + (lane >> 3);
      int g = (lane & 7) ^ (v & 7);
      const ushort_t* src = (v < 128)
        ? Bsk + (size_t)v*(2*DF) + d0 + g*8
        : Bsk + (size_t)(v - 128)*(2*DF) + DF + d0 + g*8;
      GLOAD16(src, (char*)Bs + (wid*8 + j)*1024);
    }
    __syncthreads();
    // ---- compute ----
    #pragma unroll
    for (int ks = 0; ks < 2; ++ks) {
      const int cterm = ((ks*4 + lh) ^ (lr & 7)) * 8;
      short8v a_[4], a2_[4], bh[2], bi[2];
      #pragma unroll
      for (int rb = 0; rb < 4; ++rb) {
        a_[rb]  = *(const short8v*)&xs[(rb*16 + lr)*64 + cterm];
        a2_[rb] = *(const short8v*)&x2s[(rb*16 + lr)*64 + cterm];
      }
      #pragma unroll
      for (int cb = 0; cb < 2; ++cb) {
        int vh = wc*32 + cb*16 + lr;
        bh[cb] = *(const short8v*)&Bs[vh*64 + cterm];
        bi[cb] = *(const short8v*)&Bs[(128 + vh)*64 + cterm];
      }
      #pragma unroll
      for (int cb = 0; cb < 2; ++cb)
        #pragma unroll
        for (int rb = 0; rb < 4; ++rb) {
          acc[rb][cb] = __builtin_amdgcn_mfma_f32_16x16x32_bf16(a_[rb],  bh[cb], acc[rb][cb], 0,0,0);
          acc[rb][cb] = __builtin_amdgcn_mfma_f32_16x16x32_bf16(a2_[rb], bi[cb], acc[rb][cb], 0,0,0);
        }
    }
  }
  // ---- epilogue: out = csk - 0.5*dot ----
  #pragma unroll
  for (int cb = 0; cb < 2; ++cb) {
    int comp = wc*32 + cb*16 + lr;
    float ck = csk[comp];
    #pragma unroll
    for (int rb = 0; rb < 4; ++rb)
      #pragma unroll
      for (int j = 0; j < 4; ++j) {
        int row = n0 + rb*16 + lh*4 + j;
        out[(size_t)row*KCOMP + comp] = ck - 0.5f*acc[rb][cb][j];
      }
  }
}

// ---------------------------------------------------------------------------
// gemm5: out[n,comp] += 0.5 * sum_l y_l^2, y = xbf . Bg^T (16384x2048x1024)
// 256x256 tile, BK=64, 1024 thr = 16 waves (4Mx4N), wave 64x64 (acc 4x4).
// 128 KiB LDS dbuf, 2 phases/tile, counted vmcnt(4), 2 barriers/tile,
// DPP-based squared-column reduce epilogue.
// ---------------------------------------------------------------------------
__global__ __launch_bounds__(1024, 4) void mfa_gemm5(
    const ushort_t* __restrict__ xbf, const ushort_t* __restrict__ Bg,
    float* __restrict__ out)
{
  __shared__ ushort_t smem[65536];   // 128 KiB: 2 slots x [A 32KB | B 32KB]
  const int t = threadIdx.x, lane = t & 63, wid = t >> 6;  // 16 waves
  const int wm = wid & 3, wn = wid >> 2;
  const int lr = lane & 15, lh = lane >> 4;

  const int bid = blockIdx.x;            // 512 = 64 rowbands x 8 colblocks
  const int xcd = bid & 7, ib = bid >> 3;
  const int rb = xcd * 8 + (ib >> 3);    // XCD owns 8 contiguous row-bands
  const int cb = ib & 7;
  const int n0 = rb * 256, c0 = cb * 256;

  f32x4 acc[4][4] = {};

  // staging: 64 x 1KB instrs per tile (A ids 0..31, B ids 32..63), 4/wave.
  // instr covers 8 rows x 128B; lane l: row_local=l>>3, chunk j=l&7;
  // src chunk = j ^ row_local  (matches ds_read swizzle XOR (lr&7))
  const int rl8 = lane >> 3, j8 = lane & 7;
  const int js8 = (j8 ^ rl8) * 8;        // ushort offset
  const ushort_t* srcP[4]; int dstO[4];
  #pragma unroll
  for (int q = 0; q < 4; ++q) {
    int id = wid*4 + q;
    if (id < 32) { srcP[q] = xbf + (size_t)(n0 + id*8 + rl8)*DF + js8; dstO[q] = id*1024; }
    else         { srcP[q] = Bg  + (size_t)(c0 + (id-32)*8 + rl8)*DF + js8; dstO[q] = 32768 + (id-32)*1024; }
  }

  const int aO  = (wm*64 + lr)*128;              // + rt*2048 + cs
  const int bO  = 32768 + (wn*64 + lr)*128;      // + ct*2048 + cs
  const int cs0 = ((0 + lh) ^ (lr & 7))*16;
  const int cs1 = ((4 + lh) ^ (lr & 7))*16;

  #define STAGE5(slot, tt_) do { \
    _Pragma("unroll") \
    for (int q = 0; q < 4; ++q) \
      GLOAD16(srcP[q] + (tt_)*64, (char*)smem + (slot)*65536 + dstO[q]); \
  } while (0)

  STAGE5(0, 0);
  STAGE5(1, 1);

  for (int tt = 0; tt < 16; ++tt) {
    const char* lb = (const char*)smem + (tt & 1)*65536;
    short8v af[4], bf[4];

    if (tt < 15) asm volatile("s_waitcnt vmcnt(4)" ::: "memory");
    else         asm volatile("s_waitcnt vmcnt(0)" ::: "memory");
    __builtin_amdgcn_s_barrier();

    // phase 0: ks=0
    #pragma unroll
    for (int rt = 0; rt < 4; ++rt) af[rt] = *(const short8v*)(lb + aO + rt*2048 + cs0);
    #pragma unroll
    for (int ct = 0; ct < 4; ++ct) bf[ct] = *(const short8v*)(lb + bO + ct*2048 + cs0);
    asm volatile("s_waitcnt lgkmcnt(0)" ::: "memory");
    __builtin_amdgcn_sched_barrier(0);
    __builtin_amdgcn_s_setprio(1);
    #pragma unroll
    for (int ct = 0; ct < 4; ++ct)
      #pragma unroll
      for (int rt = 0; rt < 4; ++rt)
        acc[rt][ct] = __builtin_amdgcn_mfma_f32_16x16x32_bf16(af[rt], bf[ct], acc[rt][ct], 0,0,0);
    __builtin_amdgcn_s_setprio(0);

    // phase 1: ks=1 ; restage this slot with tile tt+2 after all waves sampled
    #pragma unroll
    for (int rt = 0; rt < 4; ++rt) af[rt] = *(const short8v*)(lb + aO + rt*2048 + cs1);
    #pragma unroll
    for (int ct = 0; ct < 4; ++ct) bf[ct] = *(const short8v*)(lb + bO + ct*2048 + cs1);
    asm volatile("s_waitcnt lgkmcnt(0)" ::: "memory");
    __builtin_amdgcn_sched_barrier(0);
    __builtin_amdgcn_s_barrier();
    if (tt <= 13) STAGE5(tt & 1, tt + 2);
    __builtin_amdgcn_sched_barrier(0);
    __builtin_amdgcn_s_setprio(1);
    #pragma unroll
    for (int ct = 0; ct < 4; ++ct)
      #pragma unroll
      for (int rt = 0; rt < 4; ++rt)
        acc[rt][ct] = __builtin_amdgcn_mfma_f32_16x16x32_bf16(af[rt], bf[ct], acc[rt][ct], 0,0,0);
    __builtin_amdgcn_s_setprio(0);
  }

  // ---- epilogue: per-(row,comp) sum over 16 cols via DPP, out += 0.5*sum ----
  #pragma unroll
  for (int ct = 0; ct < 4; ++ct) {
    const int comp = cb*16 + wn*4 + ct;
    #pragma unroll
    for (int rt = 0; rt < 4; ++rt) {
      #pragma unroll
      for (int j = 0; j < 4; ++j) {
        float v = acc[rt][ct][j];
        float sq = v*v;
        DPPADD(sq, 0xB1);   // quad_perm xor1
        DPPADD(sq, 0x4E);   // quad_perm xor2
        DPPADD(sq, 0x124);  // row_ror:4
        DPPADD(sq, 0x128);  // row_ror:8
        if (lr == 0) {
          int row = n0 + wm*64 + rt*16 + lh*4 + j;
          size_t idx = (size_t)row * KCOMP + comp;
          out[idx] = out[idx] + 0.5f*sq;
        }
      }
    }
  }
}

// ===========================================================================
// Fallback path (round-2 kernels, needs ~4.8 MB ws) — used if ws too small
// ===========================================================================
#define FB_NG 8
#define FB_CG 288
#define FB_BN 128
#define FB_DT 32
#define FB_PITCH 40
#define FB_BMAT_ELEMS ((size_t)(FB_NG*FB_CG)*DF)
#define FB_CST_OFF (FB_BMAT_ELEMS*2)
#define FB_MUH_OFF (FB_CST_OFF + 512)

__global__ __launch_bounds__(256) void fb_pre(
    const float* __restrict__ PI, const float* __restrict__ MU,
    const float* __restrict__ A, const float* __restrict__ Dm,
    ushort_t* __restrict__ Bmat, float* __restrict__ cst, float* __restrict__ muh)
{
  const int k = blockIdx.x, t = threadIdx.x;
  const int tl = t >> 4, tm = t & 15;
  __shared__ float As[16][16], iDsh[16], MUsh[16];
  __shared__ float R[16][17], rinv[16], zsh[16], bsh[16];
  __shared__ float red[256];

  float accL = 0.f, accb = 0.f, slog = 0.f;
  for (int d0 = 0; d0 < DF; d0 += 16) {
    __syncthreads();
    As[tl][tm] = A[((size_t)k*DF + d0 + tl)*LF + tm];
    if (t < 16) {
      float dv = Dm[k*DF + d0 + t];
      iDsh[t] = 1.f/(dv*dv);
      MUsh[t] = MU[k*DF + d0 + t];
    }
    __syncthreads();
    #pragma unroll
    for (int dd = 0; dd < 16; ++dd)
      accL = fmaf(As[dd][tl]*iDsh[dd], As[dd][tm], accL);
    if (tm == 0) {
      #pragma unroll
      for (int dd = 0; dd < 16; ++dd)
        accb = fmaf(iDsh[dd]*MUsh[dd], As[dd][tl], accb);
    }
    if (t < 16) slog += logf(iDsh[t]);
  }
  __syncthreads();
  R[tl][tm] = accL + (tl == tm ? 1.f : 0.f);
  if (tm == 0) bsh[tl] = accb;
  red[t] = (t < 16) ? slog : 0.f;
  __syncthreads();
  float sumlogiD = 0.f;
  if (t == 0) { for (int i = 0; i < 16; ++i) sumlogiD += red[i]; }

  for (int j = 0; j < 16; ++j) {
    if (t == j) {
      float s = R[j][j];
      for (int i = 0; i < j; ++i) s -= R[j][i]*R[j][i];
      float rj = sqrtf(s);
      R[j][j] = rj; rinv[j] = 1.f/rj;
    }
    __syncthreads();
    if (t < 16 && t > j) {
      float s = R[t][j];
      for (int i = 0; i < j; ++i) s -= R[t][i]*R[j][i];
      R[t][j] = s * rinv[j];
    }
    __syncthreads();
  }

  float ldet = 0.f;
  if (t == 0) {
    #pragma unroll
    for (int j = 0; j < 16; ++j) ldet += 2.f*logf(R[j][j]);
    float w[16], z[16];
    #pragma unroll
    for (int j = 0; j < 16; ++j) {
      float s = bsh[j];
      #pragma unroll
      for (int i = 0; i < 16; ++i) if (i < j) s -= R[j][i]*w[i];
      w[j] = s*rinv[j];
    }
    #pragma unroll
    for (int j = 15; j >= 0; --j) {
      float s = w[j];
      #pragma unroll
      for (int i = 0; i < 16; ++i) if (i > j) s -= R[i][j]*z[i];
      z[j] = s*rinv[j];
      zsh[j] = z[j];
    }
  }
  __syncthreads();

  const int g = k >> 4, kl = k & 15;
  ushort_t* Bgp = Bmat + (size_t)g*FB_CG*DF;
  float muhp = 0.f;
  for (int itr = 0; itr < 4; ++itr) {
    int d = t + itr*256;
    float dv = Dm[k*DF + d];
    float iD = 1.f/(dv*dv);
    float mu = MU[k*DF + d];
    float v[16], gg[16];
    #pragma unroll
    for (int l = 0; l < 16; ++l) v[l] = iD * A[((size_t)k*DF + d)*LF + l];
    #pragma unroll
    for (int j = 0; j < 16; ++j) {
      float s = v[j];
      #pragma unroll
      for (int i = 0; i < 16; ++i) if (i < j) s -= R[j][i]*gg[i];
      gg[j] = s * rinv[j];
    }
    float h = iD*mu;
    #pragma unroll
    for (int l = 0; l < 16; ++l) h -= v[l]*zsh[l];
    muhp = fmaf(mu, h, muhp);
    #pragma unroll
    for (int l = 0; l < 16; ++l)
      Bgp[(size_t)(kl*16 + l)*DF + d] = f2bf(gg[l]);
    Bgp[(size_t)(256 + kl)*DF + d] = f2bf(h);
    Bgp[(size_t)(272 + kl)*DF + d] = f2bf(iD);
  }
  red[t] = muhp;
  __syncthreads();
  for (int s = 128; s > 0; s >>= 1) {
    if (t < s) red[t] += red[t + s];
    __syncthreads();
  }
  if (t == 0) {
    muh[k] = red[0];
    cst[k] = PI[k] - 0.5f*((float)DF*LOG2PI + ldet - sumlogiD);
  }
}

__global__ __launch_bounds__(512, 2) void fb_main(
    const float* __restrict__ x, const ushort_t* __restrict__ Bmat,
    const float* __restrict__ cst, const float* __restrict__ muh,
    float* __restrict__ out)
{
  __shared__ __align__(16) ushort_t smem[2*FB_BN*FB_PITCH + FB_CG*FB_PITCH];
  ushort_t* xs  = smem;
  ushort_t* x2s = smem + FB_BN*FB_PITCH;
  ushort_t* Bs  = smem + 2*FB_BN*FB_PITCH;

  const int t = threadIdx.x;
  const int lane = t & 63, wid = t >> 6;
  const int wr = wid & 3, wc = wid >> 2;
  const int lr = lane & 15, lh = lane >> 4;
  const int n0 = blockIdx.x * FB_BN;
  const int g  = blockIdx.y;

  f32x4 acc[2][9] = {};
  const int srow = t >> 2, sc = t & 3;

  int xoff[2];
  #pragma unroll
  for (int rt = 0; rt < 2; ++rt)
    xoff[rt] = (wr*32 + rt*16 + lr)*FB_PITCH + lh*8;
  int boff[9];
  #pragma unroll
  for (int ct = 0; ct < 9; ++ct)
    boff[ct] = (wc*144 + ct*16 + lr)*FB_PITCH + lh*8;

  for (int d0 = 0; d0 < DF; d0 += FB_DT) {
    __syncthreads();
    {
      const float* xp = x + (size_t)(n0 + srow)*DF + d0 + sc*8;
      float4 v0 = *(const float4*)xp;
      float4 v1 = *(const float4*)(xp + 4);
      float e[8] = {v0.x,v0.y,v0.z,v0.w,v1.x,v1.y,v1.z,v1.w};
      short8v xv, qv;
      #pragma unroll
      for (int i = 0; i < 8; ++i) {
        xv[i] = (short)f2bf(e[i]);
        qv[i] = (short)f2bf(e[i]*e[i]);
      }
      *(short8v*)&xs[srow*FB_PITCH + sc*8]  = xv;
      *(short8v*)&x2s[srow*FB_PITCH + sc*8] = qv;
    }
    for (int u = t; u < FB_CG*4; u += 512) {
      int col = u >> 2, c = u & 3;
      *(short8v*)&Bs[col*FB_PITCH + c*8] =
        *(const short8v*)&Bmat[((size_t)(g*FB_CG + col))*DF + d0 + c*8];
    }
    __syncthreads();

    short8v xf[2];
    #pragma unroll
    for (int rt = 0; rt < 2; ++rt) xf[rt] = *(short8v*)&xs[xoff[rt]];
    #pragma unroll
    for (int ct = 0; ct < 8; ++ct) {
      short8v bfr = *(short8v*)&Bs[boff[ct]];
      #pragma unroll
      for (int rt = 0; rt < 2; ++rt)
        acc[rt][ct] = __builtin_amdgcn_mfma_f32_16x16x32_bf16(xf[rt], bfr, acc[rt][ct], 0, 0, 0);
    }
    {
      short8v bfr = *(short8v*)&Bs[boff[8]];
      short8v a0 = xf[0], a1 = xf[1];
      if (wc) {
        a0 = *(short8v*)&x2s[xoff[0]];
        a1 = *(short8v*)&x2s[xoff[1]];
      }
      acc[0][8] = __builtin_amdgcn_mfma_f32_16x16x32_bf16(a0, bfr, acc[0][8], 0, 0, 0);
      acc[1][8] = __builtin_amdgcn_mfma_f32_16x16x32_bf16(a1, bfr, acc[1][8], 0, 0, 0);
    }
  }

  __syncthreads();
  float* s1v = (float*)smem;
  float* s2h = s1v + FB_BN*17;
  if (wc == 1) {
    #pragma unroll
    for (int rt = 0; rt < 2; ++rt)
      #pragma unroll
      for (int j = 0; j < 4; ++j) {
        int row = wr*32 + rt*16 + lh*4 + j;
        s2h[row*17 + lr] = acc[rt][7][j];
        s1v[row*17 + lr] = acc[rt][8][j];
      }
  }
  __syncthreads();

  const int nyt = wc ? 7 : 9;
  #pragma unroll
  for (int ct = 0; ct < 9; ++ct) {
    if (ct < nyt) {
      int comp = wc*9 + ct;
      int kk = g*16 + comp;
      float cstk = cst[kk], muhk = muh[kk];
      #pragma unroll
      for (int rt = 0; rt < 2; ++rt)
        #pragma unroll
        for (int j = 0; j < 4; ++j) {
          float yv = acc[rt][ct][j];
          float sq = yv*yv;
          sq += __shfl_xor(sq, 1);
          sq += __shfl_xor(sq, 2);
          sq += __shfl_xor(sq, 4);
          sq += __shfl_xor(sq, 8);
          int row = wr*32 + rt*16 + lh*4 + j;
          float s1 = s1v[row*17 + comp];
          float s2 = s2h[row*17 + comp];
          float res = cstk - 0.5f*(s1 - sq - 2.f*s2 + muhk);
          if (lr == 0) out[(size_t)(n0 + row)*KCOMP + kk] = res;
        }
    }
  }
}

// ===========================================================================
extern "C" void kernel_launch(void* const* d_in, const int* in_sizes, int n_in,
                              void* d_out, int out_size, void* d_ws, size_t ws_size,
                              hipStream_t stream) {
  const float* x  = (const float*)d_in[0];
  const float* PI = (const float*)d_in[1];
  const float* MU = (const float*)d_in[2];
  const float* A  = (const float*)d_in[3];
  const float* Dm = (const float*)d_in[4];
  float* out = (float*)d_out;

  if (ws_size >= FULL_NEED) {
    ushort_t* xbf = (ushort_t*)((char*)d_ws + XBF_OFF);
    ushort_t* Bg  = (ushort_t*)((char*)d_ws + BG_OFF);
    ushort_t* Bsk = (ushort_t*)((char*)d_ws + BSK_OFF);
    float* pack   = (float*)((char*)d_ws + PACK_OFF);
    float* csk    = (float*)((char*)d_ws + CSK_OFF);

    mfa_pre1<<<dim3(KCOMP), dim3(256), 0, stream>>>(PI, MU, A, Dm, pack, csk);
    mfa_pre2<<<dim3(KCOMP*4), dim3(256), 0, stream>>>(MU, A, Dm, pack, Bg, Bsk);
    mfa_sk2<<<dim3(NPTS/64), dim3(256), 0, stream>>>(x, Bsk, csk, xbf, out);
    mfa_gemm5<<<dim3((NPTS/256)*(2048/256)), dim3(1024), 0, stream>>>(xbf, Bg, out);
  } else {
    ushort_t* Bmat = (ushort_t*)d_ws;
    float* cstp = (float*)((char*)d_ws + FB_CST_OFF);
    float* muhp = (float*)((char*)d_ws + FB_MUH_OFF);
    fb_pre<<<dim3(KCOMP), dim3(256), 0, stream>>>(PI, MU, A, Dm, Bmat, cstp, muhp);
    fb_main<<<dim3(NPTS/FB_BN, FB_NG), dim3(512), 0, stream>>>(x, Bmat, cstp, muhp, out);
  }
}

// Round 7
// 175.131 us; speedup vs baseline: 1.3912x; 1.0000x over previous
//
#include <hip/hip_runtime.h>
#include <math.h>

typedef unsigned short ushort_t;
typedef __attribute__((ext_vector_type(8))) short short8v;
typedef __attribute__((ext_vector_type(4))) float f32x4;

#define KCOMP 128
#define DF    1024
#define LF    16
#define NPTS  16384
#define LOG2PI 1.8378770664093453f

// ---------------- full-path ws layout (bytes) ----------------
#define XBF_OFF   ((size_t)0)
#define XBF_BYTES ((size_t)NPTS*DF*2)            // 33,554,432
#define BG_OFF    (XBF_OFF + XBF_BYTES)
#define BG_BYTES  ((size_t)2048*DF*2)            // 4,194,304
#define BSK_OFF   (BG_OFF + BG_BYTES)
#define BSK_BYTES ((size_t)KCOMP*2*DF*2)         // 524,288
#define PACK_OFF  (BSK_OFF + BSK_BYTES)
#define PACK_BYTES ((size_t)KCOMP*288*4)         // 147,456
#define CSK_OFF   (PACK_OFF + PACK_BYTES)
#define FULL_NEED (CSK_OFF + 512)

__device__ __forceinline__ ushort_t f2bf(float f) {
  union { float f; unsigned u; } v; v.f = f;
  unsigned u = v.u;
  return (ushort_t)((u + 0x7FFFu + ((u >> 16) & 1u)) >> 16);
}

#define GLOAD16(gp, lp) __builtin_amdgcn_global_load_lds( \
  (const __attribute__((address_space(1))) unsigned int*)(gp), \
  (__attribute__((address_space(3))) unsigned int*)(lp), 16, 0, 0)
#define GLOAD16NT(gp, lp) __builtin_amdgcn_global_load_lds( \
  (const __attribute__((address_space(1))) unsigned int*)(gp), \
  (__attribute__((address_space(3))) unsigned int*)(lp), 16, 0, 2)

// DPP reduce-add within 16-lane rows (VALU only, no LDS)
#define DPPADD(x, ctrl) do { \
  int _yi = __builtin_amdgcn_update_dpp(0, __float_as_int(x), ctrl, 0xF, 0xF, true); \
  (x) += __int_as_float(_yi); } while (0)

// ---------------------------------------------------------------------------
// pre1: per-k Lm = I + A^T iD A ; chol ; z ; csk = cst - 0.5*muh ; pack R/rinv/z
// ---------------------------------------------------------------------------
__global__ __launch_bounds__(256) void mfa_pre1(
    const float* __restrict__ PI, const float* __restrict__ MU,
    const float* __restrict__ A, const float* __restrict__ Dm,
    float* __restrict__ pack, float* __restrict__ csk)
{
  const int k = blockIdx.x, t = threadIdx.x;
  const int tl = t >> 4, tm = t & 15;
  __shared__ float As[64][16];
  __shared__ float iD64[64], MU64[64];
  __shared__ float R[16][17];
  __shared__ float rinv_s[16], zsh[16], bsh[16];
  __shared__ float red[64];
  __shared__ float sc_sumlog, sc_c3;

  float accL = 0.f, accb = 0.f, c3p = 0.f, slogp = 0.f;
  for (int ch = 0; ch < 16; ++ch) {
    __syncthreads();
    ((float4*)&As[0][0])[t] =
        ((const float4*)(A + (size_t)k*DF*LF + (size_t)ch*1024))[t];
    if (t < 64) {
      float dv = Dm[k*DF + ch*64 + t];
      iD64[t] = 1.f/(dv*dv);
      MU64[t] = MU[k*DF + ch*64 + t];
    }
    __syncthreads();
    #pragma unroll 4
    for (int dd = 0; dd < 64; ++dd)
      accL = fmaf(As[dd][tl]*iD64[dd], As[dd][tm], accL);
    if (tm == 0)
      for (int dd = 0; dd < 64; ++dd)
        accb = fmaf(iD64[dd]*MU64[dd], As[dd][tl], accb);
    if (t < 64) {
      c3p = fmaf(iD64[t]*MU64[t], MU64[t], c3p);
      slogp += logf(iD64[t]);
    }
  }
  __syncthreads();
  R[tl][tm] = accL + (tl == tm ? 1.f : 0.f);
  if (tm == 0) bsh[tl] = accb;
  if (t < 64) red[t] = slogp;
  __syncthreads();
  if (t == 0) { float s = 0.f; for (int i = 0; i < 64; ++i) s += red[i]; sc_sumlog = s; }
  __syncthreads();
  if (t < 64) red[t] = c3p;
  __syncthreads();
  if (t == 0) { float s = 0.f; for (int i = 0; i < 64; ++i) s += red[i]; sc_c3 = s; }

  for (int j = 0; j < 16; ++j) {
    __syncthreads();
    if (t == j) {
      float s = R[j][j];
      for (int i = 0; i < j; ++i) s -= R[j][i]*R[j][i];
      float rj = sqrtf(s);
      R[j][j] = rj; rinv_s[j] = 1.f/rj;
    }
    __syncthreads();
    if (t < 16 && t > j) {
      float s = R[t][j];
      for (int i = 0; i < j; ++i) s -= R[t][i]*R[j][i];
      R[t][j] = s * rinv_s[j];
    }
  }
  __syncthreads();
  if (t == 0) {
    float ldet = 0.f;
    for (int j = 0; j < 16; ++j) ldet += 2.f*logf(R[j][j]);
    float w[16], z[16];
    for (int j = 0; j < 16; ++j) {
      float s = bsh[j];
      for (int i = 0; i < j; ++i) s -= R[j][i]*w[i];
      w[j] = s*rinv_s[j];
    }
    for (int j = 15; j >= 0; --j) {
      float s = w[j];
      for (int i = j+1; i < 16; ++i) s -= R[i][j]*z[i];
      z[j] = s*rinv_s[j];
      zsh[j] = z[j];
    }
    float muh = sc_c3;
    for (int l = 0; l < 16; ++l) muh -= bsh[l]*zsh[l];
    csk[k] = PI[k] - 0.5f*((float)DF*LOG2PI + ldet - sc_sumlog) - 0.5f*muh;
  }
  __syncthreads();
  pack[(size_t)k*288 + t] = R[tl][tm];
  if (t < 16) {
    pack[(size_t)k*288 + 256 + t] = rinv_s[t];
    pack[(size_t)k*288 + 272 + t] = zsh[t];
  }
}

// ---------------------------------------------------------------------------
// pre2: G = iDA L^{-T}, h = iD*mu - iDA z ; write Bg (bf16) and Bsk [-2h; iD]
// ---------------------------------------------------------------------------
__global__ __launch_bounds__(256) void mfa_pre2(
    const float* __restrict__ MU, const float* __restrict__ A,
    const float* __restrict__ Dm, const float* __restrict__ pack,
    ushort_t* __restrict__ Bg, ushort_t* __restrict__ Bsk)
{
  const int k = blockIdx.x >> 2;
  const int t = threadIdx.x;
  const int d = (blockIdx.x & 3) * 256 + t;
  __shared__ float Rl[16][16], ri[16], zl[16];
  ((float*)Rl)[t] = pack[(size_t)k*288 + t];
  if (t < 16) { ri[t] = pack[(size_t)k*288+256+t]; zl[t] = pack[(size_t)k*288+272+t]; }
  __syncthreads();
  float dv = Dm[k*DF + d];
  float iD = 1.f/(dv*dv);
  float mu = MU[k*DF + d];
  float v[16], gg[16];
  #pragma unroll
  for (int l = 0; l < 16; ++l) v[l] = iD * A[((size_t)k*DF + d)*LF + l];
  #pragma unroll
  for (int j = 0; j < 16; ++j) {
    float s = v[j];
    #pragma unroll
    for (int i = 0; i < 16; ++i) if (i < j) s -= Rl[j][i]*gg[i];
    gg[j] = s * ri[j];
  }
  float h = iD*mu;
  #pragma unroll
  for (int l = 0; l < 16; ++l) h -= v[l]*zl[l];
  #pragma unroll
  for (int l = 0; l < 16; ++l)
    Bg[(size_t)(k*16 + l)*DF + d] = f2bf(gg[l]);
  Bsk[(size_t)k*2*DF + d]      = f2bf(-2.f*h);
  Bsk[(size_t)k*2*DF + DF + d] = f2bf(iD);
}

// ---------------------------------------------------------------------------
// sk3 (race-fixed): per 32-row block: convert x->bf16 (write xbf), x^2 in
// LDS, out[n,c] = csk[c] - 0.5*( x.(-2h) + x^2.iD ).  512 blocks x 256 thr.
// Safe sync: unconditional vmcnt(0)+lgkmcnt(0) drain before the compute
// barrier; next-x prefetch issued AFTER the drain (register-dep tracked by
// compiler -> auto exact wait at next use). No counted vmcnt anywhere.
// ---------------------------------------------------------------------------
__global__ __launch_bounds__(256) void mfa_sk3(
    const float* __restrict__ x, const ushort_t* __restrict__ Bsk,
    const float* __restrict__ csk, ushort_t* __restrict__ xbf,
    float* __restrict__ out)
{
  __shared__ ushort_t xs[2048];    // [32][64] swizzled
  __shared__ ushort_t x2s[2048];
  __shared__ ushort_t Bs[16384];   // [256 vcols][64] swizzled (0-127 h, 128-255 iD)
  const int t = threadIdx.x, lane = t & 63, wid = t >> 6;
  const int wn = wid;              // comp band
  const int lr = lane & 15, lh = lane >> 4;
  const int n0 = blockIdx.x * 32;
  const int xr = t >> 3, xc = t & 7;

  f32x4 acc[2][2] = {};

  // B staging constants: 32 ids of 1KB, 8 ids/wave
  const ushort_t* bsrc[8];
  int bdst[8];
  #pragma unroll
  for (int jj = 0; jj < 8; ++jj) {
    int id = wid*8 + jj;
    int vc = id*8 + (lane >> 3);
    int g = (lane & 7) ^ (vc & 7);
    bsrc[jj] = (vc < 128) ? Bsk + (size_t)vc*2048 + g*8
                          : Bsk + (size_t)(vc-128)*2048 + DF + g*8;
    bdst[jj] = id*1024;
  }

  float4 v0, v1;
  {
    const float* xp = x + (size_t)(n0 + xr)*DF + xc*8;
    v0 = *(const float4*)xp; v1 = *(const float4*)(xp + 4);
  }

  for (int tt = 0; tt < 16; ++tt) {
    const int d0 = tt * 64;
    __builtin_amdgcn_s_barrier();         // prev-iter LDS reads all retired
    // convert + write LDS + xbf plane (compiler auto-waits v0/v1 loads)
    {
      float e[8] = {v0.x,v0.y,v0.z,v0.w,v1.x,v1.y,v1.z,v1.w};
      short8v b, qv;
      #pragma unroll
      for (int i = 0; i < 8; ++i) {
        b[i]  = (short)f2bf(e[i]);
        qv[i] = (short)f2bf(e[i]*e[i]);
      }
      const int ch = xc ^ (xr & 7);
      *(short8v*)&xs[xr*64 + ch*8]  = b;
      *(short8v*)&x2s[xr*64 + ch*8] = qv;
      *(short8v*)&xbf[(size_t)(n0 + xr)*DF + d0 + xc*8] = b;
    }
    // stage B tile (32KB)
    #pragma unroll
    for (int jj = 0; jj < 8; ++jj)
      GLOAD16(bsrc[jj] + d0, (char*)Bs + bdst[jj]);
    // full drain: store + all staging done; nothing younger outstanding
    asm volatile("s_waitcnt vmcnt(0) lgkmcnt(0)" ::: "memory");
    __builtin_amdgcn_s_barrier();
    // prefetch next x AFTER the drain -> stays in flight across the MFMAs;
    // consumed next iteration (compiler inserts the exact wait there)
    if (tt < 15) {
      const float* xp = x + (size_t)(n0 + xr)*DF + (d0 + 64) + xc*8;
      v0 = *(const float4*)xp; v1 = *(const float4*)(xp + 4);
    }
    __builtin_amdgcn_sched_barrier(0);

    #pragma unroll
    for (int ks = 0; ks < 2; ++ks) {
      short8v a_[2], a2_[2], bh[2], bi[2];
      #pragma unroll
      for (int rt = 0; rt < 2; ++rt) {
        int row = rt*16 + lr;
        int cA = ((ks*4 + lh) ^ (row & 7)) * 8;
        a_[rt]  = *(const short8v*)&xs[row*64 + cA];
        a2_[rt] = *(const short8v*)&x2s[row*64 + cA];
      }
      #pragma unroll
      for (int ct = 0; ct < 2; ++ct) {
        int vh = wn*32 + ct*16 + lr;
        int cB = ((ks*4 + lh) ^ (vh & 7)) * 8;
        bh[ct] = *(const short8v*)&Bs[vh*64 + cB];
        int vi = 128 + vh;
        int cB2 = ((ks*4 + lh) ^ (vi & 7)) * 8;
        bi[ct] = *(const short8v*)&Bs[vi*64 + cB2];
      }
      #pragma unroll
      for (int ct = 0; ct < 2; ++ct)
        #pragma unroll
        for (int rt = 0; rt < 2; ++rt) {
          acc[rt][ct] = __builtin_amdgcn_mfma_f32_16x16x32_bf16(a_[rt],  bh[ct], acc[rt][ct], 0,0,0);
          acc[rt][ct] = __builtin_amdgcn_mfma_f32_16x16x32_bf16(a2_[rt], bi[ct], acc[rt][ct], 0,0,0);
        }
    }
  }

  #pragma unroll
  for (int ct = 0; ct < 2; ++ct) {
    int comp = wn*32 + ct*16 + lr;
    float ck = csk[comp];
    #pragma unroll
    for (int rt = 0; rt < 2; ++rt)
      #pragma unroll
      for (int j = 0; j < 4; ++j) {
        int row = n0 + rt*16 + lh*4 + j;
        out[(size_t)row*KCOMP + comp] = ck - 0.5f*acc[rt][ct][j];
      }
  }
}

// ---------------------------------------------------------------------------
// gemm6: out[n,comp] += 0.5 * sum_l y_l^2, y = xbf . Bg^T (16384x2048x1024)
// R5 skeleton + L2-locality: supertiled XCD mapping + nt-policy B staging.
// ---------------------------------------------------------------------------
__global__ __launch_bounds__(1024, 4) void mfa_gemm6(
    const ushort_t* __restrict__ xbf, const ushort_t* __restrict__ Bg,
    float* __restrict__ out)
{
  __shared__ ushort_t smem[65536];   // 128 KiB: 2 slots x [A 32KB | B 32KB]
  const int t = threadIdx.x, lane = t & 63, wid = t >> 6;  // 16 waves
  const int wm = wid & 3, wn = wid >> 2;
  const int lr = lane & 15, lh = lane >> 4;

  // supertiled mapping: xcd(3b) | rs(2b) | cs(2b) | q(2b)
  const int bid = blockIdx.x;            // 512 = 64 rb x 8 cb
  const int xcd = bid & 7, s = bid >> 3;
  const int rs = s >> 4, rem = s & 15;
  const int cs = rem >> 2, q = rem & 3;
  const int rb = xcd*8 + rs*2 + (q >> 1);
  const int cb = cs*2 + (q & 1);
  const int n0 = rb * 256, c0 = cb * 256;

  f32x4 acc[4][4] = {};

  const int rl8 = lane >> 3, j8 = lane & 7;
  const int js8 = (j8 ^ rl8) * 8;        // ushort offset
  const ushort_t* srcP[4]; int dstO[4];
  #pragma unroll
  for (int qq = 0; qq < 4; ++qq) {
    int id = wid*4 + qq;
    if (id < 32) { srcP[qq] = xbf + (size_t)(n0 + id*8 + rl8)*DF + js8; dstO[qq] = id*1024; }
    else         { srcP[qq] = Bg  + (size_t)(c0 + (id-32)*8 + rl8)*DF + js8; dstO[qq] = 32768 + (id-32)*1024; }
  }
  const bool isA = (wid < 8);

  const int aO  = (wm*64 + lr)*128;              // + rt*2048 + cs
  const int bO  = 32768 + (wn*64 + lr)*128;      // + ct*2048 + cs
  const int cs0 = ((0 + lh) ^ (lr & 7))*16;
  const int cs1 = ((4 + lh) ^ (lr & 7))*16;

  #define STAGE6(slot, tt_) do { \
    if (isA) { \
      _Pragma("unroll") \
      for (int qq = 0; qq < 4; ++qq) \
        GLOAD16(srcP[qq] + (tt_)*64, (char*)smem + (slot)*65536 + dstO[qq]); \
    } else { \
      _Pragma("unroll") \
      for (int qq = 0; qq < 4; ++qq) \
        GLOAD16NT(srcP[qq] + (tt_)*64, (char*)smem + (slot)*65536 + dstO[qq]); \
    } \
  } while (0)

  STAGE6(0, 0);
  STAGE6(1, 1);

  for (int tt = 0; tt < 16; ++tt) {
    const char* lb = (const char*)smem + (tt & 1)*65536;
    short8v af[4], bf[4];

    if (tt < 15) asm volatile("s_waitcnt vmcnt(4)" ::: "memory");
    else         asm volatile("s_waitcnt vmcnt(0)" ::: "memory");
    __builtin_amdgcn_s_barrier();

    // phase 0: ks=0
    #pragma unroll
    for (int rt = 0; rt < 4; ++rt) af[rt] = *(const short8v*)(lb + aO + rt*2048 + cs0);
    #pragma unroll
    for (int ct = 0; ct < 4; ++ct) bf[ct] = *(const short8v*)(lb + bO + ct*2048 + cs0);
    asm volatile("s_waitcnt lgkmcnt(0)" ::: "memory");
    __builtin_amdgcn_sched_barrier(0);
    __builtin_amdgcn_s_setprio(1);
    #pragma unroll
    for (int ct = 0; ct < 4; ++ct)
      #pragma unroll
      for (int rt = 0; rt < 4; ++rt)
        acc[rt][ct] = __builtin_amdgcn_mfma_f32_16x16x32_bf16(af[rt], bf[ct], acc[rt][ct], 0,0,0);
    __builtin_amdgcn_s_setprio(0);

    // phase 1: ks=1 ; restage this slot with tile tt+2 after all waves sampled
    #pragma unroll
    for (int rt = 0; rt < 4; ++rt) af[rt] = *(const short8v*)(lb + aO + rt*2048 + cs1);
    #pragma unroll
    for (int ct = 0; ct < 4; ++ct) bf[ct] = *(const short8v*)(lb + bO + ct*2048 + cs1);
    asm volatile("s_waitcnt lgkmcnt(0)" ::: "memory");
    __builtin_amdgcn_sched_barrier(0);
    __builtin_amdgcn_s_barrier();
    if (tt <= 13) STAGE6(tt & 1, tt + 2);
    __builtin_amdgcn_sched_barrier(0);
    __builtin_amdgcn_s_setprio(1);
    #pragma unroll
    for (int ct = 0; ct < 4; ++ct)
      #pragma unroll
      for (int rt = 0; rt < 4; ++rt)
        acc[rt][ct] = __builtin_amdgcn_mfma_f32_16x16x32_bf16(af[rt], bf[ct], acc[rt][ct], 0,0,0);
    __builtin_amdgcn_s_setprio(0);
  }

  // ---- epilogue: per-(row,comp) sum over 16 cols via DPP, out += 0.5*sum ----
  #pragma unroll
  for (int ct = 0; ct < 4; ++ct) {
    const int comp = cb*16 + wn*4 + ct;
    #pragma unroll
    for (int rt = 0; rt < 4; ++rt) {
      #pragma unroll
      for (int j = 0; j < 4; ++j) {
        float v = acc[rt][ct][j];
        float sq = v*v;
        DPPADD(sq, 0xB1);   // quad_perm xor1
        DPPADD(sq, 0x4E);   // quad_perm xor2
        DPPADD(sq, 0x124);  // row_ror:4
        DPPADD(sq, 0x128);  // row_ror:8
        if (lr == 0) {
          int row = n0 + wm*64 + rt*16 + lh*4 + j;
          size_t idx = (size_t)row * KCOMP + comp;
          out[idx] = out[idx] + 0.5f*sq;
        }
      }
    }
  }
}

// ===========================================================================
// Fallback path (round-2 kernels, needs ~4.8 MB ws) — used if ws too small
// ===========================================================================
#define FB_NG 8
#define FB_CG 288
#define FB_BN 128
#define FB_DT 32
#define FB_PITCH 40
#define FB_BMAT_ELEMS ((size_t)(FB_NG*FB_CG)*DF)
#define FB_CST_OFF (FB_BMAT_ELEMS*2)
#define FB_MUH_OFF (FB_CST_OFF + 512)

__global__ __launch_bounds__(256) void fb_pre(
    const float* __restrict__ PI, const float* __restrict__ MU,
    const float* __restrict__ A, const float* __restrict__ Dm,
    ushort_t* __restrict__ Bmat, float* __restrict__ cst, float* __restrict__ muh)
{
  const int k = blockIdx.x, t = threadIdx.x;
  const int tl = t >> 4, tm = t & 15;
  __shared__ float As[16][16], iDsh[16], MUsh[16];
  __shared__ float R[16][17], rinv[16], zsh[16], bsh[16];
  __shared__ float red[256];

  float accL = 0.f, accb = 0.f, slog = 0.f;
  for (int d0 = 0; d0 < DF; d0 += 16) {
    __syncthreads();
    As[tl][tm] = A[((size_t)k*DF + d0 + tl)*LF + tm];
    if (t < 16) {
      float dv = Dm[k*DF + d0 + t];
      iDsh[t] = 1.f/(dv*dv);
      MUsh[t] = MU[k*DF + d0 + t];
    }
    __syncthreads();
    #pragma unroll
    for (int dd = 0; dd < 16; ++dd)
      accL = fmaf(As[dd][tl]*iDsh[dd], As[dd][tm], accL);
    if (tm == 0) {
      #pragma unroll
      for (int dd = 0; dd < 16; ++dd)
        accb = fmaf(iDsh[dd]*MUsh[dd], As[dd][tl], accb);
    }
    if (t < 16) slog += logf(iDsh[t]);
  }
  __syncthreads();
  R[tl][tm] = accL + (tl == tm ? 1.f : 0.f);
  if (tm == 0) bsh[tl] = accb;
  red[t] = (t < 16) ? slog : 0.f;
  __syncthreads();
  float sumlogiD = 0.f;
  if (t == 0) { for (int i = 0; i < 16; ++i) sumlogiD += red[i]; }

  for (int j = 0; j < 16; ++j) {
    if (t == j) {
      float s = R[j][j];
      for (int i = 0; i < j; ++i) s -= R[j][i]*R[j][i];
      float rj = sqrtf(s);
      R[j][j] = rj; rinv[j] = 1.f/rj;
    }
    __syncthreads();
    if (t < 16 && t > j) {
      float s = R[t][j];
      for (int i = 0; i < j; ++i) s -= R[t][i]*R[j][i];
      R[t][j] = s * rinv[j];
    }
    __syncthreads();
  }

  float ldet = 0.f;
  if (t == 0) {
    #pragma unroll
    for (int j = 0; j < 16; ++j) ldet += 2.f*logf(R[j][j]);
    float w[16], z[16];
    #pragma unroll
    for (int j = 0; j < 16; ++j) {
      float s = bsh[j];
      #pragma unroll
      for (int i = 0; i < 16; ++i) if (i < j) s -= R[j][i]*w[i];
      w[j] = s*rinv[j];
    }
    #pragma unroll
    for (int j = 15; j >= 0; --j) {
      float s = w[j];
      #pragma unroll
      for (int i = 0; i < 16; ++i) if (i > j) s -= R[i][j]*z[i];
      z[j] = s*rinv[j];
      zsh[j] = z[j];
    }
  }
  __syncthreads();

  const int g = k >> 4, kl = k & 15;
  ushort_t* Bgp = Bmat + (size_t)g*FB_CG*DF;
  float muhp = 0.f;
  for (int itr = 0; itr < 4; ++itr) {
    int d = t + itr*256;
    float dv = Dm[k*DF + d];
    float iD = 1.f/(dv*dv);
    float mu = MU[k*DF + d];
    float v[16], gg[16];
    #pragma unroll
    for (int l = 0; l < 16; ++l) v[l] = iD * A[((size_t)k*DF + d)*LF + l];
    #pragma unroll
    for (int j = 0; j < 16; ++j) {
      float s = v[j];
      #pragma unroll
      for (int i = 0; i < 16; ++i) if (i < j) s -= R[j][i]*gg[i];
      gg[j] = s * rinv[j];
    }
    float h = iD*mu;
    #pragma unroll
    for (int l = 0; l < 16; ++l) h -= v[l]*zsh[l];
    muhp = fmaf(mu, h, muhp);
    #pragma unroll
    for (int l = 0; l < 16; ++l)
      Bgp[(size_t)(kl*16 + l)*DF + d] = f2bf(gg[l]);
    Bgp[(size_t)(256 + kl)*DF + d] = f2bf(h);
    Bgp[(size_t)(272 + kl)*DF + d] = f2bf(iD);
  }
  red[t] = muhp;
  __syncthreads();
  for (int s = 128; s > 0; s >>= 1) {
    if (t < s) red[t] += red[t + s];
    __syncthreads();
  }
  if (t == 0) {
    muh[k] = red[0];
    cst[k] = PI[k] - 0.5f*((float)DF*LOG2PI + ldet - sumlogiD);
  }
}

__global__ __launch_bounds__(512, 2) void fb_main(
    const float* __restrict__ x, const ushort_t* __restrict__ Bmat,
    const float* __restrict__ cst, const float* __restrict__ muh,
    float* __restrict__ out)
{
  __shared__ __align__(16) ushort_t smem[2*FB_BN*FB_PITCH + FB_CG*FB_PITCH];
  ushort_t* xs  = smem;
  ushort_t* x2s = smem + FB_BN*FB_PITCH;
  ushort_t* Bs  = smem + 2*FB_BN*FB_PITCH;

  const int t = threadIdx.x;
  const int lane = t & 63, wid = t >> 6;
  const int wr = wid & 3, wc = wid >> 2;
  const int lr = lane & 15, lh = lane >> 4;
  const int n0 = blockIdx.x * FB_BN;
  const int g  = blockIdx.y;

  f32x4 acc[2][9] = {};
  const int srow = t >> 2, sc = t & 3;

  int xoff[2];
  #pragma unroll
  for (int rt = 0; rt < 2; ++rt)
    xoff[rt] = (wr*32 + rt*16 + lr)*FB_PITCH + lh*8;
  int boff[9];
  #pragma unroll
  for (int ct = 0; ct < 9; ++ct)
    boff[ct] = (wc*144 + ct*16 + lr)*FB_PITCH + lh*8;

  for (int d0 = 0; d0 < DF; d0 += FB_DT) {
    __syncthreads();
    {
      const float* xp = x + (size_t)(n0 + srow)*DF + d0 + sc*8;
      float4 v0 = *(const float4*)xp;
      float4 v1 = *(const float4*)(xp + 4);
      float e[8] = {v0.x,v0.y,v0.z,v0.w,v1.x,v1.y,v1.z,v1.w};
      short8v xv, qv;
      #pragma unroll
      for (int i = 0; i < 8; ++i) {
        xv[i] = (short)f2bf(e[i]);
        qv[i] = (short)f2bf(e[i]*e[i]);
      }
      *(short8v*)&xs[srow*FB_PITCH + sc*8]  = xv;
      *(short8v*)&x2s[srow*FB_PITCH + sc*8] = qv;
    }
    for (int u = t; u < FB_CG*4; u += 512) {
      int col = u >> 2, c = u & 3;
      *(short8v*)&Bs[col*FB_PITCH + c*8] =
        *(const short8v*)&Bmat[((size_t)(g*FB_CG + col))*DF + d0 + c*8];
    }
    __syncthreads();

    short8v xf[2];
    #pragma unroll
    for (int rt = 0; rt < 2; ++rt) xf[rt] = *(short8v*)&xs[xoff[rt]];
    #pragma unroll
    for (int ct = 0; ct < 8; ++ct) {
      short8v bfr = *(short8v*)&Bs[boff[ct]];
      #pragma unroll
      for (int rt = 0; rt < 2; ++rt)
        acc[rt][ct] = __builtin_amdgcn_mfma_f32_16x16x32_bf16(xf[rt], bfr, acc[rt][ct], 0, 0, 0);
    }
    {
      short8v bfr = *(short8v*)&Bs[boff[8]];
      short8v a0 = xf[0], a1 = xf[1];
      if (wc) {
        a0 = *(short8v*)&x2s[xoff[0]];
        a1 = *(short8v*)&x2s[xoff[1]];
      }
      acc[0][8] = __builtin_amdgcn_mfma_f32_16x16x32_bf16(a0, bfr, acc[0][8], 0, 0, 0);
      acc[1][8] = __builtin_amdgcn_mfma_f32_16x16x32_bf16(a1, bfr, acc[1][8], 0, 0, 0);
    }
  }

  __syncthreads();
  float* s1v = (float*)smem;
  float* s2h = s1v + FB_BN*17;
  if (wc == 1) {
    #pragma unroll
    for (int rt = 0; rt < 2; ++rt)
      #pragma unroll
      for (int j = 0; j < 4; ++j) {
        int row = wr*32 + rt*16 + lh*4 + j;
        s2h[row*17 + lr] = acc[rt][7][j];
        s1v[row*17 + lr] = acc[rt][8][j];
      }
  }
  __syncthreads();

  const int nyt = wc ? 7 : 9;
  #pragma unroll
  for (int ct = 0; ct < 9; ++ct) {
    if (ct < nyt) {
      int comp = wc*9 + ct;
      int kk = g*16 + comp;
      float cstk = cst[kk], muhk = muh[kk];
      #pragma unroll
      for (int rt = 0; rt < 2; ++rt)
        #pragma unroll
        for (int j = 0; j < 4; ++j) {
          float yv = acc[rt][ct][j];
          float sq = yv*yv;
          sq += __shfl_xor(sq, 1);
          sq += __shfl_xor(sq, 2);
          sq += __shfl_xor(sq, 4);
          sq += __shfl_xor(sq, 8);
          int row = wr*32 + rt*16 + lh*4 + j;
          float s1 = s1v[row*17 + comp];
          float s2 = s2h[row*17 + comp];
          float res = cstk - 0.5f*(s1 - sq - 2.f*s2 + muhk);
          if (lr == 0) out[(size_t)(n0 + row)*KCOMP + kk] = res;
        }
    }
  }
}

// ===========================================================================
extern "C" void kernel_launch(void* const* d_in, const int* in_sizes, int n_in,
                              void* d_out, int out_size, void* d_ws, size_t ws_size,
                              hipStream_t stream) {
  const float* x  = (const float*)d_in[0];
  const float* PI = (const float*)d_in[1];
  const float* MU = (const float*)d_in[2];
  const float* A  = (const float*)d_in[3];
  const float* Dm = (const float*)d_in[4];
  float* out = (float*)d_out;

  if (ws_size >= FULL_NEED) {
    ushort_t* xbf = (ushort_t*)((char*)d_ws + XBF_OFF);
    ushort_t* Bg  = (ushort_t*)((char*)d_ws + BG_OFF);
    ushort_t* Bsk = (ushort_t*)((char*)d_ws + BSK_OFF);
    float* pack   = (float*)((char*)d_ws + PACK_OFF);
    float* csk    = (float*)((char*)d_ws + CSK_OFF);

    mfa_pre1<<<dim3(KCOMP), dim3(256), 0, stream>>>(PI, MU, A, Dm, pack, csk);
    mfa_pre2<<<dim3(KCOMP*4), dim3(256), 0, stream>>>(MU, A, Dm, pack, Bg, Bsk);
    mfa_sk3<<<dim3(NPTS/32), dim3(256), 0, stream>>>(x, Bsk, csk, xbf, out);
    mfa_gemm6<<<dim3((NPTS/256)*(2048/256)), dim3(1024), 0, stream>>>(xbf, Bg, out);
  } else {
    ushort_t* Bmat = (ushort_t*)d_ws;
    float* cstp = (float*)((char*)d_ws + FB_CST_OFF);
    float* muhp = (float*)((char*)d_ws + FB_MUH_OFF);
    fb_pre<<<dim3(KCOMP), dim3(256), 0, stream>>>(PI, MU, A, Dm, Bmat, cstp, muhp);
    fb_main<<<dim3(NPTS/FB_BN, FB_NG), dim3(512), 0, stream>>>(x, Bmat, cstp, muhp, out);
  }
}

// Round 8
// 172.688 us; speedup vs baseline: 1.4109x; 1.0141x over previous
//
#include <hip/hip_runtime.h>
#include <math.h>

typedef unsigned short ushort_t;
typedef unsigned char  uchar_t;
typedef __attribute__((ext_vector_type(8))) short short8v;
typedef __attribute__((ext_vector_type(4))) float f32x4;

#define KCOMP 128
#define DF    1024
#define LF    16
#define NPTS  16384
#define LOG2PI 1.8378770664093453f

// ---------------- full-path ws layout (bytes) ----------------
#define XQ_OFF    ((size_t)0)
#define XQ_BYTES  ((size_t)NPTS*DF)              // 16,777,216 fp8
#define BQ_OFF    (XQ_OFF + XQ_BYTES)
#define BQ_BYTES  ((size_t)2048*DF)              // 2,097,152 fp8
#define BSK_OFF   (BQ_OFF + BQ_BYTES)
#define BSK_BYTES ((size_t)KCOMP*2*DF*2)         // 524,288 bf16
#define PACK_OFF  (BSK_OFF + BSK_BYTES)
#define PACK_BYTES ((size_t)KCOMP*288*4)         // 147,456
#define CSK_OFF   (PACK_OFF + PACK_BYTES)
#define FULL_NEED (CSK_OFF + 512)

__device__ __forceinline__ ushort_t f2bf(float f) {
  union { float f; unsigned u; } v; v.f = f;
  unsigned u = v.u;
  return (ushort_t)((u + 0x7FFFu + ((u >> 16) & 1u)) >> 16);
}

#define GLOAD16(gp, lp) __builtin_amdgcn_global_load_lds( \
  (const __attribute__((address_space(1))) unsigned int*)(gp), \
  (__attribute__((address_space(3))) unsigned int*)(lp), 16, 0, 0)

// DPP reduce-add within 16-lane rows (VALU only, no LDS)
#define DPPADD(x, ctrl) do { \
  int _yi = __builtin_amdgcn_update_dpp(0, __float_as_int(x), ctrl, 0xF, 0xF, true); \
  (x) += __int_as_float(_yi); } while (0)

// ---------------------------------------------------------------------------
// pre1: per-k Lm = I + A^T iD A ; chol ; z ; csk = cst - 0.5*muh ; pack R/rinv/z
// ---------------------------------------------------------------------------
__global__ __launch_bounds__(256) void mfa_pre1(
    const float* __restrict__ PI, const float* __restrict__ MU,
    const float* __restrict__ A, const float* __restrict__ Dm,
    float* __restrict__ pack, float* __restrict__ csk)
{
  const int k = blockIdx.x, t = threadIdx.x;
  const int tl = t >> 4, tm = t & 15;
  __shared__ float As[64][16];
  __shared__ float iD64[64], MU64[64];
  __shared__ float R[16][17];
  __shared__ float rinv_s[16], zsh[16], bsh[16];
  __shared__ float red[64];
  __shared__ float sc_sumlog, sc_c3;

  float accL = 0.f, accb = 0.f, c3p = 0.f, slogp = 0.f;
  for (int ch = 0; ch < 16; ++ch) {
    __syncthreads();
    ((float4*)&As[0][0])[t] =
        ((const float4*)(A + (size_t)k*DF*LF + (size_t)ch*1024))[t];
    if (t < 64) {
      float dv = Dm[k*DF + ch*64 + t];
      iD64[t] = 1.f/(dv*dv);
      MU64[t] = MU[k*DF + ch*64 + t];
    }
    __syncthreads();
    #pragma unroll 4
    for (int dd = 0; dd < 64; ++dd)
      accL = fmaf(As[dd][tl]*iD64[dd], As[dd][tm], accL);
    if (tm == 0)
      for (int dd = 0; dd < 64; ++dd)
        accb = fmaf(iD64[dd]*MU64[dd], As[dd][tl], accb);
    if (t < 64) {
      c3p = fmaf(iD64[t]*MU64[t], MU64[t], c3p);
      slogp += logf(iD64[t]);
    }
  }
  __syncthreads();
  R[tl][tm] = accL + (tl == tm ? 1.f : 0.f);
  if (tm == 0) bsh[tl] = accb;
  if (t < 64) red[t] = slogp;
  __syncthreads();
  if (t == 0) { float s = 0.f; for (int i = 0; i < 64; ++i) s += red[i]; sc_sumlog = s; }
  __syncthreads();
  if (t < 64) red[t] = c3p;
  __syncthreads();
  if (t == 0) { float s = 0.f; for (int i = 0; i < 64; ++i) s += red[i]; sc_c3 = s; }

  for (int j = 0; j < 16; ++j) {
    __syncthreads();
    if (t == j) {
      float s = R[j][j];
      for (int i = 0; i < j; ++i) s -= R[j][i]*R[j][i];
      float rj = sqrtf(s);
      R[j][j] = rj; rinv_s[j] = 1.f/rj;
    }
    __syncthreads();
    if (t < 16 && t > j) {
      float s = R[t][j];
      for (int i = 0; i < j; ++i) s -= R[t][i]*R[j][i];
      R[t][j] = s * rinv_s[j];
    }
  }
  __syncthreads();
  if (t == 0) {
    float ldet = 0.f;
    for (int j = 0; j < 16; ++j) ldet += 2.f*logf(R[j][j]);
    float w[16], z[16];
    for (int j = 0; j < 16; ++j) {
      float s = bsh[j];
      for (int i = 0; i < j; ++i) s -= R[j][i]*w[i];
      w[j] = s*rinv_s[j];
    }
    for (int j = 15; j >= 0; --j) {
      float s = w[j];
      for (int i = j+1; i < 16; ++i) s -= R[i][j]*z[i];
      z[j] = s*rinv_s[j];
      zsh[j] = z[j];
    }
    float muh = sc_c3;
    for (int l = 0; l < 16; ++l) muh -= bsh[l]*zsh[l];
    csk[k] = PI[k] - 0.5f*((float)DF*LOG2PI + ldet - sc_sumlog) - 0.5f*muh;
  }
  __syncthreads();
  pack[(size_t)k*288 + t] = R[tl][tm];
  if (t < 16) {
    pack[(size_t)k*288 + 256 + t] = rinv_s[t];
    pack[(size_t)k*288 + 272 + t] = zsh[t];
  }
}

// ---------------------------------------------------------------------------
// pre2: G = iDA L^{-T}, h = iD*mu - iDA z ; write Bq (fp8 e4m3, d-contig)
// and Bsk [-2h; iD] (bf16)
// ---------------------------------------------------------------------------
__global__ __launch_bounds__(256) void mfa_pre2(
    const float* __restrict__ MU, const float* __restrict__ A,
    const float* __restrict__ Dm, const float* __restrict__ pack,
    uchar_t* __restrict__ Bq, ushort_t* __restrict__ Bsk)
{
  const int k = blockIdx.x >> 2;
  const int t = threadIdx.x;
  const int d = (blockIdx.x & 3) * 256 + t;
  __shared__ float Rl[16][16], ri[16], zl[16];
  ((float*)Rl)[t] = pack[(size_t)k*288 + t];
  if (t < 16) { ri[t] = pack[(size_t)k*288+256+t]; zl[t] = pack[(size_t)k*288+272+t]; }
  __syncthreads();
  float dv = Dm[k*DF + d];
  float iD = 1.f/(dv*dv);
  float mu = MU[k*DF + d];
  float v[16], gg[16];
  #pragma unroll
  for (int l = 0; l < 16; ++l) v[l] = iD * A[((size_t)k*DF + d)*LF + l];
  #pragma unroll
  for (int j = 0; j < 16; ++j) {
    float s = v[j];
    #pragma unroll
    for (int i = 0; i < 16; ++i) if (i < j) s -= Rl[j][i]*gg[i];
    gg[j] = s * ri[j];
  }
  float h = iD*mu;
  #pragma unroll
  for (int l = 0; l < 16; ++l) h -= v[l]*zl[l];
  #pragma unroll
  for (int l = 0; l < 16; ++l) {
    int r8 = __builtin_amdgcn_cvt_pk_fp8_f32(gg[l], gg[l], 0, false);
    Bq[(size_t)(k*16 + l)*DF + d] = (uchar_t)(r8 & 0xFF);
  }
  Bsk[(size_t)k*2*DF + d]      = f2bf(-2.f*h);
  Bsk[(size_t)k*2*DF + DF + d] = f2bf(iD);
}

// ---------------------------------------------------------------------------
// sk2q: per 64-row block: convert x -> fp8 (write xq plane) + bf16 x/x^2 in
// LDS; out[n,c] = csk[c] - 0.5*( x.(-2h) + x^2.iD ) over K=1024 each (bf16).
// 256 thr = 4 col-waves; wave: 64 rows x 32 comps. Conservative __syncthreads.
// ---------------------------------------------------------------------------
__global__ __launch_bounds__(256) void mfa_sk2q(
    const float* __restrict__ x, const ushort_t* __restrict__ Bsk,
    const float* __restrict__ csk, uchar_t* __restrict__ xq,
    float* __restrict__ out)
{
  __shared__ ushort_t xs[4096];     // [64][64] swizzled
  __shared__ ushort_t x2s[4096];
  __shared__ ushort_t Bs[16384];    // [256 vcols][64] swizzled (0-127 h, 128-255 iD)
  const int t = threadIdx.x, lane = t & 63, wid = t >> 6;
  const int wc = wid;
  const int lr = lane & 15, lh = lane >> 4;
  const int n0 = blockIdx.x * 64;
  const int xr = t >> 2, xc = t & 3;

  f32x4 acc[4][2] = {};

  for (int tt = 0; tt < 16; ++tt) {
    const int d0 = tt * 64;
    __syncthreads();
    // ---- stage x (fp32 -> bf16 + bf16^2 in LDS; fp8 plane to xq) ----
    {
      const float* xp = x + (size_t)(n0 + xr)*DF + d0 + xc*16;
      float4 v0 = ((const float4*)xp)[0];
      float4 v1 = ((const float4*)xp)[1];
      float4 v2 = ((const float4*)xp)[2];
      float4 v3 = ((const float4*)xp)[3];
      float e[16] = {v0.x,v0.y,v0.z,v0.w, v1.x,v1.y,v1.z,v1.w,
                     v2.x,v2.y,v2.z,v2.w, v3.x,v3.y,v3.z,v3.w};
      short8v b0, b1, q0, q1;
      #pragma unroll
      for (int i = 0; i < 8; ++i) {
        b0[i] = (short)f2bf(e[i]);     q0[i] = (short)f2bf(e[i]*e[i]);
        b1[i] = (short)f2bf(e[8+i]);   q1[i] = (short)f2bf(e[8+i]*e[8+i]);
      }
      const int ch0 = (xc*2) ^ (xr & 7), ch1 = (xc*2+1) ^ (xr & 7);
      *(short8v*)&xs[xr*64 + ch0*8]  = b0;
      *(short8v*)&xs[xr*64 + ch1*8]  = b1;
      *(short8v*)&x2s[xr*64 + ch0*8] = q0;
      *(short8v*)&x2s[xr*64 + ch1*8] = q1;
      // fp8 pack (e4m3, RNE, saturating) -> 16 bytes
      int p0 = 0, p1 = 0, p2 = 0, p3 = 0;
      p0 = __builtin_amdgcn_cvt_pk_fp8_f32(e[0],  e[1],  p0, false);
      p0 = __builtin_amdgcn_cvt_pk_fp8_f32(e[2],  e[3],  p0, true);
      p1 = __builtin_amdgcn_cvt_pk_fp8_f32(e[4],  e[5],  p1, false);
      p1 = __builtin_amdgcn_cvt_pk_fp8_f32(e[6],  e[7],  p1, true);
      p2 = __builtin_amdgcn_cvt_pk_fp8_f32(e[8],  e[9],  p2, false);
      p2 = __builtin_amdgcn_cvt_pk_fp8_f32(e[10], e[11], p2, true);
      p3 = __builtin_amdgcn_cvt_pk_fp8_f32(e[12], e[13], p3, false);
      p3 = __builtin_amdgcn_cvt_pk_fp8_f32(e[14], e[15], p3, true);
      int4 pk; pk.x = p0; pk.y = p1; pk.z = p2; pk.w = p3;
      *(int4*)&xq[(size_t)(n0 + xr)*DF + d0 + xc*16] = pk;
    }
    // ---- stage B (both parts) via global_load_lds ----
    #pragma unroll
    for (int j = 0; j < 8; ++j) {
      int v = (wid*8 + j)*8 + (lane >> 3);
      int g = (lane & 7) ^ (v & 7);
      const ushort_t* src = (v < 128)
        ? Bsk + (size_t)v*(2*DF) + d0 + g*8
        : Bsk + (size_t)(v - 128)*(2*DF) + DF + d0 + g*8;
      GLOAD16(src, (char*)Bs + (wid*8 + j)*1024);
    }
    __syncthreads();
    // ---- compute ----
    #pragma unroll
    for (int ks = 0; ks < 2; ++ks) {
      const int cterm = ((ks*4 + lh) ^ (lr & 7)) * 8;
      short8v a_[4], a2_[4], bh[2], bi[2];
      #pragma unroll
      for (int rb = 0; rb < 4; ++rb) {
        a_[rb]  = *(const short8v*)&xs[(rb*16 + lr)*64 + cterm];
        a2_[rb] = *(const short8v*)&x2s[(rb*16 + lr)*64 + cterm];
      }
      #pragma unroll
      for (int cb = 0; cb < 2; ++cb) {
        int vh = wc*32 + cb*16 + lr;
        bh[cb] = *(const short8v*)&Bs[vh*64 + cterm];
        bi[cb] = *(const short8v*)&Bs[(128 + vh)*64 + cterm];
      }
      #pragma unroll
      for (int cb = 0; cb < 2; ++cb)
        #pragma unroll
        for (int rb = 0; rb < 4; ++rb) {
          acc[rb][cb] = __builtin_amdgcn_mfma_f32_16x16x32_bf16(a_[rb],  bh[cb], acc[rb][cb], 0,0,0);
          acc[rb][cb] = __builtin_amdgcn_mfma_f32_16x16x32_bf16(a2_[rb], bi[cb], acc[rb][cb], 0,0,0);
        }
    }
  }
  // ---- epilogue: out = csk - 0.5*dot ----
  #pragma unroll
  for (int cb = 0; cb < 2; ++cb) {
    int comp = wc*32 + cb*16 + lr;
    float ck = csk[comp];
    #pragma unroll
    for (int rb = 0; rb < 4; ++rb)
      #pragma unroll
      for (int j = 0; j < 4; ++j) {
        int row = n0 + rb*16 + lh*4 + j;
        out[(size_t)row*KCOMP + comp] = ck - 0.5f*acc[rb][cb][j];
      }
  }
}

// ---------------------------------------------------------------------------
// gemm7: out[n,comp] += 0.5 * sum_l y_l^2, y = xq . Bq^T  (fp8 e4m3, fp32 acc)
// 16384x2048x1024. Block 256x256, BK=64 (fp8 bytes), 16 K-tiles, 1024 thr =
// 16 waves (4Mx4N), wave 64x64 (acc 4x4). LDS 64KB (2 slots x (A16K|B16K)).
// 2-deep prefetch, counted vmcnt(2), b64 LDS reads, XOR-((row>>1)&3) swizzle.
// fp8 halves staged bytes -> per-XCD A-slice 2MB + B 2MB = L2-resident.
// ---------------------------------------------------------------------------
__global__ __launch_bounds__(1024, 4) void mfa_gemm7(
    const uchar_t* __restrict__ xq, const uchar_t* __restrict__ Bq,
    float* __restrict__ out)
{
  __shared__ uchar_t smem[65536];   // 2 slots x 32KB
  const int t = threadIdx.x, lane = t & 63, wid = t >> 6;  // 16 waves
  const int wm = wid & 3, wn = wid >> 2;
  const int lr = lane & 15, lh = lane >> 4;

  const int bid = blockIdx.x;            // 512 = 64 rb x 8 cb
  const int xcd = bid & 7, ib = bid >> 3;
  const int rb = xcd*8 + (ib >> 3);      // XCD owns 8 contiguous row-bands
  const int cb = ib & 7;
  const int n0 = rb * 256, c0 = cb * 256;

  f32x4 acc[4][4] = {};

  // staging: 32 x 1KB instrs per tile (A ids 0..15, B ids 16..31), 2/wave.
  // instr covers 16 rows x 64B; lane l: row = id*16 + (l>>2), dst chunk l&3,
  // src chunk = (l&3) ^ ((row>>1)&3) = (l&3) ^ ((l>>3)&3).
  const int js = (((lane & 3) ^ ((lane >> 3) & 3)) * 16);
  const uchar_t* srcP[2]; int dstO[2];
  #pragma unroll
  for (int q = 0; q < 2; ++q) {
    int id = wid*2 + q;
    if (id < 16) {
      int r = id*16 + (lane >> 2);
      srcP[q] = xq + (size_t)(n0 + r)*DF + js;
      dstO[q] = id*1024;
    } else {
      int cr = (id - 16)*16 + (lane >> 2);
      srcP[q] = Bq + (size_t)(c0 + cr)*DF + js;
      dstO[q] = 16384 + (id - 16)*1024;
    }
  }

  const int aBase = (wm*64 + lr)*64;             // + rt*1024 + cs_[ks]
  const int bBase = 16384 + (wn*64 + lr)*64;     // + ct*1024 + cs_[ks]
  const int swzr = (lr >> 1) & 3;
  const int cs_0 = (((0*2 + (lh>>1)) ^ swzr)*16) + (lh & 1)*8;
  const int cs_1 = (((1*2 + (lh>>1)) ^ swzr)*16) + (lh & 1)*8;

  #define STAGE7(slot, tt_) do { \
    _Pragma("unroll") \
    for (int q = 0; q < 2; ++q) \
      GLOAD16(srcP[q] + (tt_)*64, (char*)smem + (slot)*32768 + dstO[q]); \
  } while (0)

  STAGE7(0, 0);
  STAGE7(1, 1);

  for (int tt = 0; tt < 16; ++tt) {
    const char* lb = (const char*)smem + (tt & 1)*32768;
    long aL[4], bL[4];

    if (tt < 15) asm volatile("s_waitcnt vmcnt(2)" ::: "memory");
    else         asm volatile("s_waitcnt vmcnt(0)" ::: "memory");
    __builtin_amdgcn_s_barrier();

    // phase 0: ks=0
    #pragma unroll
    for (int rt = 0; rt < 4; ++rt) aL[rt] = *(const long*)(lb + aBase + rt*1024 + cs_0);
    #pragma unroll
    for (int ct = 0; ct < 4; ++ct) bL[ct] = *(const long*)(lb + bBase + ct*1024 + cs_0);
    asm volatile("s_waitcnt lgkmcnt(0)" ::: "memory");
    __builtin_amdgcn_sched_barrier(0);
    __builtin_amdgcn_s_setprio(1);
    #pragma unroll
    for (int ct = 0; ct < 4; ++ct)
      #pragma unroll
      for (int rt = 0; rt < 4; ++rt)
        acc[rt][ct] = __builtin_amdgcn_mfma_f32_16x16x32_fp8_fp8(aL[rt], bL[ct], acc[rt][ct], 0,0,0);
    __builtin_amdgcn_s_setprio(0);

    // phase 1: ks=1 ; restage this slot with tile tt+2 after all waves read
    #pragma unroll
    for (int rt = 0; rt < 4; ++rt) aL[rt] = *(const long*)(lb + aBase + rt*1024 + cs_1);
    #pragma unroll
    for (int ct = 0; ct < 4; ++ct) bL[ct] = *(const long*)(lb + bBase + ct*1024 + cs_1);
    asm volatile("s_waitcnt lgkmcnt(0)" ::: "memory");
    __builtin_amdgcn_sched_barrier(0);
    __builtin_amdgcn_s_barrier();
    if (tt <= 13) STAGE7(tt & 1, tt + 2);
    __builtin_amdgcn_sched_barrier(0);
    __builtin_amdgcn_s_setprio(1);
    #pragma unroll
    for (int ct = 0; ct < 4; ++ct)
      #pragma unroll
      for (int rt = 0; rt < 4; ++rt)
        acc[rt][ct] = __builtin_amdgcn_mfma_f32_16x16x32_fp8_fp8(aL[rt], bL[ct], acc[rt][ct], 0,0,0);
    __builtin_amdgcn_s_setprio(0);
  }

  // ---- epilogue: per-(row,comp) sum over 16 cols via DPP, out += 0.5*sum ----
  #pragma unroll
  for (int ct = 0; ct < 4; ++ct) {
    const int comp = cb*16 + wn*4 + ct;
    #pragma unroll
    for (int rt = 0; rt < 4; ++rt) {
      #pragma unroll
      for (int j = 0; j < 4; ++j) {
        float v = acc[rt][ct][j];
        float sq = v*v;
        DPPADD(sq, 0xB1);   // quad_perm xor1
        DPPADD(sq, 0x4E);   // quad_perm xor2
        DPPADD(sq, 0x124);  // row_ror:4
        DPPADD(sq, 0x128);  // row_ror:8
        if (lr == 0) {
          int row = n0 + wm*64 + rt*16 + lh*4 + j;
          size_t idx = (size_t)row * KCOMP + comp;
          out[idx] = out[idx] + 0.5f*sq;
        }
      }
    }
  }
}

// ===========================================================================
// Fallback path (round-2 kernels, needs ~4.8 MB ws) — used if ws too small
// ===========================================================================
#define FB_NG 8
#define FB_CG 288
#define FB_BN 128
#define FB_DT 32
#define FB_PITCH 40
#define FB_BMAT_ELEMS ((size_t)(FB_NG*FB_CG)*DF)
#define FB_CST_OFF (FB_BMAT_ELEMS*2)
#define FB_MUH_OFF (FB_CST_OFF + 512)

__global__ __launch_bounds__(256) void fb_pre(
    const float* __restrict__ PI, const float* __restrict__ MU,
    const float* __restrict__ A, const float* __restrict__ Dm,
    ushort_t* __restrict__ Bmat, float* __restrict__ cst, float* __restrict__ muh)
{
  const int k = blockIdx.x, t = threadIdx.x;
  const int tl = t >> 4, tm = t & 15;
  __shared__ float As[16][16], iDsh[16], MUsh[16];
  __shared__ float R[16][17], rinv[16], zsh[16], bsh[16];
  __shared__ float red[256];

  float accL = 0.f, accb = 0.f, slog = 0.f;
  for (int d0 = 0; d0 < DF; d0 += 16) {
    __syncthreads();
    As[tl][tm] = A[((size_t)k*DF + d0 + tl)*LF + tm];
    if (t < 16) {
      float dv = Dm[k*DF + d0 + t];
      iDsh[t] = 1.f/(dv*dv);
      MUsh[t] = MU[k*DF + d0 + t];
    }
    __syncthreads();
    #pragma unroll
    for (int dd = 0; dd < 16; ++dd)
      accL = fmaf(As[dd][tl]*iDsh[dd], As[dd][tm], accL);
    if (tm == 0) {
      #pragma unroll
      for (int dd = 0; dd < 16; ++dd)
        accb = fmaf(iDsh[dd]*MUsh[dd], As[dd][tl], accb);
    }
    if (t < 16) slog += logf(iDsh[t]);
  }
  __syncthreads();
  R[tl][tm] = accL + (tl == tm ? 1.f : 0.f);
  if (tm == 0) bsh[tl] = accb;
  red[t] = (t < 16) ? slog : 0.f;
  __syncthreads();
  float sumlogiD = 0.f;
  if (t == 0) { for (int i = 0; i < 16; ++i) sumlogiD += red[i]; }

  for (int j = 0; j < 16; ++j) {
    if (t == j) {
      float s = R[j][j];
      for (int i = 0; i < j; ++i) s -= R[j][i]*R[j][i];
      float rj = sqrtf(s);
      R[j][j] = rj; rinv[j] = 1.f/rj;
    }
    __syncthreads();
    if (t < 16 && t > j) {
      float s = R[t][j];
      for (int i = 0; i < j; ++i) s -= R[t][i]*R[j][i];
      R[t][j] = s * rinv[j];
    }
    __syncthreads();
  }

  float ldet = 0.f;
  if (t == 0) {
    #pragma unroll
    for (int j = 0; j < 16; ++j) ldet += 2.f*logf(R[j][j]);
    float w[16], z[16];
    #pragma unroll
    for (int j = 0; j < 16; ++j) {
      float s = bsh[j];
      #pragma unroll
      for (int i = 0; i < 16; ++i) if (i < j) s -= R[j][i]*w[i];
      w[j] = s*rinv[j];
    }
    #pragma unroll
    for (int j = 15; j >= 0; --j) {
      float s = w[j];
      #pragma unroll
      for (int i = 0; i < 16; ++i) if (i > j) s -= R[i][j]*z[i];
      z[j] = s*rinv[j];
      zsh[j] = z[j];
    }
  }
  __syncthreads();

  const int g = k >> 4, kl = k & 15;
  ushort_t* Bgp = Bmat + (size_t)g*FB_CG*DF;
  float muhp = 0.f;
  for (int itr = 0; itr < 4; ++itr) {
    int d = t + itr*256;
    float dv = Dm[k*DF + d];
    float iD = 1.f/(dv*dv);
    float mu = MU[k*DF + d];
    float v[16], gg[16];
    #pragma unroll
    for (int l = 0; l < 16; ++l) v[l] = iD * A[((size_t)k*DF + d)*LF + l];
    #pragma unroll
    for (int j = 0; j < 16; ++j) {
      float s = v[j];
      #pragma unroll
      for (int i = 0; i < 16; ++i) if (i < j) s -= R[j][i]*gg[i];
      gg[j] = s * rinv[j];
    }
    float h = iD*mu;
    #pragma unroll
    for (int l = 0; l < 16; ++l) h -= v[l]*zsh[l];
    muhp = fmaf(mu, h, muhp);
    #pragma unroll
    for (int l = 0; l < 16; ++l)
      Bgp[(size_t)(kl*16 + l)*DF + d] = f2bf(gg[l]);
    Bgp[(size_t)(256 + kl)*DF + d] = f2bf(h);
    Bgp[(size_t)(272 + kl)*DF + d] = f2bf(iD);
  }
  red[t] = muhp;
  __syncthreads();
  for (int s = 128; s > 0; s >>= 1) {
    if (t < s) red[t] += red[t + s];
    __syncthreads();
  }
  if (t == 0) {
    muh[k] = red[0];
    cst[k] = PI[k] - 0.5f*((float)DF*LOG2PI + ldet - sumlogiD);
  }
}

__global__ __launch_bounds__(512, 2) void fb_main(
    const float* __restrict__ x, const ushort_t* __restrict__ Bmat,
    const float* __restrict__ cst, const float* __restrict__ muh,
    float* __restrict__ out)
{
  __shared__ __align__(16) ushort_t smem[2*FB_BN*FB_PITCH + FB_CG*FB_PITCH];
  ushort_t* xs  = smem;
  ushort_t* x2s = smem + FB_BN*FB_PITCH;
  ushort_t* Bs  = smem + 2*FB_BN*FB_PITCH;

  const int t = threadIdx.x;
  const int lane = t & 63, wid = t >> 6;
  const int wr = wid & 3, wc = wid >> 2;
  const int lr = lane & 15, lh = lane >> 4;
  const int n0 = blockIdx.x * FB_BN;
  const int g  = blockIdx.y;

  f32x4 acc[2][9] = {};
  const int srow = t >> 2, sc = t & 3;

  int xoff[2];
  #pragma unroll
  for (int rt = 0; rt < 2; ++rt)
    xoff[rt] = (wr*32 + rt*16 + lr)*FB_PITCH + lh*8;
  int boff[9];
  #pragma unroll
  for (int ct = 0; ct < 9; ++ct)
    boff[ct] = (wc*144 + ct*16 + lr)*FB_PITCH + lh*8;

  for (int d0 = 0; d0 < DF; d0 += FB_DT) {
    __syncthreads();
    {
      const float* xp = x + (size_t)(n0 + srow)*DF + d0 + sc*8;
      float4 v0 = *(const float4*)xp;
      float4 v1 = *(const float4*)(xp + 4);
      float e[8] = {v0.x,v0.y,v0.z,v0.w,v1.x,v1.y,v1.z,v1.w};
      short8v xv, qv;
      #pragma unroll
      for (int i = 0; i < 8; ++i) {
        xv[i] = (short)f2bf(e[i]);
        qv[i] = (short)f2bf(e[i]*e[i]);
      }
      *(short8v*)&xs[srow*FB_PITCH + sc*8]  = xv;
      *(short8v*)&x2s[srow*FB_PITCH + sc*8] = qv;
    }
    for (int u = t; u < FB_CG*4; u += 512) {
      int col = u >> 2, c = u & 3;
      *(short8v*)&Bs[col*FB_PITCH + c*8] =
        *(const short8v*)&Bmat[((size_t)(g*FB_CG + col))*DF + d0 + c*8];
    }
    __syncthreads();

    short8v xf[2];
    #pragma unroll
    for (int rt = 0; rt < 2; ++rt) xf[rt] = *(short8v*)&xs[xoff[rt]];
    #pragma unroll
    for (int ct = 0; ct < 8; ++ct) {
      short8v bfr = *(short8v*)&Bs[boff[ct]];
      #pragma unroll
      for (int rt = 0; rt < 2; ++rt)
        acc[rt][ct] = __builtin_amdgcn_mfma_f32_16x16x32_bf16(xf[rt], bfr, acc[rt][ct], 0, 0, 0);
    }
    {
      short8v bfr = *(short8v*)&Bs[boff[8]];
      short8v a0 = xf[0], a1 = xf[1];
      if (wc) {
        a0 = *(short8v*)&x2s[xoff[0]];
        a1 = *(short8v*)&x2s[xoff[1]];
      }
      acc[0][8] = __builtin_amdgcn_mfma_f32_16x16x32_bf16(a0, bfr, acc[0][8], 0, 0, 0);
      acc[1][8] = __builtin_amdgcn_mfma_f32_16x16x32_bf16(a1, bfr, acc[1][8], 0, 0, 0);
    }
  }

  __syncthreads();
  float* s1v = (float*)smem;
  float* s2h = s1v + FB_BN*17;
  if (wc == 1) {
    #pragma unroll
    for (int rt = 0; rt < 2; ++rt)
      #pragma unroll
      for (int j = 0; j < 4; ++j) {
        int row = wr*32 + rt*16 + lh*4 + j;
        s2h[row*17 + lr] = acc[rt][7][j];
        s1v[row*17 + lr] = acc[rt][8][j];
      }
  }
  __syncthreads();

  const int nyt = wc ? 7 : 9;
  #pragma unroll
  for (int ct = 0; ct < 9; ++ct) {
    if (ct < nyt) {
      int comp = wc*9 + ct;
      int kk = g*16 + comp;
      float cstk = cst[kk], muhk = muh[kk];
      #pragma unroll
      for (int rt = 0; rt < 2; ++rt)
        #pragma unroll
        for (int j = 0; j < 4; ++j) {
          float yv = acc[rt][ct][j];
          float sq = yv*yv;
          sq += __shfl_xor(sq, 1);
          sq += __shfl_xor(sq, 2);
          sq += __shfl_xor(sq, 4);
          sq += __shfl_xor(sq, 8);
          int row = wr*32 + rt*16 + lh*4 + j;
          float s1 = s1v[row*17 + comp];
          float s2 = s2h[row*17 + comp];
          float res = cstk - 0.5f*(s1 - sq - 2.f*s2 + muhk);
          if (lr == 0) out[(size_t)(n0 + row)*KCOMP + kk] = res;
        }
    }
  }
}

// ===========================================================================
extern "C" void kernel_launch(void* const* d_in, const int* in_sizes, int n_in,
                              void* d_out, int out_size, void* d_ws, size_t ws_size,
                              hipStream_t stream) {
  const float* x  = (const float*)d_in[0];
  const float* PI = (const float*)d_in[1];
  const float* MU = (const float*)d_in[2];
  const float* A  = (const float*)d_in[3];
  const float* Dm = (const float*)d_in[4];
  float* out = (float*)d_out;

  if (ws_size >= FULL_NEED) {
    uchar_t* xq   = (uchar_t*)((char*)d_ws + XQ_OFF);
    uchar_t* Bq   = (uchar_t*)((char*)d_ws + BQ_OFF);
    ushort_t* Bsk = (ushort_t*)((char*)d_ws + BSK_OFF);
    float* pack   = (float*)((char*)d_ws + PACK_OFF);
    float* csk    = (float*)((char*)d_ws + CSK_OFF);

    mfa_pre1<<<dim3(KCOMP), dim3(256), 0, stream>>>(PI, MU, A, Dm, pack, csk);
    mfa_pre2<<<dim3(KCOMP*4), dim3(256), 0, stream>>>(MU, A, Dm, pack, Bq, Bsk);
    mfa_sk2q<<<dim3(NPTS/64), dim3(256), 0, stream>>>(x, Bsk, csk, xq, out);
    mfa_gemm7<<<dim3((NPTS/256)*(2048/256)), dim3(1024), 0, stream>>>(xq, Bq, out);
  } else {
    ushort_t* Bmat = (ushort_t*)d_ws;
    float* cstp = (float*)((char*)d_ws + FB_CST_OFF);
    float* muhp = (float*)((char*)d_ws + FB_MUH_OFF);
    fb_pre<<<dim3(KCOMP), dim3(256), 0, stream>>>(PI, MU, A, Dm, Bmat, cstp, muhp);
    fb_main<<<dim3(NPTS/FB_BN, FB_NG), dim3(512), 0, stream>>>(x, Bmat, cstp, muhp, out);
  }
}

// Round 9
// 157.940 us; speedup vs baseline: 1.5427x; 1.0934x over previous
//
#include <hip/hip_runtime.h>
#include <math.h>

typedef unsigned short ushort_t;
typedef unsigned char  uchar_t;
typedef __attribute__((ext_vector_type(8))) short short8v;
typedef __attribute__((ext_vector_type(4))) float f32x4;
typedef __attribute__((ext_vector_type(2))) long l64x2;

#define KCOMP 128
#define DF    1024
#define LF    16
#define NPTS  16384
#define LOG2PI 1.8378770664093453f

// ---------------- full-path ws layout (bytes) ----------------
#define XQ_OFF    ((size_t)0)
#define XQ_BYTES  ((size_t)NPTS*DF)              // 16,777,216 fp8 (K-permuted)
#define BQ_OFF    (XQ_OFF + XQ_BYTES)
#define BQ_BYTES  ((size_t)2048*DF)              // 2,097,152 fp8 (K-permuted)
#define BSK_OFF   (BQ_OFF + BQ_BYTES)
#define BSK_BYTES ((size_t)KCOMP*2*DF*2)         // 524,288 bf16
#define CSK_OFF   (BSK_OFF + BSK_BYTES)
#define FULL_NEED (CSK_OFF + 512)

__device__ __forceinline__ ushort_t f2bf(float f) {
  union { float f; unsigned u; } v; v.f = f;
  unsigned u = v.u;
  return (ushort_t)((u + 0x7FFFu + ((u >> 16) & 1u)) >> 16);
}

#define GLOAD16(gp, lp) __builtin_amdgcn_global_load_lds( \
  (const __attribute__((address_space(1))) unsigned int*)(gp), \
  (__attribute__((address_space(3))) unsigned int*)(lp), 16, 0, 0)

// DPP reduce-add within 16-lane rows (VALU only, no LDS)
#define DPPADD(x, ctrl) do { \
  int _yi = __builtin_amdgcn_update_dpp(0, __float_as_int(x), ctrl, 0xF, 0xF, true); \
  (x) += __int_as_float(_yi); } while (0)

// ---------------------------------------------------------------------------
// pre (merged pre1+pre2): per component k:
//   Lm = I + A^T iD A ; chol R ; z = Lm^{-1} b ; csk = PI - 0.5*(logdet + muh)
//   then per d: G = iDA R^{-T} col-solve, h = iD*mu - iDA z ->
//   Bq fp8 (K-permuted: within each 64B tile, byte (ks*32+lh*8+b) stored at
//   (lh*16+ks*8+b)) and Bsk bf16 [-2h ; iD].
// ---------------------------------------------------------------------------
__global__ __launch_bounds__(256) void mfa_pre(
    const float* __restrict__ PI, const float* __restrict__ MU,
    const float* __restrict__ A, const float* __restrict__ Dm,
    uchar_t* __restrict__ Bq, ushort_t* __restrict__ Bsk,
    float* __restrict__ csk)
{
  const int k = blockIdx.x, t = threadIdx.x;
  const int tl = t >> 4, tm = t & 15;
  __shared__ float As[64][16];
  __shared__ float iD64[64], MU64[64];
  __shared__ float R[16][17];
  __shared__ float rinv_s[16], zsh[16], bsh[16];
  __shared__ float red[64];
  __shared__ float sc_sumlog, sc_c3;

  float accL = 0.f, accb = 0.f, c3p = 0.f, slogp = 0.f;
  for (int ch = 0; ch < 16; ++ch) {
    __syncthreads();
    ((float4*)&As[0][0])[t] =
        ((const float4*)(A + (size_t)k*DF*LF + (size_t)ch*1024))[t];
    if (t < 64) {
      float dv = Dm[k*DF + ch*64 + t];
      iD64[t] = 1.f/(dv*dv);
      MU64[t] = MU[k*DF + ch*64 + t];
    }
    __syncthreads();
    #pragma unroll 4
    for (int dd = 0; dd < 64; ++dd)
      accL = fmaf(As[dd][tl]*iD64[dd], As[dd][tm], accL);
    if (tm == 0)
      for (int dd = 0; dd < 64; ++dd)
        accb = fmaf(iD64[dd]*MU64[dd], As[dd][tl], accb);
    if (t < 64) {
      c3p = fmaf(iD64[t]*MU64[t], MU64[t], c3p);
      slogp += logf(iD64[t]);
    }
  }
  __syncthreads();
  R[tl][tm] = accL + (tl == tm ? 1.f : 0.f);
  if (tm == 0) bsh[tl] = accb;
  if (t < 64) red[t] = slogp;
  __syncthreads();
  if (t == 0) { float s = 0.f; for (int i = 0; i < 64; ++i) s += red[i]; sc_sumlog = s; }
  __syncthreads();
  if (t < 64) red[t] = c3p;
  __syncthreads();
  if (t == 0) { float s = 0.f; for (int i = 0; i < 64; ++i) s += red[i]; sc_c3 = s; }

  // Cholesky (lower), SPD diag-dominant
  for (int j = 0; j < 16; ++j) {
    __syncthreads();
    if (t == j) {
      float s = R[j][j];
      for (int i = 0; i < j; ++i) s -= R[j][i]*R[j][i];
      float rj = sqrtf(s);
      R[j][j] = rj; rinv_s[j] = 1.f/rj;
    }
    __syncthreads();
    if (t < 16 && t > j) {
      float s = R[t][j];
      for (int i = 0; i < j; ++i) s -= R[t][i]*R[j][i];
      R[t][j] = s * rinv_s[j];
    }
  }
  __syncthreads();
  if (t == 0) {
    float ldet = 0.f;
    for (int j = 0; j < 16; ++j) ldet += 2.f*logf(R[j][j]);
    float w[16], z[16];
    for (int j = 0; j < 16; ++j) {
      float s = bsh[j];
      for (int i = 0; i < j; ++i) s -= R[j][i]*w[i];
      w[j] = s*rinv_s[j];
    }
    for (int j = 15; j >= 0; --j) {
      float s = w[j];
      for (int i = j+1; i < 16; ++i) s -= R[i][j]*z[i];
      z[j] = s*rinv_s[j];
      zsh[j] = z[j];
    }
    float muh = sc_c3;
    for (int l = 0; l < 16; ++l) muh -= bsh[l]*zsh[l];
    csk[k] = PI[k] - 0.5f*((float)DF*LOG2PI + ldet - sc_sumlog) - 0.5f*muh;
  }
  __syncthreads();

  // per-d G/h/iD outputs (4 x 256 d's)
  for (int it = 0; it < 4; ++it) {
    const int d = t + it*256;
    float dv = Dm[k*DF + d];
    float iD = 1.f/(dv*dv);
    float mu = MU[k*DF + d];
    float v[16], gg[16];
    #pragma unroll
    for (int l = 0; l < 16; ++l) v[l] = iD * A[((size_t)k*DF + d)*LF + l];
    #pragma unroll
    for (int j = 0; j < 16; ++j) {
      float s = v[j];
      #pragma unroll
      for (int i = 0; i < 16; ++i) if (i < j) s -= R[j][i]*gg[i];
      gg[j] = s * rinv_s[j];
    }
    float h = iD*mu;
    #pragma unroll
    for (int l = 0; l < 16; ++l) h -= v[l]*zsh[l];
    // K-permuted byte position within the 64B tile
    const int dd = d & 63;
    const size_t poff = (size_t)(d & ~63) + ((dd >> 3) & 3)*16 + (dd >> 5)*8 + (dd & 7);
    #pragma unroll
    for (int l = 0; l < 16; ++l) {
      int r8 = __builtin_amdgcn_cvt_pk_fp8_f32(gg[l], gg[l], 0, false);
      Bq[(size_t)(k*16 + l)*DF + poff] = (uchar_t)(r8 & 0xFF);
    }
    Bsk[(size_t)k*2*DF + d]      = f2bf(-2.f*h);
    Bsk[(size_t)k*2*DF + DF + d] = f2bf(iD);
  }
}

// ---------------------------------------------------------------------------
// sk2q: per 64-row block: convert x -> fp8 (write K-permuted xq plane) +
// bf16 x/x^2 in LDS; out[n,c] = csk[c] - 0.5*( x.(-2h) + x^2.iD )  (bf16 MFMA).
// x-register prefetch across the MFMA phase (sk3-verified safe pattern).
// ---------------------------------------------------------------------------
__global__ __launch_bounds__(256) void mfa_sk2q(
    const float* __restrict__ x, const ushort_t* __restrict__ Bsk,
    const float* __restrict__ csk, uchar_t* __restrict__ xq,
    float* __restrict__ out)
{
  __shared__ ushort_t xs[4096];     // [64][64] swizzled
  __shared__ ushort_t x2s[4096];
  __shared__ ushort_t Bs[16384];    // [256 vcols][64] swizzled (0-127 h, 128-255 iD)
  const int t = threadIdx.x, lane = t & 63, wid = t >> 6;
  const int wc = wid;
  const int lr = lane & 15, lh = lane >> 4;
  const int n0 = blockIdx.x * 64;
  const int xr = t >> 2, xc = t & 3;

  f32x4 acc[4][2] = {};

  float4 v0, v1, v2, v3;
  {
    const float* xp = x + (size_t)(n0 + xr)*DF + xc*16;
    v0 = ((const float4*)xp)[0]; v1 = ((const float4*)xp)[1];
    v2 = ((const float4*)xp)[2]; v3 = ((const float4*)xp)[3];
  }

  for (int tt = 0; tt < 16; ++tt) {
    const int d0 = tt * 64;
    __syncthreads();
    // ---- convert prefetched x (fp32 -> bf16 + bf16^2 LDS; fp8 perm plane) ----
    {
      float e[16] = {v0.x,v0.y,v0.z,v0.w, v1.x,v1.y,v1.z,v1.w,
                     v2.x,v2.y,v2.z,v2.w, v3.x,v3.y,v3.z,v3.w};
      short8v b0, b1, q0, q1;
      #pragma unroll
      for (int i = 0; i < 8; ++i) {
        b0[i] = (short)f2bf(e[i]);     q0[i] = (short)f2bf(e[i]*e[i]);
        b1[i] = (short)f2bf(e[8+i]);   q1[i] = (short)f2bf(e[8+i]*e[8+i]);
      }
      const int ch0 = (xc*2) ^ (xr & 7), ch1 = (xc*2+1) ^ (xr & 7);
      *(short8v*)&xs[xr*64 + ch0*8]  = b0;
      *(short8v*)&xs[xr*64 + ch1*8]  = b1;
      *(short8v*)&x2s[xr*64 + ch0*8] = q0;
      *(short8v*)&x2s[xr*64 + ch1*8] = q1;
      // fp8 pack (e4m3, saturating) -> two 8B groups, K-permuted positions
      int p0 = 0, p1 = 0, p2 = 0, p3 = 0;
      p0 = __builtin_amdgcn_cvt_pk_fp8_f32(e[0],  e[1],  p0, false);
      p0 = __builtin_amdgcn_cvt_pk_fp8_f32(e[2],  e[3],  p0, true);
      p1 = __builtin_amdgcn_cvt_pk_fp8_f32(e[4],  e[5],  p1, false);
      p1 = __builtin_amdgcn_cvt_pk_fp8_f32(e[6],  e[7],  p1, true);
      p2 = __builtin_amdgcn_cvt_pk_fp8_f32(e[8],  e[9],  p2, false);
      p2 = __builtin_amdgcn_cvt_pk_fp8_f32(e[10], e[11], p2, true);
      p3 = __builtin_amdgcn_cvt_pk_fp8_f32(e[12], e[13], p3, false);
      p3 = __builtin_amdgcn_cvt_pk_fp8_f32(e[14], e[15], p3, true);
      long lo = (long)(((unsigned long long)(unsigned)p1 << 32) | (unsigned)p0);
      long hi = (long)(((unsigned long long)(unsigned)p3 << 32) | (unsigned)p2);
      size_t base = (size_t)(n0 + xr)*DF + d0 + (xc & 1)*32 + (xc >> 1)*8;
      *(long*)&xq[base]      = lo;
      *(long*)&xq[base + 16] = hi;
    }
    // ---- stage B (both parts) via global_load_lds ----
    #pragma unroll
    for (int j = 0; j < 8; ++j) {
      int v = (wid*8 + j)*8 + (lane >> 3);
      int g = (lane & 7) ^ (v & 7);
      const ushort_t* src = (v < 128)
        ? Bsk + (size_t)v*(2*DF) + d0 + g*8
        : Bsk + (size_t)(v - 128)*(2*DF) + DF + d0 + g*8;
      GLOAD16(src, (char*)Bs + (wid*8 + j)*1024);
    }
    __syncthreads();
    // prefetch next x chunk (in flight across MFMAs; consumed next iter)
    if (tt < 15) {
      const float* xp = x + (size_t)(n0 + xr)*DF + (d0 + 64) + xc*16;
      v0 = ((const float4*)xp)[0]; v1 = ((const float4*)xp)[1];
      v2 = ((const float4*)xp)[2]; v3 = ((const float4*)xp)[3];
    }
    __builtin_amdgcn_sched_barrier(0);
    // ---- compute ----
    #pragma unroll
    for (int ks = 0; ks < 2; ++ks) {
      const int cterm = ((ks*4 + lh) ^ (lr & 7)) * 8;
      short8v a_[4], a2_[4], bh[2], bi[2];
      #pragma unroll
      for (int rb = 0; rb < 4; ++rb) {
        a_[rb]  = *(const short8v*)&xs[(rb*16 + lr)*64 + cterm];
        a2_[rb] = *(const short8v*)&x2s[(rb*16 + lr)*64 + cterm];
      }
      #pragma unroll
      for (int cb = 0; cb < 2; ++cb) {
        int vh = wc*32 + cb*16 + lr;
        bh[cb] = *(const short8v*)&Bs[vh*64 + cterm];
        bi[cb] = *(const short8v*)&Bs[(128 + vh)*64 + cterm];
      }
      #pragma unroll
      for (int cb = 0; cb < 2; ++cb)
        #pragma unroll
        for (int rb = 0; rb < 4; ++rb) {
          acc[rb][cb] = __builtin_amdgcn_mfma_f32_16x16x32_bf16(a_[rb],  bh[cb], acc[rb][cb], 0,0,0);
          acc[rb][cb] = __builtin_amdgcn_mfma_f32_16x16x32_bf16(a2_[rb], bi[cb], acc[rb][cb], 0,0,0);
        }
    }
  }
  // ---- epilogue ----
  #pragma unroll
  for (int cb = 0; cb < 2; ++cb) {
    int comp = wc*32 + cb*16 + lr;
    float ck = csk[comp];
    #pragma unroll
    for (int rb = 0; rb < 4; ++rb)
      #pragma unroll
      for (int j = 0; j < 4; ++j) {
        int row = n0 + rb*16 + lh*4 + j;
        out[(size_t)row*KCOMP + comp] = ck - 0.5f*acc[rb][cb][j];
      }
  }
}

// ---------------------------------------------------------------------------
// gemm8: out[n,comp] += 0.5 * sum_l y_l^2 ; y = xq . Bq^T (fp8 e4m3, f32 acc)
// 16384x2048x1024. 256x256 tile, BK=64, 1024 thr = 16 waves (4Mx4N), wave
// 64x64 (acc 4x4). LDS 64KB (2 slots x (A16K|B16K)). K-permuted storage ->
// one b128 read = both K-step fragments. Conflict-free swizzle:
// src chunk (lane&3)^((lane>>3)&3), read chunk lh^((lr>>1)&3).
// Single-phase K-tile: gate vmcnt(2) | barrier | 8 reads | lgkm(0) | barrier
// | restage(tt+2) | 32 MFMA.
// ---------------------------------------------------------------------------
__global__ __launch_bounds__(1024, 4) void mfa_gemm8(
    const uchar_t* __restrict__ xq, const uchar_t* __restrict__ Bq,
    float* __restrict__ out)
{
  __shared__ uchar_t smem[65536];   // 2 slots x 32KB
  const int t = threadIdx.x, lane = t & 63, wid = t >> 6;  // 16 waves
  const int wm = wid & 3, wn = wid >> 2;
  const int lr = lane & 15, lh = lane >> 4;

  const int bid = blockIdx.x;            // 512 = 64 rb x 8 cb
  const int xcd = bid & 7, ib = bid >> 3;
  const int rb = xcd*8 + (ib >> 3);      // XCD owns 8 contiguous row-bands
  const int cb = ib & 7;
  const int n0 = rb * 256, c0 = cb * 256;

  f32x4 acc[4][4] = {};

  // staging: 32 x 1KB instrs per K-tile (A ids 0..15, B ids 16..31), 2/wave.
  // instr covers 16 rows x 64B; lane: r_local = lane>>2, dst chunk = lane&3,
  // src chunk = (lane&3) ^ ((lane>>3)&3)   [= (r_local>>1)&3]
  const int js = (((lane & 3) ^ ((lane >> 3) & 3)) * 16);
  const uchar_t* srcP[2]; int dstO[2];
  #pragma unroll
  for (int q = 0; q < 2; ++q) {
    int id = wid*2 + q;
    if (id < 16) {
      int r = id*16 + (lane >> 2);
      srcP[q] = xq + (size_t)(n0 + r)*DF + js;
      dstO[q] = id*1024 + (lane & 3)*16 + (lane >> 2)*64 - (lane)*16; // placeholder, fixed below
    } else {
      int cr = (id - 16)*16 + (lane >> 2);
      srcP[q] = Bq + (size_t)(c0 + cr)*DF + js;
    }
  }
  // linear dest: id*1024 + lane*16 (= row*64 + chunk*16)
  dstO[0] = (wid*2 + 0) < 16 ? (wid*2+0)*1024 : 16384 + ((wid*2+0)-16)*1024;
  dstO[1] = (wid*2 + 1) < 16 ? (wid*2+1)*1024 : 16384 + ((wid*2+1)-16)*1024;

  // read offsets: row*64 + (lh ^ ((lr>>1)&3))*16 ; one b128 = ks0|ks1
  const int rsw = (lh ^ ((lr >> 1) & 3)) * 16;
  const int aO = (wm*64 + lr)*64 + rsw;            // + rt*1024
  const int bO = 16384 + (wn*64 + lr)*64 + rsw;    // + ct*1024

  #define STAGE8(slot, tt_) do { \
    _Pragma("unroll") \
    for (int q = 0; q < 2; ++q) \
      GLOAD16(srcP[q] + (tt_)*64, (char*)smem + (slot)*32768 + dstO[q] + (lane & 63)*0 + ((lane)*16 & 1023)); \
  } while (0)

  STAGE8(0, 0);
  STAGE8(1, 1);

  for (int tt = 0; tt < 16; ++tt) {
    const char* lb = (const char*)smem + (tt & 1)*32768;
    l64x2 a2[4], b2[4];

    if (tt < 15) asm volatile("s_waitcnt vmcnt(2)" ::: "memory");
    else         asm volatile("s_waitcnt vmcnt(0)" ::: "memory");
    __builtin_amdgcn_s_barrier();

    #pragma unroll
    for (int rt = 0; rt < 4; ++rt) a2[rt] = *(const l64x2*)(lb + aO + rt*1024);
    #pragma unroll
    for (int ct = 0; ct < 4; ++ct) b2[ct] = *(const l64x2*)(lb + bO + ct*1024);
    asm volatile("s_waitcnt lgkmcnt(0)" ::: "memory");
    __builtin_amdgcn_sched_barrier(0);
    __builtin_amdgcn_s_barrier();           // all waves done reading this slot
    if (tt <= 13) STAGE8(tt & 1, tt + 2);   // overwrite overlaps MFMAs
    __builtin_amdgcn_sched_barrier(0);

    __builtin_amdgcn_s_setprio(1);
    #pragma unroll
    for (int ct = 0; ct < 4; ++ct)
      #pragma unroll
      for (int rt = 0; rt < 4; ++rt)
        acc[rt][ct] = __builtin_amdgcn_mfma_f32_16x16x32_fp8_fp8(a2[rt][0], b2[ct][0], acc[rt][ct], 0,0,0);
    #pragma unroll
    for (int ct = 0; ct < 4; ++ct)
      #pragma unroll
      for (int rt = 0; rt < 4; ++rt)
        acc[rt][ct] = __builtin_amdgcn_mfma_f32_16x16x32_fp8_fp8(a2[rt][1], b2[ct][1], acc[rt][ct], 0,0,0);
    __builtin_amdgcn_s_setprio(0);
  }

  // ---- epilogue: per-(row,comp) sum over 16 cols via DPP, out += 0.5*sum ----
  #pragma unroll
  for (int ct = 0; ct < 4; ++ct) {
    const int comp = cb*16 + wn*4 + ct;
    #pragma unroll
    for (int rt = 0; rt < 4; ++rt) {
      #pragma unroll
      for (int j = 0; j < 4; ++j) {
        float v = acc[rt][ct][j];
        float sq = v*v;
        DPPADD(sq, 0xB1);   // quad_perm xor1
        DPPADD(sq, 0x4E);   // quad_perm xor2
        DPPADD(sq, 0x124);  // row_ror:4
        DPPADD(sq, 0x128);  // row_ror:8
        if (lr == 0) {
          int row = n0 + wm*64 + rt*16 + lh*4 + j;
          size_t idx = (size_t)row * KCOMP + comp;
          out[idx] = out[idx] + 0.5f*sq;
        }
      }
    }
  }
}

// ===========================================================================
// Fallback path (round-2 kernels, needs ~4.8 MB ws) — used if ws too small
// ===========================================================================
#define FB_NG 8
#define FB_CG 288
#define FB_BN 128
#define FB_DT 32
#define FB_PITCH 40
#define FB_BMAT_ELEMS ((size_t)(FB_NG*FB_CG)*DF)
#define FB_CST_OFF (FB_BMAT_ELEMS*2)
#define FB_MUH_OFF (FB_CST_OFF + 512)

__global__ __launch_bounds__(256) void fb_pre(
    const float* __restrict__ PI, const float* __restrict__ MU,
    const float* __restrict__ A, const float* __restrict__ Dm,
    ushort_t* __restrict__ Bmat, float* __restrict__ cst, float* __restrict__ muh)
{
  const int k = blockIdx.x, t = threadIdx.x;
  const int tl = t >> 4, tm = t & 15;
  __shared__ float As[16][16], iDsh[16], MUsh[16];
  __shared__ float R[16][17], rinv[16], zsh[16], bsh[16];
  __shared__ float red[256];

  float accL = 0.f, accb = 0.f, slog = 0.f;
  for (int d0 = 0; d0 < DF; d0 += 16) {
    __syncthreads();
    As[tl][tm] = A[((size_t)k*DF + d0 + tl)*LF + tm];
    if (t < 16) {
      float dv = Dm[k*DF + d0 + t];
      iDsh[t] = 1.f/(dv*dv);
      MUsh[t] = MU[k*DF + d0 + t];
    }
    __syncthreads();
    #pragma unroll
    for (int dd = 0; dd < 16; ++dd)
      accL = fmaf(As[dd][tl]*iDsh[dd], As[dd][tm], accL);
    if (tm == 0) {
      #pragma unroll
      for (int dd = 0; dd < 16; ++dd)
        accb = fmaf(iDsh[dd]*MUsh[dd], As[dd][tl], accb);
    }
    if (t < 16) slog += logf(iDsh[t]);
  }
  __syncthreads();
  R[tl][tm] = accL + (tl == tm ? 1.f : 0.f);
  if (tm == 0) bsh[tl] = accb;
  red[t] = (t < 16) ? slog : 0.f;
  __syncthreads();
  float sumlogiD = 0.f;
  if (t == 0) { for (int i = 0; i < 16; ++i) sumlogiD += red[i]; }

  for (int j = 0; j < 16; ++j) {
    if (t == j) {
      float s = R[j][j];
      for (int i = 0; i < j; ++i) s -= R[j][i]*R[j][i];
      float rj = sqrtf(s);
      R[j][j] = rj; rinv[j] = 1.f/rj;
    }
    __syncthreads();
    if (t < 16 && t > j) {
      float s = R[t][j];
      for (int i = 0; i < j; ++i) s -= R[t][i]*R[j][i];
      R[t][j] = s * rinv[j];
    }
    __syncthreads();
  }

  float ldet = 0.f;
  if (t == 0) {
    #pragma unroll
    for (int j = 0; j < 16; ++j) ldet += 2.f*logf(R[j][j]);
    float w[16], z[16];
    #pragma unroll
    for (int j = 0; j < 16; ++j) {
      float s = bsh[j];
      #pragma unroll
      for (int i = 0; i < 16; ++i) if (i < j) s -= R[j][i]*w[i];
      w[j] = s*rinv[j];
    }
    #pragma unroll
    for (int j = 15; j >= 0; --j) {
      float s = w[j];
      #pragma unroll
      for (int i = 0; i < 16; ++i) if (i > j) s -= R[i][j]*z[i];
      z[j] = s*rinv[j];
      zsh[j] = z[j];
    }
  }
  __syncthreads();

  const int g = k >> 4, kl = k & 15;
  ushort_t* Bgp = Bmat + (size_t)g*FB_CG*DF;
  float muhp = 0.f;
  for (int itr = 0; itr < 4; ++itr) {
    int d = t + itr*256;
    float dv = Dm[k*DF + d];
    float iD = 1.f/(dv*dv);
    float mu = MU[k*DF + d];
    float v[16], gg[16];
    #pragma unroll
    for (int l = 0; l < 16; ++l) v[l] = iD * A[((size_t)k*DF + d)*LF + l];
    #pragma unroll
    for (int j = 0; j < 16; ++j) {
      float s = v[j];
      #pragma unroll
      for (int i = 0; i < 16; ++i) if (i < j) s -= R[j][i]*gg[i];
      gg[j] = s * rinv[j];
    }
    float h = iD*mu;
    #pragma unroll
    for (int l = 0; l < 16; ++l) h -= v[l]*zsh[l];
    muhp = fmaf(mu, h, muhp);
    #pragma unroll
    for (int l = 0; l < 16; ++l)
      Bgp[(size_t)(kl*16 + l)*DF + d] = f2bf(gg[l]);
    Bgp[(size_t)(256 + kl)*DF + d] = f2bf(h);
    Bgp[(size_t)(272 + kl)*DF + d] = f2bf(iD);
  }
  red[t] = muhp;
  __syncthreads();
  for (int s = 128; s > 0; s >>= 1) {
    if (t < s) red[t] += red[t + s];
    __syncthreads();
  }
  if (t == 0) {
    muh[k] = red[0];
    cst[k] = PI[k] - 0.5f*((float)DF*LOG2PI + ldet - sumlogiD);
  }
}

__global__ __launch_bounds__(512, 2) void fb_main(
    const float* __restrict__ x, const ushort_t* __restrict__ Bmat,
    const float* __restrict__ cst, const float* __restrict__ muh,
    float* __restrict__ out)
{
  __shared__ __align__(16) ushort_t smem[2*FB_BN*FB_PITCH + FB_CG*FB_PITCH];
  ushort_t* xs  = smem;
  ushort_t* x2s = smem + FB_BN*FB_PITCH;
  ushort_t* Bs  = smem + 2*FB_BN*FB_PITCH;

  const int t = threadIdx.x;
  const int lane = t & 63, wid = t >> 6;
  const int wr = wid & 3, wc = wid >> 2;
  const int lr = lane & 15, lh = lane >> 4;
  const int n0 = blockIdx.x * FB_BN;
  const int g  = blockIdx.y;

  f32x4 acc[2][9] = {};
  const int srow = t >> 2, sc = t & 3;

  int xoff[2];
  #pragma unroll
  for (int rt = 0; rt < 2; ++rt)
    xoff[rt] = (wr*32 + rt*16 + lr)*FB_PITCH + lh*8;
  int boff[9];
  #pragma unroll
  for (int ct = 0; ct < 9; ++ct)
    boff[ct] = (wc*144 + ct*16 + lr)*FB_PITCH + lh*8;

  for (int d0 = 0; d0 < DF; d0 += FB_DT) {
    __syncthreads();
    {
      const float* xp = x + (size_t)(n0 + srow)*DF + d0 + sc*8;
      float4 v0 = *(const float4*)xp;
      float4 v1 = *(const float4*)(xp + 4);
      float e[8] = {v0.x,v0.y,v0.z,v0.w,v1.x,v1.y,v1.z,v1.w};
      short8v xv, qv;
      #pragma unroll
      for (int i = 0; i < 8; ++i) {
        xv[i] = (short)f2bf(e[i]);
        qv[i] = (short)f2bf(e[i]*e[i]);
      }
      *(short8v*)&xs[srow*FB_PITCH + sc*8]  = xv;
      *(short8v*)&x2s[srow*FB_PITCH + sc*8] = qv;
    }
    for (int u = t; u < FB_CG*4; u += 512) {
      int col = u >> 2, c = u & 3;
      *(short8v*)&Bs[col*FB_PITCH + c*8] =
        *(const short8v*)&Bmat[((size_t)(g*FB_CG + col))*DF + d0 + c*8];
    }
    __syncthreads();

    short8v xf[2];
    #pragma unroll
    for (int rt = 0; rt < 2; ++rt) xf[rt] = *(short8v*)&xs[xoff[rt]];
    #pragma unroll
    for (int ct = 0; ct < 8; ++ct) {
      short8v bfr = *(short8v*)&Bs[boff[ct]];
      #pragma unroll
      for (int rt = 0; rt < 2; ++rt)
        acc[rt][ct] = __builtin_amdgcn_mfma_f32_16x16x32_bf16(xf[rt], bfr, acc[rt][ct], 0, 0, 0);
    }
    {
      short8v bfr = *(short8v*)&Bs[boff[8]];
      short8v a0 = xf[0], a1 = xf[1];
      if (wc) {
        a0 = *(short8v*)&x2s[xoff[0]];
        a1 = *(short8v*)&x2s[xoff[1]];
      }
      acc[0][8] = __builtin_amdgcn_mfma_f32_16x16x32_bf16(a0, bfr, acc[0][8], 0, 0, 0);
      acc[1][8] = __builtin_amdgcn_mfma_f32_16x16x32_bf16(a1, bfr, acc[1][8], 0, 0, 0);
    }
  }

  __syncthreads();
  float* s1v = (float*)smem;
  float* s2h = s1v + FB_BN*17;
  if (wc == 1) {
    #pragma unroll
    for (int rt = 0; rt < 2; ++rt)
      #pragma unroll
      for (int j = 0; j < 4; ++j) {
        int row = wr*32 + rt*16 + lh*4 + j;
        s2h[row*17 + lr] = acc[rt][7][j];
        s1v[row*17 + lr] = acc[rt][8][j];
      }
  }
  __syncthreads();

  const int nyt = wc ? 7 : 9;
  #pragma unroll
  for (int ct = 0; ct < 9; ++ct) {
    if (ct < nyt) {
      int comp = wc*9 + ct;
      int kk = g*16 + comp;
      float cstk = cst[kk], muhk = muh[kk];
      #pragma unroll
      for (int rt = 0; rt < 2; ++rt)
        #pragma unroll
        for (int j = 0; j < 4; ++j) {
          float yv = acc[rt][ct][j];
          float sq = yv*yv;
          sq += __shfl_xor(sq, 1);
          sq += __shfl_xor(sq, 2);
          sq += __shfl_xor(sq, 4);
          sq += __shfl_xor(sq, 8);
          int row = wr*32 + rt*16 + lh*4 + j;
          float s1 = s1v[row*17 + comp];
          float s2 = s2h[row*17 + comp];
          float res = cstk - 0.5f*(s1 - sq - 2.f*s2 + muhk);
          if (lr == 0) out[(size_t)(n0 + row)*KCOMP + kk] = res;
        }
    }
  }
}

// ===========================================================================
extern "C" void kernel_launch(void* const* d_in, const int* in_sizes, int n_in,
                              void* d_out, int out_size, void* d_ws, size_t ws_size,
                              hipStream_t stream) {
  const float* x  = (const float*)d_in[0];
  const float* PI = (const float*)d_in[1];
  const float* MU = (const float*)d_in[2];
  const float* A  = (const float*)d_in[3];
  const float* Dm = (const float*)d_in[4];
  float* out = (float*)d_out;

  if (ws_size >= FULL_NEED) {
    uchar_t* xq   = (uchar_t*)((char*)d_ws + XQ_OFF);
    uchar_t* Bq   = (uchar_t*)((char*)d_ws + BQ_OFF);
    ushort_t* Bsk = (ushort_t*)((char*)d_ws + BSK_OFF);
    float* csk    = (float*)((char*)d_ws + CSK_OFF);

    mfa_pre<<<dim3(KCOMP), dim3(256), 0, stream>>>(PI, MU, A, Dm, Bq, Bsk, csk);
    mfa_sk2q<<<dim3(NPTS/64), dim3(256), 0, stream>>>(x, Bsk, csk, xq, out);
    mfa_gemm8<<<dim3((NPTS/256)*(2048/256)), dim3(1024), 0, stream>>>(xq, Bq, out);
  } else {
    ushort_t* Bmat = (ushort_t*)d_ws;
    float* cstp = (float*)((char*)d_ws + FB_CST_OFF);
    float* muhp = (float*)((char*)d_ws + FB_MUH_OFF);
    fb_pre<<<dim3(KCOMP), dim3(256), 0, stream>>>(PI, MU, A, Dm, Bmat, cstp, muhp);
    fb_main<<<dim3(NPTS/FB_BN, FB_NG), dim3(512), 0, stream>>>(x, Bmat, cstp, muhp, out);
  }
}

// Round 11
// 157.003 us; speedup vs baseline: 1.5519x; 1.0060x over previous
//
#include <hip/hip_runtime.h>
#include <math.h>

typedef unsigned short ushort_t;
typedef unsigned char  uchar_t;
typedef __attribute__((ext_vector_type(8))) short short8v;
typedef __attribute__((ext_vector_type(4))) float f32x4;
typedef __attribute__((ext_vector_type(2))) long l64x2;

#define KCOMP 128
#define DF    1024
#define LF    16
#define NPTS  16384
#define LOG2PI 1.8378770664093453f

// ---------------- full-path ws layout (bytes) ----------------
#define XQ_OFF    ((size_t)0)
#define XQ_BYTES  ((size_t)NPTS*DF)              // 16,777,216 fp8 (K-permuted)
#define BQ_OFF    (XQ_OFF + XQ_BYTES)
#define BQ_BYTES  ((size_t)2048*DF)              // 2,097,152 fp8 (K-permuted)
#define BSK_OFF   (BQ_OFF + BQ_BYTES)
#define BSK_BYTES ((size_t)KCOMP*2*DF*2)         // 524,288 bf16
#define CSK_OFF   (BSK_OFF + BSK_BYTES)
#define FULL_NEED (CSK_OFF + 512)

__device__ __forceinline__ ushort_t f2bf(float f) {
  union { float f; unsigned u; } v; v.f = f;
  unsigned u = v.u;
  return (ushort_t)((u + 0x7FFFu + ((u >> 16) & 1u)) >> 16);
}

#define GLOAD16(gp, lp) __builtin_amdgcn_global_load_lds( \
  (const __attribute__((address_space(1))) unsigned int*)(gp), \
  (__attribute__((address_space(3))) unsigned int*)(lp), 16, 0, 0)

// DPP reduce-add within 16-lane rows (VALU only, no LDS)
#define DPPADD(x, ctrl) do { \
  int _yi = __builtin_amdgcn_update_dpp(0, __float_as_int(x), ctrl, 0xF, 0xF, true); \
  (x) += __int_as_float(_yi); } while (0)

// ---------------------------------------------------------------------------
// pre: per component k: Lm = I + A^T iD A ; chol R ; z ; csk ; then per-d:
// G = iDA R^{-T}, h = iD*mu - iDA z -> Bq fp8 (K-permuted) + Bsk bf16 [-2h;iD]
// ---------------------------------------------------------------------------
__global__ __launch_bounds__(256) void mfa_pre(
    const float* __restrict__ PI, const float* __restrict__ MU,
    const float* __restrict__ A, const float* __restrict__ Dm,
    uchar_t* __restrict__ Bq, ushort_t* __restrict__ Bsk,
    float* __restrict__ csk)
{
  const int k = blockIdx.x, t = threadIdx.x;
  const int tl = t >> 4, tm = t & 15;
  __shared__ float As[64][16];
  __shared__ float iD64[64], MU64[64];
  __shared__ float R[16][17];
  __shared__ float rinv_s[16], zsh[16], bsh[16];
  __shared__ float red[64];
  __shared__ float sc_sumlog, sc_c3;

  float accL = 0.f, accb = 0.f, c3p = 0.f, slogp = 0.f;
  for (int ch = 0; ch < 16; ++ch) {
    __syncthreads();
    ((float4*)&As[0][0])[t] =
        ((const float4*)(A + (size_t)k*DF*LF + (size_t)ch*1024))[t];
    if (t < 64) {
      float dv = Dm[k*DF + ch*64 + t];
      iD64[t] = 1.f/(dv*dv);
      MU64[t] = MU[k*DF + ch*64 + t];
    }
    __syncthreads();
    #pragma unroll 4
    for (int dd = 0; dd < 64; ++dd)
      accL = fmaf(As[dd][tl]*iD64[dd], As[dd][tm], accL);
    if (tm == 0)
      for (int dd = 0; dd < 64; ++dd)
        accb = fmaf(iD64[dd]*MU64[dd], As[dd][tl], accb);
    if (t < 64) {
      c3p = fmaf(iD64[t]*MU64[t], MU64[t], c3p);
      slogp += logf(iD64[t]);
    }
  }
  __syncthreads();
  R[tl][tm] = accL + (tl == tm ? 1.f : 0.f);
  if (tm == 0) bsh[tl] = accb;
  if (t < 64) red[t] = slogp;
  __syncthreads();
  if (t == 0) { float s = 0.f; for (int i = 0; i < 64; ++i) s += red[i]; sc_sumlog = s; }
  __syncthreads();
  if (t < 64) red[t] = c3p;
  __syncthreads();
  if (t == 0) { float s = 0.f; for (int i = 0; i < 64; ++i) s += red[i]; sc_c3 = s; }

  for (int j = 0; j < 16; ++j) {
    __syncthreads();
    if (t == j) {
      float s = R[j][j];
      for (int i = 0; i < j; ++i) s -= R[j][i]*R[j][i];
      float rj = sqrtf(s);
      R[j][j] = rj; rinv_s[j] = 1.f/rj;
    }
    __syncthreads();
    if (t < 16 && t > j) {
      float s = R[t][j];
      for (int i = 0; i < j; ++i) s -= R[t][i]*R[j][i];
      R[t][j] = s * rinv_s[j];
    }
  }
  __syncthreads();
  if (t == 0) {
    float ldet = 0.f;
    for (int j = 0; j < 16; ++j) ldet += 2.f*logf(R[j][j]);
    float w[16], z[16];
    for (int j = 0; j < 16; ++j) {
      float s = bsh[j];
      for (int i = 0; i < j; ++i) s -= R[j][i]*w[i];
      w[j] = s*rinv_s[j];
    }
    for (int j = 15; j >= 0; --j) {
      float s = w[j];
      for (int i = j+1; i < 16; ++i) s -= R[i][j]*z[i];
      z[j] = s*rinv_s[j];
      zsh[j] = z[j];
    }
    float muh = sc_c3;
    for (int l = 0; l < 16; ++l) muh -= bsh[l]*zsh[l];
    csk[k] = PI[k] - 0.5f*((float)DF*LOG2PI + ldet - sc_sumlog) - 0.5f*muh;
  }
  __syncthreads();

  for (int it = 0; it < 4; ++it) {
    const int d = t + it*256;
    float dv = Dm[k*DF + d];
    float iD = 1.f/(dv*dv);
    float mu = MU[k*DF + d];
    float v[16], gg[16];
    #pragma unroll
    for (int l = 0; l < 16; ++l) v[l] = iD * A[((size_t)k*DF + d)*LF + l];
    #pragma unroll
    for (int j = 0; j < 16; ++j) {
      float s = v[j];
      #pragma unroll
      for (int i = 0; i < 16; ++i) if (i < j) s -= R[j][i]*gg[i];
      gg[j] = s * rinv_s[j];
    }
    float h = iD*mu;
    #pragma unroll
    for (int l = 0; l < 16; ++l) h -= v[l]*zsh[l];
    const int dd = d & 63;
    const size_t poff = (size_t)(d & ~63) + ((dd >> 3) & 3)*16 + (dd >> 5)*8 + (dd & 7);
    #pragma unroll
    for (int l = 0; l < 16; ++l) {
      int r8 = __builtin_amdgcn_cvt_pk_fp8_f32(gg[l], gg[l], 0, false);
      Bq[(size_t)(k*16 + l)*DF + poff] = (uchar_t)(r8 & 0xFF);
    }
    Bsk[(size_t)k*2*DF + d]      = f2bf(-2.f*h);
    Bsk[(size_t)k*2*DF + DF + d] = f2bf(iD);
  }
}

// ---------------------------------------------------------------------------
// sk4: per 128-row block (128 blocks x 512 thr, 8 waves): convert x -> fp8
// (write K-permuted xq) + bf16 x/x^2 in LDS; out = csk - 0.5*(x.(-2h)+x^2.iD).
// Waves 0-3: rows 0-63; waves 4-7: rows 64-127. B tile (32KB) shared by both
// row groups. Conservative sync: full vmcnt/lgkm drain + __syncthreads.
// ---------------------------------------------------------------------------
__global__ __launch_bounds__(512) void mfa_sk4(
    const float* __restrict__ x, const ushort_t* __restrict__ Bsk,
    const float* __restrict__ csk, uchar_t* __restrict__ xq,
    float* __restrict__ out)
{
  __shared__ ushort_t xs[8192];     // [128][64] swizzled
  __shared__ ushort_t x2s[8192];
  __shared__ ushort_t Bs[16384];    // [256 vcols][64] swizzled (0-127 h, 128-255 iD)
  const int t = threadIdx.x, lane = t & 63, wid = t >> 6;
  const int wc = wid & 3, rgrp = wid >> 2;
  const int lr = lane & 15, lh = lane >> 4;
  const int n0 = blockIdx.x * 128;
  const int xr = t >> 2, xc = t & 3;    // 128 rows x 4 col-chunks

  f32x4 acc[4][2] = {};

  float4 v0, v1, v2, v3;
  {
    const float* xp = x + (size_t)(n0 + xr)*DF + xc*16;
    v0 = ((const float4*)xp)[0]; v1 = ((const float4*)xp)[1];
    v2 = ((const float4*)xp)[2]; v3 = ((const float4*)xp)[3];
  }

  for (int tt = 0; tt < 16; ++tt) {
    const int d0 = tt * 64;
    __syncthreads();
    // ---- convert prefetched x (bf16 + bf16^2 -> LDS; fp8 K-perm -> xq) ----
    {
      float e[16] = {v0.x,v0.y,v0.z,v0.w, v1.x,v1.y,v1.z,v1.w,
                     v2.x,v2.y,v2.z,v2.w, v3.x,v3.y,v3.z,v3.w};
      short8v b0, b1, q0, q1;
      #pragma unroll
      for (int i = 0; i < 8; ++i) {
        b0[i] = (short)f2bf(e[i]);     q0[i] = (short)f2bf(e[i]*e[i]);
        b1[i] = (short)f2bf(e[8+i]);   q1[i] = (short)f2bf(e[8+i]*e[8+i]);
      }
      const int ch0 = (xc*2) ^ (xr & 7), ch1 = (xc*2+1) ^ (xr & 7);
      *(short8v*)&xs[xr*64 + ch0*8]  = b0;
      *(short8v*)&xs[xr*64 + ch1*8]  = b1;
      *(short8v*)&x2s[xr*64 + ch0*8] = q0;
      *(short8v*)&x2s[xr*64 + ch1*8] = q1;
      int p0 = 0, p1 = 0, p2 = 0, p3 = 0;
      p0 = __builtin_amdgcn_cvt_pk_fp8_f32(e[0],  e[1],  p0, false);
      p0 = __builtin_amdgcn_cvt_pk_fp8_f32(e[2],  e[3],  p0, true);
      p1 = __builtin_amdgcn_cvt_pk_fp8_f32(e[4],  e[5],  p1, false);
      p1 = __builtin_amdgcn_cvt_pk_fp8_f32(e[6],  e[7],  p1, true);
      p2 = __builtin_amdgcn_cvt_pk_fp8_f32(e[8],  e[9],  p2, false);
      p2 = __builtin_amdgcn_cvt_pk_fp8_f32(e[10], e[11], p2, true);
      p3 = __builtin_amdgcn_cvt_pk_fp8_f32(e[12], e[13], p3, false);
      p3 = __builtin_amdgcn_cvt_pk_fp8_f32(e[14], e[15], p3, true);
      long lo = (long)(((unsigned long long)(unsigned)p1 << 32) | (unsigned)p0);
      long hi = (long)(((unsigned long long)(unsigned)p3 << 32) | (unsigned)p2);
      size_t base = (size_t)(n0 + xr)*DF + d0 + (xc & 1)*32 + (xc >> 1)*8;
      *(long*)&xq[base]      = lo;
      *(long*)&xq[base + 16] = hi;
    }
    // ---- stage B tile (32KB, shared): 32 ids, 4 per wave ----
    #pragma unroll
    for (int jj = 0; jj < 4; ++jj) {
      int id = wid*4 + jj;
      int v = id*8 + (lane >> 3);
      int g = (lane & 7) ^ (v & 7);
      const ushort_t* src = (v < 128)
        ? Bsk + (size_t)v*(2*DF) + d0 + g*8
        : Bsk + (size_t)(v - 128)*(2*DF) + DF + d0 + g*8;
      GLOAD16(src, (char*)Bs + id*1024);
    }
    asm volatile("s_waitcnt vmcnt(0) lgkmcnt(0)" ::: "memory");
    __syncthreads();
    // prefetch next x chunk (in flight across MFMAs, consumed next iter)
    if (tt < 15) {
      const float* xp = x + (size_t)(n0 + xr)*DF + (d0 + 64) + xc*16;
      v0 = ((const float4*)xp)[0]; v1 = ((const float4*)xp)[1];
      v2 = ((const float4*)xp)[2]; v3 = ((const float4*)xp)[3];
    }
    __builtin_amdgcn_sched_barrier(0);
    // ---- compute ----
    #pragma unroll
    for (int ks = 0; ks < 2; ++ks) {
      const int cterm = ((ks*4 + lh) ^ (lr & 7)) * 8;
      short8v a_[4], a2_[4], bh[2], bi[2];
      #pragma unroll
      for (int rb = 0; rb < 4; ++rb) {
        int row = rgrp*64 + rb*16 + lr;
        a_[rb]  = *(const short8v*)&xs[row*64 + cterm];
        a2_[rb] = *(const short8v*)&x2s[row*64 + cterm];
      }
      #pragma unroll
      for (int cb = 0; cb < 2; ++cb) {
        int vh = wc*32 + cb*16 + lr;
        bh[cb] = *(const short8v*)&Bs[vh*64 + cterm];
        bi[cb] = *(const short8v*)&Bs[(128 + vh)*64 + cterm];
      }
      #pragma unroll
      for (int cb = 0; cb < 2; ++cb)
        #pragma unroll
        for (int rb = 0; rb < 4; ++rb) {
          acc[rb][cb] = __builtin_amdgcn_mfma_f32_16x16x32_bf16(a_[rb],  bh[cb], acc[rb][cb], 0,0,0);
          acc[rb][cb] = __builtin_amdgcn_mfma_f32_16x16x32_bf16(a2_[rb], bi[cb], acc[rb][cb], 0,0,0);
        }
    }
  }
  // ---- epilogue ----
  #pragma unroll
  for (int cb = 0; cb < 2; ++cb) {
    int comp = wc*32 + cb*16 + lr;
    float ck = csk[comp];
    #pragma unroll
    for (int rb = 0; rb < 4; ++rb)
      #pragma unroll
      for (int j = 0; j < 4; ++j) {
        int row = n0 + rgrp*64 + rb*16 + lh*4 + j;
        out[(size_t)row*KCOMP + comp] = ck - 0.5f*acc[rb][cb][j];
      }
  }
}

// ---------------------------------------------------------------------------
// gemm10: out += 0.5 * sum_l y_l^2 ; y = xq . Bq^T (fp8 e4m3, f32 acc)
// gemm8's verified schedule re-parameterized: 512 thr (8 waves, 2Mx4N),
// block tile 128x256, wave 64x64 (acc 4x4), LDS 48KB (2 slots x 24KB) ->
// 2 blocks/CU co-resident (cross-block overlap hides the barrier train).
// Per tile: gate vmcnt(3) | barrier | 8 C++ b128 reads | lgkm(0) | barrier |
// restage(tt+2, 3 instrs/wave) | 32 MFMA. Same K-permuted layout as R9.
// ---------------------------------------------------------------------------
__global__ __launch_bounds__(512, 4) void mfa_gemm10(
    const uchar_t* __restrict__ xq, const uchar_t* __restrict__ Bq,
    float* __restrict__ out)
{
  __shared__ uchar_t smem[49152];   // 2 slots x 24KB (A 8KB | B 16KB)
  const int t = threadIdx.x, lane = t & 63, wid = t >> 6;  // 8 waves
  const int wm = wid & 1, wn = wid >> 1;
  const int lr = lane & 15, lh = lane >> 4;

  const int bid = blockIdx.x;            // 1024 = 128 rb x 8 cb
  const int xcd = bid & 7, ib = bid >> 3;
  const int rb = xcd*16 + (ib >> 3);     // XCD owns 16 contiguous row-bands
  const int cb = ib & 7;
  const int n0 = rb * 128, c0 = cb * 256;

  f32x4 acc[4][4] = {};

  // staging: 24 x 1KB instrs per K-tile (A ids 0..7, B ids 8..23), 3/wave.
  // instr covers 16 rows x 64B; lane: row = id*16 + (lane>>2),
  // dst chunk = lane&3 (linear), src chunk = (lane&3) ^ ((lane>>3)&3).
  const int js = (((lane & 3) ^ ((lane >> 3) & 3)) * 16);
  const uchar_t* srcP[3]; int dstO[3];
  #pragma unroll
  for (int q = 0; q < 3; ++q) {
    int id = wid*3 + q;
    if (id < 8) {
      int r = id*16 + (lane >> 2);
      srcP[q] = xq + (size_t)(n0 + r)*DF + js;
      dstO[q] = id*1024;
    } else {
      int cr = (id - 8)*16 + (lane >> 2);
      srcP[q] = Bq + (size_t)(c0 + cr)*DF + js;
      dstO[q] = 8192 + (id - 8)*1024;
    }
  }
  // read offsets: row*64 + (lh ^ ((lr>>1)&3))*16 ; one b128 = ks0|ks1
  const int rsw = (lh ^ ((lr >> 1) & 3)) * 16;
  const int aO = (wm*64 + lr)*64 + rsw;            // + rt*1024
  const int bO = 8192 + (wn*64 + lr)*64 + rsw;     // + ct*1024

  #define STAGE10(slot, tt_) do { \
    _Pragma("unroll") \
    for (int q = 0; q < 3; ++q) \
      GLOAD16(srcP[q] + (tt_)*64, (char*)smem + (slot)*24576 + dstO[q] + ((lane)*16 & 1023)); \
  } while (0)

  STAGE10(0, 0);
  STAGE10(1, 1);

  for (int tt = 0; tt < 16; ++tt) {
    const char* lb = (const char*)smem + (tt & 1)*24576;
    l64x2 a2[4], b2[4];

    if (tt < 15) asm volatile("s_waitcnt vmcnt(3)" ::: "memory");
    else         asm volatile("s_waitcnt vmcnt(0)" ::: "memory");
    __builtin_amdgcn_s_barrier();

    #pragma unroll
    for (int rt = 0; rt < 4; ++rt) a2[rt] = *(const l64x2*)(lb + aO + rt*1024);
    #pragma unroll
    for (int ct = 0; ct < 4; ++ct) b2[ct] = *(const l64x2*)(lb + bO + ct*1024);
    asm volatile("s_waitcnt lgkmcnt(0)" ::: "memory");
    __builtin_amdgcn_sched_barrier(0);
    __builtin_amdgcn_s_barrier();           // all waves done reading this slot
    if (tt <= 13) STAGE10(tt & 1, tt + 2);  // overwrite overlaps MFMAs
    __builtin_amdgcn_sched_barrier(0);

    __builtin_amdgcn_s_setprio(1);
    #pragma unroll
    for (int ct = 0; ct < 4; ++ct)
      #pragma unroll
      for (int rt = 0; rt < 4; ++rt)
        acc[rt][ct] = __builtin_amdgcn_mfma_f32_16x16x32_fp8_fp8(a2[rt][0], b2[ct][0], acc[rt][ct], 0,0,0);
    #pragma unroll
    for (int ct = 0; ct < 4; ++ct)
      #pragma unroll
      for (int rt = 0; rt < 4; ++rt)
        acc[rt][ct] = __builtin_amdgcn_mfma_f32_16x16x32_fp8_fp8(a2[rt][1], b2[ct][1], acc[rt][ct], 0,0,0);
    __builtin_amdgcn_s_setprio(0);
  }

  // ---- epilogue: per-(row,comp) sum over 16 cols via DPP, out += 0.5*sum ----
  #pragma unroll
  for (int ct = 0; ct < 4; ++ct) {
    const int comp = cb*16 + wn*4 + ct;
    #pragma unroll
    for (int rt = 0; rt < 4; ++rt) {
      #pragma unroll
      for (int j = 0; j < 4; ++j) {
        float v = acc[rt][ct][j];
        float sq = v*v;
        DPPADD(sq, 0xB1);
        DPPADD(sq, 0x4E);
        DPPADD(sq, 0x124);
        DPPADD(sq, 0x128);
        if (lr == 0) {
          int row = n0 + wm*64 + rt*16 + lh*4 + j;
          size_t idx = (size_t)row * KCOMP + comp;
          out[idx] = out[idx] + 0.5f*sq;
        }
      }
    }
  }
}

// ===========================================================================
// Fallback path (round-2 kernels, needs ~4.8 MB ws) — used if ws too small
// ===========================================================================
#define FB_NG 8
#define FB_CG 288
#define FB_BN 128
#define FB_DT 32
#define FB_PITCH 40
#define FB_BMAT_ELEMS ((size_t)(FB_NG*FB_CG)*DF)
#define FB_CST_OFF (FB_BMAT_ELEMS*2)
#define FB_MUH_OFF (FB_CST_OFF + 512)

__global__ __launch_bounds__(256) void fb_pre(
    const float* __restrict__ PI, const float* __restrict__ MU,
    const float* __restrict__ A, const float* __restrict__ Dm,
    ushort_t* __restrict__ Bmat, float* __restrict__ cst, float* __restrict__ muh)
{
  const int k = blockIdx.x, t = threadIdx.x;
  const int tl = t >> 4, tm = t & 15;
  __shared__ float As[16][16], iDsh[16], MUsh[16];
  __shared__ float R[16][17], rinv[16], zsh[16], bsh[16];
  __shared__ float red[256];

  float accL = 0.f, accb = 0.f, slog = 0.f;
  for (int d0 = 0; d0 < DF; d0 += 16) {
    __syncthreads();
    As[tl][tm] = A[((size_t)k*DF + d0 + tl)*LF + tm];
    if (t < 16) {
      float dv = Dm[k*DF + d0 + t];
      iDsh[t] = 1.f/(dv*dv);
      MUsh[t] = MU[k*DF + d0 + t];
    }
    __syncthreads();
    #pragma unroll
    for (int dd = 0; dd < 16; ++dd)
      accL = fmaf(As[dd][tl]*iDsh[dd], As[dd][tm], accL);
    if (tm == 0) {
      #pragma unroll
      for (int dd = 0; dd < 16; ++dd)
        accb = fmaf(iDsh[dd]*MUsh[dd], As[dd][tl], accb);
    }
    if (t < 16) slog += logf(iDsh[t]);
  }
  __syncthreads();
  R[tl][tm] = accL + (tl == tm ? 1.f : 0.f);
  if (tm == 0) bsh[tl] = accb;
  red[t] = (t < 16) ? slog : 0.f;
  __syncthreads();
  float sumlogiD = 0.f;
  if (t == 0) { for (int i = 0; i < 16; ++i) sumlogiD += red[i]; }

  for (int j = 0; j < 16; ++j) {
    if (t == j) {
      float s = R[j][j];
      for (int i = 0; i < j; ++i) s -= R[j][i]*R[j][i];
      float rj = sqrtf(s);
      R[j][j] = rj; rinv[j] = 1.f/rj;
    }
    __syncthreads();
    if (t < 16 && t > j) {
      float s = R[t][j];
      for (int i = 0; i < j; ++i) s -= R[t][i]*R[j][i];
      R[t][j] = s * rinv[j];
    }
    __syncthreads();
  }

  float ldet = 0.f;
  if (t == 0) {
    #pragma unroll
    for (int j = 0; j < 16; ++j) ldet += 2.f*logf(R[j][j]);
    float w[16], z[16];
    #pragma unroll
    for (int j = 0; j < 16; ++j) {
      float s = bsh[j];
      #pragma unroll
      for (int i = 0; i < 16; ++i) if (i < j) s -= R[j][i]*w[i];
      w[j] = s*rinv[j];
    }
    #pragma unroll
    for (int j = 15; j >= 0; --j) {
      float s = w[j];
      #pragma unroll
      for (int i = 0; i < 16; ++i) if (i > j) s -= R[i][j]*z[i];
      z[j] = s*rinv[j];
      zsh[j] = z[j];
    }
  }
  __syncthreads();

  const int g = k >> 4, kl = k & 15;
  ushort_t* Bgp = Bmat + (size_t)g*FB_CG*DF;
  float muhp = 0.f;
  for (int itr = 0; itr < 4; ++itr) {
    int d = t + itr*256;
    float dv = Dm[k*DF + d];
    float iD = 1.f/(dv*dv);
    float mu = MU[k*DF + d];
    float v[16], gg[16];
    #pragma unroll
    for (int l = 0; l < 16; ++l) v[l] = iD * A[((size_t)k*DF + d)*LF + l];
    #pragma unroll
    for (int j = 0; j < 16; ++j) {
      float s = v[j];
      #pragma unroll
      for (int i = 0; i < 16; ++i) if (i < j) s -= R[j][i]*gg[i];
      gg[j] = s * rinv[j];
    }
    float h = iD*mu;
    #pragma unroll
    for (int l = 0; l < 16; ++l) h -= v[l]*zsh[l];
    muhp = fmaf(mu, h, muhp);
    #pragma unroll
    for (int l = 0; l < 16; ++l)
      Bgp[(size_t)(kl*16 + l)*DF + d] = f2bf(gg[l]);
    Bgp[(size_t)(256 + kl)*DF + d] = f2bf(h);
    Bgp[(size_t)(272 + kl)*DF + d] = f2bf(iD);
  }
  red[t] = muhp;
  __syncthreads();
  for (int s = 128; s > 0; s >>= 1) {
    if (t < s) red[t] += red[t + s];
    __syncthreads();
  }
  if (t == 0) {
    muh[k] = red[0];
    cst[k] = PI[k] - 0.5f*((float)DF*LOG2PI + ldet - sumlogiD);
  }
}

__global__ __launch_bounds__(512, 2) void fb_main(
    const float* __restrict__ x, const ushort_t* __restrict__ Bmat,
    const float* __restrict__ cst, const float* __restrict__ muh,
    float* __restrict__ out)
{
  __shared__ __align__(16) ushort_t smem[2*FB_BN*FB_PITCH + FB_CG*FB_PITCH];
  ushort_t* xs  = smem;
  ushort_t* x2s = smem + FB_BN*FB_PITCH;
  ushort_t* Bs  = smem + 2*FB_BN*FB_PITCH;

  const int t = threadIdx.x;
  const int lane = t & 63, wid = t >> 6;
  const int wr = wid & 3, wc = wid >> 2;
  const int lr = lane & 15, lh = lane >> 4;
  const int n0 = blockIdx.x * FB_BN;
  const int g  = blockIdx.y;

  f32x4 acc[2][9] = {};
  const int srow = t >> 2, sc = t & 3;

  int xoff[2];
  #pragma unroll
  for (int rt = 0; rt < 2; ++rt)
    xoff[rt] = (wr*32 + rt*16 + lr)*FB_PITCH + lh*8;
  int boff[9];
  #pragma unroll
  for (int ct = 0; ct < 9; ++ct)
    boff[ct] = (wc*144 + ct*16 + lr)*FB_PITCH + lh*8;

  for (int d0 = 0; d0 < DF; d0 += FB_DT) {
    __syncthreads();
    {
      const float* xp = x + (size_t)(n0 + srow)*DF + d0 + sc*8;
      float4 v0 = *(const float4*)xp;
      float4 v1 = *(const float4*)(xp + 4);
      float e[8] = {v0.x,v0.y,v0.z,v0.w,v1.x,v1.y,v1.z,v1.w};
      short8v xv, qv;
      #pragma unroll
      for (int i = 0; i < 8; ++i) {
        xv[i] = (short)f2bf(e[i]);
        qv[i] = (short)f2bf(e[i]*e[i]);
      }
      *(short8v*)&xs[srow*FB_PITCH + sc*8]  = xv;
      *(short8v*)&x2s[srow*FB_PITCH + sc*8] = qv;
    }
    for (int u = t; u < FB_CG*4; u += 512) {
      int col = u >> 2, c = u & 3;
      *(short8v*)&Bs[col*FB_PITCH + c*8] =
        *(const short8v*)&Bmat[((size_t)(g*FB_CG + col))*DF + d0 + c*8];
    }
    __syncthreads();

    short8v xf[2];
    #pragma unroll
    for (int rt = 0; rt < 2; ++rt) xf[rt] = *(short8v*)&xs[xoff[rt]];
    #pragma unroll
    for (int ct = 0; ct < 8; ++ct) {
      short8v bfr = *(short8v*)&Bs[boff[ct]];
      #pragma unroll
      for (int rt = 0; rt < 2; ++rt)
        acc[rt][ct] = __builtin_amdgcn_mfma_f32_16x16x32_bf16(xf[rt], bfr, acc[rt][ct], 0, 0, 0);
    }
    {
      short8v bfr = *(short8v*)&Bs[boff[8]];
      short8v a0 = xf[0], a1 = xf[1];
      if (wc) {
        a0 = *(short8v*)&x2s[xoff[0]];
        a1 = *(short8v*)&x2s[xoff[1]];
      }
      acc[0][8] = __builtin_amdgcn_mfma_f32_16x16x32_bf16(a0, bfr, acc[0][8], 0, 0, 0);
      acc[1][8] = __builtin_amdgcn_mfma_f32_16x16x32_bf16(a1, bfr, acc[1][8], 0, 0, 0);
    }
  }

  __syncthreads();
  float* s1v = (float*)smem;
  float* s2h = s1v + FB_BN*17;
  if (wc == 1) {
    #pragma unroll
    for (int rt = 0; rt < 2; ++rt)
      #pragma unroll
      for (int j = 0; j < 4; ++j) {
        int row = wr*32 + rt*16 + lh*4 + j;
        s2h[row*17 + lr] = acc[rt][7][j];
        s1v[row*17 + lr] = acc[rt][8][j];
      }
  }
  __syncthreads();

  const int nyt = wc ? 7 : 9;
  #pragma unroll
  for (int ct = 0; ct < 9; ++ct) {
    if (ct < nyt) {
      int comp = wc*9 + ct;
      int kk = g*16 + comp;
      float cstk = cst[kk], muhk = muh[kk];
      #pragma unroll
      for (int rt = 0; rt < 2; ++rt)
        #pragma unroll
        for (int j = 0; j < 4; ++j) {
          float yv = acc[rt][ct][j];
          float sq = yv*yv;
          sq += __shfl_xor(sq, 1);
          sq += __shfl_xor(sq, 2);
          sq += __shfl_xor(sq, 4);
          sq += __shfl_xor(sq, 8);
          int row = wr*32 + rt*16 + lh*4 + j;
          float s1 = s1v[row*17 + comp];
          float s2 = s2h[row*17 + comp];
          float res = cstk - 0.5f*(s1 - sq - 2.f*s2 + muhk);
          if (lr == 0) out[(size_t)(n0 + row)*KCOMP + kk] = res;
        }
    }
  }
}

// ===========================================================================
extern "C" void kernel_launch(void* const* d_in, const int* in_sizes, int n_in,
                              void* d_out, int out_size, void* d_ws, size_t ws_size,
                              hipStream_t stream) {
  const float* x  = (const float*)d_in[0];
  const float* PI = (const float*)d_in[1];
  const float* MU = (const float*)d_in[2];
  const float* A  = (const float*)d_in[3];
  const float* Dm = (const float*)d_in[4];
  float* out = (float*)d_out;

  if (ws_size >= FULL_NEED) {
    uchar_t* xq   = (uchar_t*)((char*)d_ws + XQ_OFF);
    uchar_t* Bq   = (uchar_t*)((char*)d_ws + BQ_OFF);
    ushort_t* Bsk = (ushort_t*)((char*)d_ws + BSK_OFF);
    float* csk    = (float*)((char*)d_ws + CSK_OFF);

    mfa_pre<<<dim3(KCOMP), dim3(256), 0, stream>>>(PI, MU, A, Dm, Bq, Bsk, csk);
    mfa_sk4<<<dim3(NPTS/128), dim3(512), 0, stream>>>(x, Bsk, csk, xq, out);
    mfa_gemm10<<<dim3((NPTS/128)*(2048/256)), dim3(512), 0, stream>>>(xq, Bq, out);
  } else {
    ushort_t* Bmat = (ushort_t*)d_ws;
    float* cstp = (float*)((char*)d_ws + FB_CST_OFF);
    float* muhp = (float*)((char*)d_ws + FB_MUH_OFF);
    fb_pre<<<dim3(KCOMP), dim3(256), 0, stream>>>(PI, MU, A, Dm, Bmat, cstp, muhp);
    fb_main<<<dim3(NPTS/FB_BN, FB_NG), dim3(512), 0, stream>>>(x, Bmat, cstp, muhp, out);
  }
}

// Round 12
// 151.670 us; speedup vs baseline: 1.6064x; 1.0352x over previous
//
#include <hip/hip_runtime.h>
#include <math.h>

typedef unsigned short ushort_t;
typedef unsigned char  uchar_t;
typedef __attribute__((ext_vector_type(8))) short short8v;
typedef __attribute__((ext_vector_type(4))) float f32x4;
typedef __attribute__((ext_vector_type(2))) long l64x2;

#define KCOMP 128
#define DF    1024
#define LF    16
#define NPTS  16384
#define LOG2PI 1.8378770664093453f

// ---------------- full-path ws layout (bytes) ----------------
#define XQ_OFF    ((size_t)0)
#define XQ_BYTES  ((size_t)NPTS*DF)              // 16,777,216 fp8 (K-permuted)
#define BQ_OFF    (XQ_OFF + XQ_BYTES)
#define BQ_BYTES  ((size_t)2048*DF)              // 2,097,152 fp8 (K-permuted)
#define BSK_OFF   (BQ_OFF + BQ_BYTES)
#define BSK_BYTES ((size_t)KCOMP*2*DF*2)         // 524,288 bf16
#define CSK_OFF   (BSK_OFF + BSK_BYTES)
#define FULL_NEED (CSK_OFF + 512)

__device__ __forceinline__ ushort_t f2bf(float f) {
  union { float f; unsigned u; } v; v.f = f;
  unsigned u = v.u;
  return (ushort_t)((u + 0x7FFFu + ((u >> 16) & 1u)) >> 16);
}

#define GLOAD16(gp, lp) __builtin_amdgcn_global_load_lds( \
  (const __attribute__((address_space(1))) unsigned int*)(gp), \
  (__attribute__((address_space(3))) unsigned int*)(lp), 16, 0, 0)

// DPP reduce-add within 16-lane rows (VALU only, no LDS)
#define DPPADD(x, ctrl) do { \
  int _yi = __builtin_amdgcn_update_dpp(0, __float_as_int(x), ctrl, 0xF, 0xF, true); \
  (x) += __int_as_float(_yi); } while (0)

// ---------------------------------------------------------------------------
// pre: per component k: Lm = I + A^T iD A ; chol R ; z ; csk ; then per-d:
// G = iDA R^{-T}, h = iD*mu - iDA z -> Bq fp8 (K-permuted) + Bsk bf16 [-2h;iD]
// ---------------------------------------------------------------------------
__global__ __launch_bounds__(256) void mfa_pre(
    const float* __restrict__ PI, const float* __restrict__ MU,
    const float* __restrict__ A, const float* __restrict__ Dm,
    uchar_t* __restrict__ Bq, ushort_t* __restrict__ Bsk,
    float* __restrict__ csk)
{
  const int k = blockIdx.x, t = threadIdx.x;
  const int tl = t >> 4, tm = t & 15;
  __shared__ float As[64][16];
  __shared__ float iD64[64], MU64[64];
  __shared__ float R[16][17];
  __shared__ float rinv_s[16], zsh[16], bsh[16];
  __shared__ float red[64];
  __shared__ float sc_sumlog, sc_c3;

  float accL = 0.f, accb = 0.f, c3p = 0.f, slogp = 0.f;
  for (int ch = 0; ch < 16; ++ch) {
    __syncthreads();
    ((float4*)&As[0][0])[t] =
        ((const float4*)(A + (size_t)k*DF*LF + (size_t)ch*1024))[t];
    if (t < 64) {
      float dv = Dm[k*DF + ch*64 + t];
      iD64[t] = 1.f/(dv*dv);
      MU64[t] = MU[k*DF + ch*64 + t];
    }
    __syncthreads();
    #pragma unroll 4
    for (int dd = 0; dd < 64; ++dd)
      accL = fmaf(As[dd][tl]*iD64[dd], As[dd][tm], accL);
    if (tm == 0)
      for (int dd = 0; dd < 64; ++dd)
        accb = fmaf(iD64[dd]*MU64[dd], As[dd][tl], accb);
    if (t < 64) {
      c3p = fmaf(iD64[t]*MU64[t], MU64[t], c3p);
      slogp += logf(iD64[t]);
    }
  }
  __syncthreads();
  R[tl][tm] = accL + (tl == tm ? 1.f : 0.f);
  if (tm == 0) bsh[tl] = accb;
  if (t < 64) red[t] = slogp;
  __syncthreads();
  if (t == 0) { float s = 0.f; for (int i = 0; i < 64; ++i) s += red[i]; sc_sumlog = s; }
  __syncthreads();
  if (t < 64) red[t] = c3p;
  __syncthreads();
  if (t == 0) { float s = 0.f; for (int i = 0; i < 64; ++i) s += red[i]; sc_c3 = s; }

  for (int j = 0; j < 16; ++j) {
    __syncthreads();
    if (t == j) {
      float s = R[j][j];
      for (int i = 0; i < j; ++i) s -= R[j][i]*R[j][i];
      float rj = sqrtf(s);
      R[j][j] = rj; rinv_s[j] = 1.f/rj;
    }
    __syncthreads();
    if (t < 16 && t > j) {
      float s = R[t][j];
      for (int i = 0; i < j; ++i) s -= R[t][i]*R[j][i];
      R[t][j] = s * rinv_s[j];
    }
  }
  __syncthreads();
  if (t == 0) {
    float ldet = 0.f;
    for (int j = 0; j < 16; ++j) ldet += 2.f*logf(R[j][j]);
    float w[16], z[16];
    for (int j = 0; j < 16; ++j) {
      float s = bsh[j];
      for (int i = 0; i < j; ++i) s -= R[j][i]*w[i];
      w[j] = s*rinv_s[j];
    }
    for (int j = 15; j >= 0; --j) {
      float s = w[j];
      for (int i = j+1; i < 16; ++i) s -= R[i][j]*z[i];
      z[j] = s*rinv_s[j];
      zsh[j] = z[j];
    }
    float muh = sc_c3;
    for (int l = 0; l < 16; ++l) muh -= bsh[l]*zsh[l];
    csk[k] = PI[k] - 0.5f*((float)DF*LOG2PI + ldet - sc_sumlog) - 0.5f*muh;
  }
  __syncthreads();

  for (int it = 0; it < 4; ++it) {
    const int d = t + it*256;
    float dv = Dm[k*DF + d];
    float iD = 1.f/(dv*dv);
    float mu = MU[k*DF + d];
    float v[16], gg[16];
    #pragma unroll
    for (int l = 0; l < 16; ++l) v[l] = iD * A[((size_t)k*DF + d)*LF + l];
    #pragma unroll
    for (int j = 0; j < 16; ++j) {
      float s = v[j];
      #pragma unroll
      for (int i = 0; i < 16; ++i) if (i < j) s -= R[j][i]*gg[i];
      gg[j] = s * rinv_s[j];
    }
    float h = iD*mu;
    #pragma unroll
    for (int l = 0; l < 16; ++l) h -= v[l]*zsh[l];
    const int dd = d & 63;
    const size_t poff = (size_t)(d & ~63) + ((dd >> 3) & 3)*16 + (dd >> 5)*8 + (dd & 7);
    #pragma unroll
    for (int l = 0; l < 16; ++l) {
      int r8 = __builtin_amdgcn_cvt_pk_fp8_f32(gg[l], gg[l], 0, false);
      Bq[(size_t)(k*16 + l)*DF + poff] = (uchar_t)(r8 & 0xFF);
    }
    Bsk[(size_t)k*2*DF + d]      = f2bf(-2.f*h);
    Bsk[(size_t)k*2*DF + DF + d] = f2bf(iD);
  }
}

// ---------------------------------------------------------------------------
// sk2q (R9-verified): per 64-row block: convert x -> fp8 (write K-permuted
// xq) + bf16 x/x^2 in LDS; out[n,c] = csk[c] - 0.5*( x.(-2h) + x^2.iD ).
// 256 blocks x 256 thr; x-register prefetch across the MFMA phase.
// ---------------------------------------------------------------------------
__global__ __launch_bounds__(256) void mfa_sk2q(
    const float* __restrict__ x, const ushort_t* __restrict__ Bsk,
    const float* __restrict__ csk, uchar_t* __restrict__ xq,
    float* __restrict__ out)
{
  __shared__ ushort_t xs[4096];     // [64][64] swizzled
  __shared__ ushort_t x2s[4096];
  __shared__ ushort_t Bs[16384];    // [256 vcols][64] swizzled (0-127 h, 128-255 iD)
  const int t = threadIdx.x, lane = t & 63, wid = t >> 6;
  const int wc = wid;
  const int lr = lane & 15, lh = lane >> 4;
  const int n0 = blockIdx.x * 64;
  const int xr = t >> 2, xc = t & 3;

  f32x4 acc[4][2] = {};

  float4 v0, v1, v2, v3;
  {
    const float* xp = x + (size_t)(n0 + xr)*DF + xc*16;
    v0 = ((const float4*)xp)[0]; v1 = ((const float4*)xp)[1];
    v2 = ((const float4*)xp)[2]; v3 = ((const float4*)xp)[3];
  }

  for (int tt = 0; tt < 16; ++tt) {
    const int d0 = tt * 64;
    __syncthreads();
    // ---- convert prefetched x (fp32 -> bf16 + bf16^2 LDS; fp8 perm plane) ----
    {
      float e[16] = {v0.x,v0.y,v0.z,v0.w, v1.x,v1.y,v1.z,v1.w,
                     v2.x,v2.y,v2.z,v2.w, v3.x,v3.y,v3.z,v3.w};
      short8v b0, b1, q0, q1;
      #pragma unroll
      for (int i = 0; i < 8; ++i) {
        b0[i] = (short)f2bf(e[i]);     q0[i] = (short)f2bf(e[i]*e[i]);
        b1[i] = (short)f2bf(e[8+i]);   q1[i] = (short)f2bf(e[8+i]*e[8+i]);
      }
      const int ch0 = (xc*2) ^ (xr & 7), ch1 = (xc*2+1) ^ (xr & 7);
      *(short8v*)&xs[xr*64 + ch0*8]  = b0;
      *(short8v*)&xs[xr*64 + ch1*8]  = b1;
      *(short8v*)&x2s[xr*64 + ch0*8] = q0;
      *(short8v*)&x2s[xr*64 + ch1*8] = q1;
      // fp8 pack (e4m3, saturating) -> two 8B groups, K-permuted positions
      int p0 = 0, p1 = 0, p2 = 0, p3 = 0;
      p0 = __builtin_amdgcn_cvt_pk_fp8_f32(e[0],  e[1],  p0, false);
      p0 = __builtin_amdgcn_cvt_pk_fp8_f32(e[2],  e[3],  p0, true);
      p1 = __builtin_amdgcn_cvt_pk_fp8_f32(e[4],  e[5],  p1, false);
      p1 = __builtin_amdgcn_cvt_pk_fp8_f32(e[6],  e[7],  p1, true);
      p2 = __builtin_amdgcn_cvt_pk_fp8_f32(e[8],  e[9],  p2, false);
      p2 = __builtin_amdgcn_cvt_pk_fp8_f32(e[10], e[11], p2, true);
      p3 = __builtin_amdgcn_cvt_pk_fp8_f32(e[12], e[13], p3, false);
      p3 = __builtin_amdgcn_cvt_pk_fp8_f32(e[14], e[15], p3, true);
      long lo = (long)(((unsigned long long)(unsigned)p1 << 32) | (unsigned)p0);
      long hi = (long)(((unsigned long long)(unsigned)p3 << 32) | (unsigned)p2);
      size_t base = (size_t)(n0 + xr)*DF + d0 + (xc & 1)*32 + (xc >> 1)*8;
      *(long*)&xq[base]      = lo;
      *(long*)&xq[base + 16] = hi;
    }
    // ---- stage B (both parts) via global_load_lds ----
    #pragma unroll
    for (int j = 0; j < 8; ++j) {
      int v = (wid*8 + j)*8 + (lane >> 3);
      int g = (lane & 7) ^ (v & 7);
      const ushort_t* src = (v < 128)
        ? Bsk + (size_t)v*(2*DF) + d0 + g*8
        : Bsk + (size_t)(v - 128)*(2*DF) + DF + d0 + g*8;
      GLOAD16(src, (char*)Bs + (wid*8 + j)*1024);
    }
    __syncthreads();
    // prefetch next x chunk (in flight across MFMAs; consumed next iter)
    if (tt < 15) {
      const float* xp = x + (size_t)(n0 + xr)*DF + (d0 + 64) + xc*16;
      v0 = ((const float4*)xp)[0]; v1 = ((const float4*)xp)[1];
      v2 = ((const float4*)xp)[2]; v3 = ((const float4*)xp)[3];
    }
    __builtin_amdgcn_sched_barrier(0);
    // ---- compute ----
    #pragma unroll
    for (int ks = 0; ks < 2; ++ks) {
      const int cterm = ((ks*4 + lh) ^ (lr & 7)) * 8;
      short8v a_[4], a2_[4], bh[2], bi[2];
      #pragma unroll
      for (int rb = 0; rb < 4; ++rb) {
        a_[rb]  = *(const short8v*)&xs[(rb*16 + lr)*64 + cterm];
        a2_[rb] = *(const short8v*)&x2s[(rb*16 + lr)*64 + cterm];
      }
      #pragma unroll
      for (int cb = 0; cb < 2; ++cb) {
        int vh = wc*32 + cb*16 + lr;
        bh[cb] = *(const short8v*)&Bs[vh*64 + cterm];
        bi[cb] = *(const short8v*)&Bs[(128 + vh)*64 + cterm];
      }
      #pragma unroll
      for (int cb = 0; cb < 2; ++cb)
        #pragma unroll
        for (int rb = 0; rb < 4; ++rb) {
          acc[rb][cb] = __builtin_amdgcn_mfma_f32_16x16x32_bf16(a_[rb],  bh[cb], acc[rb][cb], 0,0,0);
          acc[rb][cb] = __builtin_amdgcn_mfma_f32_16x16x32_bf16(a2_[rb], bi[cb], acc[rb][cb], 0,0,0);
        }
    }
  }
  // ---- epilogue ----
  #pragma unroll
  for (int cb = 0; cb < 2; ++cb) {
    int comp = wc*32 + cb*16 + lr;
    float ck = csk[comp];
    #pragma unroll
    for (int rb = 0; rb < 4; ++rb)
      #pragma unroll
      for (int j = 0; j < 4; ++j) {
        int row = n0 + rb*16 + lh*4 + j;
        out[(size_t)row*KCOMP + comp] = ck - 0.5f*acc[rb][cb][j];
      }
  }
}

// ---------------------------------------------------------------------------
// gemm11: out += 0.5 * sum_l y_l^2 ; y = xq . Bq^T (fp8 e4m3, f32 acc)
// gemm10 addressing (verified) + 3-slot LDS rotation: slot(tt) read now,
// slot(tt+1) staged/in-flight, slot(tt+2) restaged this iter (its reads
// completed LAST iter -> no in-wave lgkm drain needed; compiler emits
// fine-grained lgkmcnt interleave of ds_reads with MFMAs).
// Per tile: vmcnt(3) gate | barrier | stage(tt+2) | 8 C++ b128 reads | 32 MFMA.
// LDS 72KB -> still 2 blocks/CU.
// ---------------------------------------------------------------------------
__global__ __launch_bounds__(512, 4) void mfa_gemm11(
    const uchar_t* __restrict__ xq, const uchar_t* __restrict__ Bq,
    float* __restrict__ out)
{
  __shared__ uchar_t smem[73728];   // 3 slots x 24KB (A 8KB | B 16KB)
  const int t = threadIdx.x, lane = t & 63, wid = t >> 6;  // 8 waves
  const int wm = wid & 1, wn = wid >> 1;
  const int lr = lane & 15, lh = lane >> 4;

  const int bid = blockIdx.x;            // 1024 = 128 rb x 8 cb
  const int xcd = bid & 7, ib = bid >> 3;
  const int rb = xcd*16 + (ib >> 3);     // XCD owns 16 contiguous row-bands
  const int cb = ib & 7;
  const int n0 = rb * 128, c0 = cb * 256;

  f32x4 acc[4][4] = {};

  // staging: 24 x 1KB instrs per K-tile (A ids 0..7, B ids 8..23), 3/wave.
  // instr covers 16 rows x 64B; lane: row = id*16 + (lane>>2),
  // dst chunk = lane&3 (linear), src chunk = (lane&3) ^ ((lane>>3)&3).
  const int js = (((lane & 3) ^ ((lane >> 3) & 3)) * 16);
  const uchar_t* srcP[3]; int dstO[3];
  #pragma unroll
  for (int q = 0; q < 3; ++q) {
    int id = wid*3 + q;
    if (id < 8) {
      int r = id*16 + (lane >> 2);
      srcP[q] = xq + (size_t)(n0 + r)*DF + js;
      dstO[q] = id*1024;
    } else {
      int cr = (id - 8)*16 + (lane >> 2);
      srcP[q] = Bq + (size_t)(c0 + cr)*DF + js;
      dstO[q] = 8192 + (id - 8)*1024;
    }
  }
  // read offsets: row*64 + (lh ^ ((lr>>1)&3))*16 ; one b128 = ks0|ks1
  const int rsw = (lh ^ ((lr >> 1) & 3)) * 16;
  const int aO = (wm*64 + lr)*64 + rsw;            // + rt*1024
  const int bO = 8192 + (wn*64 + lr)*64 + rsw;     // + ct*1024

  #define STAGE11(slot, tt_) do { \
    _Pragma("unroll") \
    for (int q = 0; q < 3; ++q) \
      GLOAD16(srcP[q] + (tt_)*64, (char*)smem + (slot)*24576 + dstO[q] + ((lane)*16 & 1023)); \
  } while (0)

  STAGE11(0, 0);
  STAGE11(1, 1);

  for (int tt = 0; tt < 16; ++tt) {
    // gate: tile tt resident. Outstanding at gate: stage(tt+1) = 3 instrs.
    if (tt < 15) asm volatile("s_waitcnt vmcnt(3)" ::: "memory");
    else         asm volatile("s_waitcnt vmcnt(0)" ::: "memory");
    __builtin_amdgcn_s_barrier();
    // restage slot[(tt+2)%3] (its tile tt-1 reads completed last iter,
    // before this barrier) with tile tt+2
    if (tt + 2 <= 15) STAGE11((tt + 2) % 3, tt + 2);

    const char* lb = (const char*)smem + (tt % 3) * 24576;
    l64x2 a2[4], b2[4];
    #pragma unroll
    for (int rt = 0; rt < 4; ++rt) a2[rt] = *(const l64x2*)(lb + aO + rt*1024);
    #pragma unroll
    for (int ct = 0; ct < 4; ++ct) b2[ct] = *(const l64x2*)(lb + bO + ct*1024);
    // no lgkm drain: compiler inserts fine-grained waits before each MFMA

    __builtin_amdgcn_s_setprio(1);
    #pragma unroll
    for (int ct = 0; ct < 4; ++ct)
      #pragma unroll
      for (int rt = 0; rt < 4; ++rt)
        acc[rt][ct] = __builtin_amdgcn_mfma_f32_16x16x32_fp8_fp8(a2[rt][0], b2[ct][0], acc[rt][ct], 0,0,0);
    #pragma unroll
    for (int ct = 0; ct < 4; ++ct)
      #pragma unroll
      for (int rt = 0; rt < 4; ++rt)
        acc[rt][ct] = __builtin_amdgcn_mfma_f32_16x16x32_fp8_fp8(a2[rt][1], b2[ct][1], acc[rt][ct], 0,0,0);
    __builtin_amdgcn_s_setprio(0);
  }

  // ---- epilogue: per-(row,comp) sum over 16 cols via DPP, out += 0.5*sum ----
  #pragma unroll
  for (int ct = 0; ct < 4; ++ct) {
    const int comp = cb*16 + wn*4 + ct;
    #pragma unroll
    for (int rt = 0; rt < 4; ++rt) {
      #pragma unroll
      for (int j = 0; j < 4; ++j) {
        float v = acc[rt][ct][j];
        float sq = v*v;
        DPPADD(sq, 0xB1);
        DPPADD(sq, 0x4E);
        DPPADD(sq, 0x124);
        DPPADD(sq, 0x128);
        if (lr == 0) {
          int row = n0 + wm*64 + rt*16 + lh*4 + j;
          size_t idx = (size_t)row * KCOMP + comp;
          out[idx] = out[idx] + 0.5f*sq;
        }
      }
    }
  }
}

// ===========================================================================
// Fallback path (round-2 kernels, needs ~4.8 MB ws) — used if ws too small
// ===========================================================================
#define FB_NG 8
#define FB_CG 288
#define FB_BN 128
#define FB_DT 32
#define FB_PITCH 40
#define FB_BMAT_ELEMS ((size_t)(FB_NG*FB_CG)*DF)
#define FB_CST_OFF (FB_BMAT_ELEMS*2)
#define FB_MUH_OFF (FB_CST_OFF + 512)

__global__ __launch_bounds__(256) void fb_pre(
    const float* __restrict__ PI, const float* __restrict__ MU,
    const float* __restrict__ A, const float* __restrict__ Dm,
    ushort_t* __restrict__ Bmat, float* __restrict__ cst, float* __restrict__ muh)
{
  const int k = blockIdx.x, t = threadIdx.x;
  const int tl = t >> 4, tm = t & 15;
  __shared__ float As[16][16], iDsh[16], MUsh[16];
  __shared__ float R[16][17], rinv[16], zsh[16], bsh[16];
  __shared__ float red[256];

  float accL = 0.f, accb = 0.f, slog = 0.f;
  for (int d0 = 0; d0 < DF; d0 += 16) {
    __syncthreads();
    As[tl][tm] = A[((size_t)k*DF + d0 + tl)*LF + tm];
    if (t < 16) {
      float dv = Dm[k*DF + d0 + t];
      iDsh[t] = 1.f/(dv*dv);
      MUsh[t] = MU[k*DF + d0 + t];
    }
    __syncthreads();
    #pragma unroll
    for (int dd = 0; dd < 16; ++dd)
      accL = fmaf(As[dd][tl]*iDsh[dd], As[dd][tm], accL);
    if (tm == 0) {
      #pragma unroll
      for (int dd = 0; dd < 16; ++dd)
        accb = fmaf(iDsh[dd]*MUsh[dd], As[dd][tl], accb);
    }
    if (t < 16) slog += logf(iDsh[t]);
  }
  __syncthreads();
  R[tl][tm] = accL + (tl == tm ? 1.f : 0.f);
  if (tm == 0) bsh[tl] = accb;
  red[t] = (t < 16) ? slog : 0.f;
  __syncthreads();
  float sumlogiD = 0.f;
  if (t == 0) { for (int i = 0; i < 16; ++i) sumlogiD += red[i]; }

  for (int j = 0; j < 16; ++j) {
    if (t == j) {
      float s = R[j][j];
      for (int i = 0; i < j; ++i) s -= R[j][i]*R[j][i];
      float rj = sqrtf(s);
      R[j][j] = rj; rinv[j] = 1.f/rj;
    }
    __syncthreads();
    if (t < 16 && t > j) {
      float s = R[t][j];
      for (int i = 0; i < j; ++i) s -= R[t][i]*R[j][i];
      R[t][j] = s * rinv[j];
    }
    __syncthreads();
  }

  float ldet = 0.f;
  if (t == 0) {
    #pragma unroll
    for (int j = 0; j < 16; ++j) ldet += 2.f*logf(R[j][j]);
    float w[16], z[16];
    #pragma unroll
    for (int j = 0; j < 16; ++j) {
      float s = bsh[j];
      #pragma unroll
      for (int i = 0; i < 16; ++i) if (i < j) s -= R[j][i]*w[i];
      w[j] = s*rinv[j];
    }
    #pragma unroll
    for (int j = 15; j >= 0; --j) {
      float s = w[j];
      #pragma unroll
      for (int i = 0; i < 16; ++i) if (i > j) s -= R[i][j]*z[i];
      z[j] = s*rinv[j];
      zsh[j] = z[j];
    }
  }
  __syncthreads();

  const int g = k >> 4, kl = k & 15;
  ushort_t* Bgp = Bmat + (size_t)g*FB_CG*DF;
  float muhp = 0.f;
  for (int itr = 0; itr < 4; ++itr) {
    int d = t + itr*256;
    float dv = Dm[k*DF + d];
    float iD = 1.f/(dv*dv);
    float mu = MU[k*DF + d];
    float v[16], gg[16];
    #pragma unroll
    for (int l = 0; l < 16; ++l) v[l] = iD * A[((size_t)k*DF + d)*LF + l];
    #pragma unroll
    for (int j = 0; j < 16; ++j) {
      float s = v[j];
      #pragma unroll
      for (int i = 0; i < 16; ++i) if (i < j) s -= R[j][i]*gg[i];
      gg[j] = s * rinv[j];
    }
    float h = iD*mu;
    #pragma unroll
    for (int l = 0; l < 16; ++l) h -= v[l]*zsh[l];
    muhp = fmaf(mu, h, muhp);
    #pragma unroll
    for (int l = 0; l < 16; ++l)
      Bgp[(size_t)(kl*16 + l)*DF + d] = f2bf(gg[l]);
    Bgp[(size_t)(256 + kl)*DF + d] = f2bf(h);
    Bgp[(size_t)(272 + kl)*DF + d] = f2bf(iD);
  }
  red[t] = muhp;
  __syncthreads();
  for (int s = 128; s > 0; s >>= 1) {
    if (t < s) red[t] += red[t + s];
    __syncthreads();
  }
  if (t == 0) {
    muh[k] = red[0];
    cst[k] = PI[k] - 0.5f*((float)DF*LOG2PI + ldet - sumlogiD);
  }
}

__global__ __launch_bounds__(512, 2) void fb_main(
    const float* __restrict__ x, const ushort_t* __restrict__ Bmat,
    const float* __restrict__ cst, const float* __restrict__ muh,
    float* __restrict__ out)
{
  __shared__ __align__(16) ushort_t smem[2*FB_BN*FB_PITCH + FB_CG*FB_PITCH];
  ushort_t* xs  = smem;
  ushort_t* x2s = smem + FB_BN*FB_PITCH;
  ushort_t* Bs  = smem + 2*FB_BN*FB_PITCH;

  const int t = threadIdx.x;
  const int lane = t & 63, wid = t >> 6;
  const int wr = wid & 3, wc = wid >> 2;
  const int lr = lane & 15, lh = lane >> 4;
  const int n0 = blockIdx.x * FB_BN;
  const int g  = blockIdx.y;

  f32x4 acc[2][9] = {};
  const int srow = t >> 2, sc = t & 3;

  int xoff[2];
  #pragma unroll
  for (int rt = 0; rt < 2; ++rt)
    xoff[rt] = (wr*32 + rt*16 + lr)*FB_PITCH + lh*8;
  int boff[9];
  #pragma unroll
  for (int ct = 0; ct < 9; ++ct)
    boff[ct] = (wc*144 + ct*16 + lr)*FB_PITCH + lh*8;

  for (int d0 = 0; d0 < DF; d0 += FB_DT) {
    __syncthreads();
    {
      const float* xp = x + (size_t)(n0 + srow)*DF + d0 + sc*8;
      float4 v0 = *(const float4*)xp;
      float4 v1 = *(const float4*)(xp + 4);
      float e[8] = {v0.x,v0.y,v0.z,v0.w,v1.x,v1.y,v1.z,v1.w};
      short8v xv, qv;
      #pragma unroll
      for (int i = 0; i < 8; ++i) {
        xv[i] = (short)f2bf(e[i]);
        qv[i] = (short)f2bf(e[i]*e[i]);
      }
      *(short8v*)&xs[srow*FB_PITCH + sc*8]  = xv;
      *(short8v*)&x2s[srow*FB_PITCH + sc*8] = qv;
    }
    for (int u = t; u < FB_CG*4; u += 512) {
      int col = u >> 2, c = u & 3;
      *(short8v*)&Bs[col*FB_PITCH + c*8] =
        *(const short8v*)&Bmat[((size_t)(g*FB_CG + col))*DF + d0 + c*8];
    }
    __syncthreads();

    short8v xf[2];
    #pragma unroll
    for (int rt = 0; rt < 2; ++rt) xf[rt] = *(short8v*)&xs[xoff[rt]];
    #pragma unroll
    for (int ct = 0; ct < 8; ++ct) {
      short8v bfr = *(short8v*)&Bs[boff[ct]];
      #pragma unroll
      for (int rt = 0; rt < 2; ++rt)
        acc[rt][ct] = __builtin_amdgcn_mfma_f32_16x16x32_bf16(xf[rt], bfr, acc[rt][ct], 0, 0, 0);
    }
    {
      short8v bfr = *(short8v*)&Bs[boff[8]];
      short8v a0 = xf[0], a1 = xf[1];
      if (wc) {
        a0 = *(short8v*)&x2s[xoff[0]];
        a1 = *(short8v*)&x2s[xoff[1]];
      }
      acc[0][8] = __builtin_amdgcn_mfma_f32_16x16x32_bf16(a0, bfr, acc[0][8], 0, 0, 0);
      acc[1][8] = __builtin_amdgcn_mfma_f32_16x16x32_bf16(a1, bfr, acc[1][8], 0, 0, 0);
    }
  }

  __syncthreads();
  float* s1v = (float*)smem;
  float* s2h = s1v + FB_BN*17;
  if (wc == 1) {
    #pragma unroll
    for (int rt = 0; rt < 2; ++rt)
      #pragma unroll
      for (int j = 0; j < 4; ++j) {
        int row = wr*32 + rt*16 + lh*4 + j;
        s2h[row*17 + lr] = acc[rt][7][j];
        s1v[row*17 + lr] = acc[rt][8][j];
      }
  }
  __syncthreads();

  const int nyt = wc ? 7 : 9;
  #pragma unroll
  for (int ct = 0; ct < 9; ++ct) {
    if (ct < nyt) {
      int comp = wc*9 + ct;
      int kk = g*16 + comp;
      float cstk = cst[kk], muhk = muh[kk];
      #pragma unroll
      for (int rt = 0; rt < 2; ++rt)
        #pragma unroll
        for (int j = 0; j < 4; ++j) {
          float yv = acc[rt][ct][j];
          float sq = yv*yv;
          sq += __shfl_xor(sq, 1);
          sq += __shfl_xor(sq, 2);
          sq += __shfl_xor(sq, 4);
          sq += __shfl_xor(sq, 8);
          int row = wr*32 + rt*16 + lh*4 + j;
          float s1 = s1v[row*17 + comp];
          float s2 = s2h[row*17 + comp];
          float res = cstk - 0.5f*(s1 - sq - 2.f*s2 + muhk);
          if (lr == 0) out[(size_t)(n0 + row)*KCOMP + kk] = res;
        }
    }
  }
}

// ===========================================================================
extern "C" void kernel_launch(void* const* d_in, const int* in_sizes, int n_in,
                              void* d_out, int out_size, void* d_ws, size_t ws_size,
                              hipStream_t stream) {
  const float* x  = (const float*)d_in[0];
  const float* PI = (const float*)d_in[1];
  const float* MU = (const float*)d_in[2];
  const float* A  = (const float*)d_in[3];
  const float* Dm = (const float*)d_in[4];
  float* out = (float*)d_out;

  if (ws_size >= FULL_NEED) {
    uchar_t* xq   = (uchar_t*)((char*)d_ws + XQ_OFF);
    uchar_t* Bq   = (uchar_t*)((char*)d_ws + BQ_OFF);
    ushort_t* Bsk = (ushort_t*)((char*)d_ws + BSK_OFF);
    float* csk    = (float*)((char*)d_ws + CSK_OFF);

    mfa_pre<<<dim3(KCOMP), dim3(256), 0, stream>>>(PI, MU, A, Dm, Bq, Bsk, csk);
    mfa_sk2q<<<dim3(NPTS/64), dim3(256), 0, stream>>>(x, Bsk, csk, xq, out);
    mfa_gemm11<<<dim3((NPTS/128)*(2048/256)), dim3(512), 0, stream>>>(xq, Bq, out);
  } else {
    ushort_t* Bmat = (ushort_t*)d_ws;
    float* cstp = (float*)((char*)d_ws + FB_CST_OFF);
    float* muhp = (float*)((char*)d_ws + FB_MUH_OFF);
    fb_pre<<<dim3(KCOMP), dim3(256), 0, stream>>>(PI, MU, A, Dm, Bmat, cstp, muhp);
    fb_main<<<dim3(NPTS/FB_BN, FB_NG), dim3(512), 0, stream>>>(x, Bmat, cstp, muhp, out);
  }
}

// Round 13
// 149.035 us; speedup vs baseline: 1.6348x; 1.0177x over previous
//
#include <hip/hip_runtime.h>
#include <math.h>

typedef unsigned short ushort_t;
typedef unsigned char  uchar_t;
typedef __attribute__((ext_vector_type(8))) short short8v;
typedef __attribute__((ext_vector_type(4))) float f32x4;
typedef __attribute__((ext_vector_type(2))) long l64x2;

#define KCOMP 128
#define DF    1024
#define LF    16
#define NPTS  16384
#define LOG2PI 1.8378770664093453f

// ---------------- full-path ws layout (bytes) ----------------
#define XQ_OFF    ((size_t)0)
#define XQ_BYTES  ((size_t)NPTS*DF)              // 16,777,216 fp8 (K-permuted)
#define BQ_OFF    (XQ_OFF + XQ_BYTES)
#define BQ_BYTES  ((size_t)2048*DF)              // 2,097,152 fp8 (K-permuted)
#define BSK_OFF   (BQ_OFF + BQ_BYTES)
#define BSK_BYTES ((size_t)KCOMP*2*DF*2)         // 524,288 bf16
#define CSK_OFF   (BSK_OFF + BSK_BYTES)
#define FULL_NEED (CSK_OFF + 512)

__device__ __forceinline__ ushort_t f2bf(float f) {
  union { float f; unsigned u; } v; v.f = f;
  unsigned u = v.u;
  return (ushort_t)((u + 0x7FFFu + ((u >> 16) & 1u)) >> 16);
}

#define GLOAD16(gp, lp) __builtin_amdgcn_global_load_lds( \
  (const __attribute__((address_space(1))) unsigned int*)(gp), \
  (__attribute__((address_space(3))) unsigned int*)(lp), 16, 0, 0)

// DPP reduce-add within 16-lane rows (VALU only, no LDS)
#define DPPADD(x, ctrl) do { \
  int _yi = __builtin_amdgcn_update_dpp(0, __float_as_int(x), ctrl, 0xF, 0xF, true); \
  (x) += __int_as_float(_yi); } while (0)

// ---------------------------------------------------------------------------
// pre: per component k: Lm = I + A^T iD A ; chol R ; z ; csk ; then per-d:
// G = iDA R^{-T}, h = iD*mu - iDA z -> Bq fp8 (K-permuted) + Bsk bf16 [-2h;iD]
// ---------------------------------------------------------------------------
__global__ __launch_bounds__(256) void mfa_pre(
    const float* __restrict__ PI, const float* __restrict__ MU,
    const float* __restrict__ A, const float* __restrict__ Dm,
    uchar_t* __restrict__ Bq, ushort_t* __restrict__ Bsk,
    float* __restrict__ csk)
{
  const int k = blockIdx.x, t = threadIdx.x;
  const int tl = t >> 4, tm = t & 15;
  __shared__ float As[64][16];
  __shared__ float iD64[64], MU64[64];
  __shared__ float R[16][17];
  __shared__ float rinv_s[16], zsh[16], bsh[16];
  __shared__ float red[64];
  __shared__ float sc_sumlog, sc_c3;

  float accL = 0.f, accb = 0.f, c3p = 0.f, slogp = 0.f;
  for (int ch = 0; ch < 16; ++ch) {
    __syncthreads();
    ((float4*)&As[0][0])[t] =
        ((const float4*)(A + (size_t)k*DF*LF + (size_t)ch*1024))[t];
    if (t < 64) {
      float dv = Dm[k*DF + ch*64 + t];
      iD64[t] = 1.f/(dv*dv);
      MU64[t] = MU[k*DF + ch*64 + t];
    }
    __syncthreads();
    #pragma unroll 4
    for (int dd = 0; dd < 64; ++dd)
      accL = fmaf(As[dd][tl]*iD64[dd], As[dd][tm], accL);
    if (tm == 0)
      for (int dd = 0; dd < 64; ++dd)
        accb = fmaf(iD64[dd]*MU64[dd], As[dd][tl], accb);
    if (t < 64) {
      c3p = fmaf(iD64[t]*MU64[t], MU64[t], c3p);
      slogp += logf(iD64[t]);
    }
  }
  __syncthreads();
  R[tl][tm] = accL + (tl == tm ? 1.f : 0.f);
  if (tm == 0) bsh[tl] = accb;
  if (t < 64) red[t] = slogp;
  __syncthreads();
  if (t == 0) { float s = 0.f; for (int i = 0; i < 64; ++i) s += red[i]; sc_sumlog = s; }
  __syncthreads();
  if (t < 64) red[t] = c3p;
  __syncthreads();
  if (t == 0) { float s = 0.f; for (int i = 0; i < 64; ++i) s += red[i]; sc_c3 = s; }

  for (int j = 0; j < 16; ++j) {
    __syncthreads();
    if (t == j) {
      float s = R[j][j];
      for (int i = 0; i < j; ++i) s -= R[j][i]*R[j][i];
      float rj = sqrtf(s);
      R[j][j] = rj; rinv_s[j] = 1.f/rj;
    }
    __syncthreads();
    if (t < 16 && t > j) {
      float s = R[t][j];
      for (int i = 0; i < j; ++i) s -= R[t][i]*R[j][i];
      R[t][j] = s * rinv_s[j];
    }
  }
  __syncthreads();
  if (t == 0) {
    float ldet = 0.f;
    for (int j = 0; j < 16; ++j) ldet += 2.f*logf(R[j][j]);
    float w[16], z[16];
    for (int j = 0; j < 16; ++j) {
      float s = bsh[j];
      for (int i = 0; i < j; ++i) s -= R[j][i]*w[i];
      w[j] = s*rinv_s[j];
    }
    for (int j = 15; j >= 0; --j) {
      float s = w[j];
      for (int i = j+1; i < 16; ++i) s -= R[i][j]*z[i];
      z[j] = s*rinv_s[j];
      zsh[j] = z[j];
    }
    float muh = sc_c3;
    for (int l = 0; l < 16; ++l) muh -= bsh[l]*zsh[l];
    csk[k] = PI[k] - 0.5f*((float)DF*LOG2PI + ldet - sc_sumlog) - 0.5f*muh;
  }
  __syncthreads();

  for (int it = 0; it < 4; ++it) {
    const int d = t + it*256;
    float dv = Dm[k*DF + d];
    float iD = 1.f/(dv*dv);
    float mu = MU[k*DF + d];
    float v[16], gg[16];
    #pragma unroll
    for (int l = 0; l < 16; ++l) v[l] = iD * A[((size_t)k*DF + d)*LF + l];
    #pragma unroll
    for (int j = 0; j < 16; ++j) {
      float s = v[j];
      #pragma unroll
      for (int i = 0; i < 16; ++i) if (i < j) s -= R[j][i]*gg[i];
      gg[j] = s * rinv_s[j];
    }
    float h = iD*mu;
    #pragma unroll
    for (int l = 0; l < 16; ++l) h -= v[l]*zsh[l];
    const int dd = d & 63;
    const size_t poff = (size_t)(d & ~63) + ((dd >> 3) & 3)*16 + (dd >> 5)*8 + (dd & 7);
    #pragma unroll
    for (int l = 0; l < 16; ++l) {
      int r8 = __builtin_amdgcn_cvt_pk_fp8_f32(gg[l], gg[l], 0, false);
      Bq[(size_t)(k*16 + l)*DF + poff] = (uchar_t)(r8 & 0xFF);
    }
    Bsk[(size_t)k*2*DF + d]      = f2bf(-2.f*h);
    Bsk[(size_t)k*2*DF + DF + d] = f2bf(iD);
  }
}

// ---------------------------------------------------------------------------
// sk5: per 64-row block, 256 blocks x 512 thr (8 waves: rgrp = wid>>2 rows,
// wc = wid&3 comp band). Convert x -> bf16/x^2 LDS + fp8 xq (K-permuted);
// out[n,c] = csk[c] - 0.5*( x.(-2h) + x^2.iD )  (bf16 MFMA).
// Key changes vs sk2q: 8 waves (2x latency hiding) and the xq store issued
// POST-drain (store-ack retires during the MFMA phase, off the critical path).
// ---------------------------------------------------------------------------
__global__ __launch_bounds__(512) void mfa_sk5(
    const float* __restrict__ x, const ushort_t* __restrict__ Bsk,
    const float* __restrict__ csk, uchar_t* __restrict__ xq,
    float* __restrict__ out)
{
  __shared__ ushort_t xs[4096];     // [64][64] swizzled (16B-chunk ^ row&7)
  __shared__ ushort_t x2s[4096];
  __shared__ ushort_t Bs[16384];    // [256 vcols][64] swizzled (0-127 h, 128-255 iD)
  const int t = threadIdx.x, lane = t & 63, wid = t >> 6;
  const int wc = wid & 3, rgrp = wid >> 2;
  const int lr = lane & 15, lh = lane >> 4;
  const int n0 = blockIdx.x * 64;
  const int xr = t >> 3, c8 = t & 7;    // 64 rows x 8 chunks of 8 floats

  f32x4 acc[2][2] = {};

  float4 v0, v1;
  {
    const float* xp = x + (size_t)(n0 + xr)*DF + c8*8;
    v0 = ((const float4*)xp)[0]; v1 = ((const float4*)xp)[1];
  }

  for (int tt = 0; tt < 16; ++tt) {
    const int d0 = tt * 64;
    __syncthreads();                    // prev-iter LDS reads retired
    // ---- convert prefetched x: bf16 + bf16^2 -> LDS; fp8 pack -> regs ----
    long xq_pack;
    {
      float e[8] = {v0.x,v0.y,v0.z,v0.w, v1.x,v1.y,v1.z,v1.w};
      short8v b, q;
      #pragma unroll
      for (int i = 0; i < 8; ++i) {
        b[i] = (short)f2bf(e[i]);
        q[i] = (short)f2bf(e[i]*e[i]);
      }
      const int ch = c8 ^ (xr & 7);
      *(short8v*)&xs[xr*64 + ch*8]  = b;
      *(short8v*)&x2s[xr*64 + ch*8] = q;
      int p0 = 0, p1 = 0;
      p0 = __builtin_amdgcn_cvt_pk_fp8_f32(e[0], e[1], p0, false);
      p0 = __builtin_amdgcn_cvt_pk_fp8_f32(e[2], e[3], p0, true);
      p1 = __builtin_amdgcn_cvt_pk_fp8_f32(e[4], e[5], p1, false);
      p1 = __builtin_amdgcn_cvt_pk_fp8_f32(e[6], e[7], p1, true);
      xq_pack = (long)(((unsigned long long)(unsigned)p1 << 32) | (unsigned)p0);
    }
    // ---- stage B tile (32KB): 32 ids, 4 per wave ----
    #pragma unroll
    for (int jj = 0; jj < 4; ++jj) {
      int id = wid*4 + jj;
      int vc = id*8 + (lane >> 3);
      int g = (lane & 7) ^ (vc & 7);
      const ushort_t* src = (vc < 128)
        ? Bsk + (size_t)vc*(2*DF) + d0 + g*8
        : Bsk + (size_t)(vc - 128)*(2*DF) + DF + d0 + g*8;
      GLOAD16(src, (char*)Bs + id*1024);
    }
    // drain: B staging + LDS writes visible (last iter's xq store also
    // retires here, having had a full MFMA phase of slack)
    asm volatile("s_waitcnt vmcnt(0) lgkmcnt(0)" ::: "memory");
    __syncthreads();
    // ---- post-drain: xq store (fire-and-forget) + next-x prefetch ----
    {
      const size_t perm = (size_t)(c8 & 3)*16 + (size_t)(c8 >> 2)*8;
      *(long*)&xq[(size_t)(n0 + xr)*DF + d0 + perm] = xq_pack;
    }
    if (tt < 15) {
      const float* xp = x + (size_t)(n0 + xr)*DF + (d0 + 64) + c8*8;
      v0 = ((const float4*)xp)[0]; v1 = ((const float4*)xp)[1];
    }
    __builtin_amdgcn_sched_barrier(0);
    // ---- compute: wave covers rows rgrp*32..+32, comps wc*32..+32 ----
    #pragma unroll
    for (int ks = 0; ks < 2; ++ks) {
      const int cterm = ((ks*4 + lh) ^ (lr & 7)) * 8;
      short8v a_[2], a2_[2], bh[2], bi[2];
      #pragma unroll
      for (int rb = 0; rb < 2; ++rb) {
        int row = rgrp*32 + rb*16 + lr;
        a_[rb]  = *(const short8v*)&xs[row*64 + cterm];
        a2_[rb] = *(const short8v*)&x2s[row*64 + cterm];
      }
      #pragma unroll
      for (int cb = 0; cb < 2; ++cb) {
        int vh = wc*32 + cb*16 + lr;
        bh[cb] = *(const short8v*)&Bs[vh*64 + cterm];
        bi[cb] = *(const short8v*)&Bs[(128 + vh)*64 + cterm];
      }
      #pragma unroll
      for (int cb = 0; cb < 2; ++cb)
        #pragma unroll
        for (int rb = 0; rb < 2; ++rb) {
          acc[rb][cb] = __builtin_amdgcn_mfma_f32_16x16x32_bf16(a_[rb],  bh[cb], acc[rb][cb], 0,0,0);
          acc[rb][cb] = __builtin_amdgcn_mfma_f32_16x16x32_bf16(a2_[rb], bi[cb], acc[rb][cb], 0,0,0);
        }
    }
  }
  // ---- epilogue ----
  #pragma unroll
  for (int cb = 0; cb < 2; ++cb) {
    int comp = wc*32 + cb*16 + lr;
    float ck = csk[comp];
    #pragma unroll
    for (int rb = 0; rb < 2; ++rb)
      #pragma unroll
      for (int j = 0; j < 4; ++j) {
        int row = n0 + rgrp*32 + rb*16 + lh*4 + j;
        out[(size_t)row*KCOMP + comp] = ck - 0.5f*acc[rb][cb][j];
      }
  }
}

// ---------------------------------------------------------------------------
// gemm11 (R12-verified, unchanged): out += 0.5 * sum_l y_l^2 ;
// y = xq . Bq^T (fp8 e4m3, f32 acc). 3-slot LDS rotation, vmcnt(3) gate,
// 1 barrier/tile, C++ b128 reads (K-permuted pair layout), DPP epilogue.
// ---------------------------------------------------------------------------
__global__ __launch_bounds__(512, 4) void mfa_gemm11(
    const uchar_t* __restrict__ xq, const uchar_t* __restrict__ Bq,
    float* __restrict__ out)
{
  __shared__ uchar_t smem[73728];   // 3 slots x 24KB (A 8KB | B 16KB)
  const int t = threadIdx.x, lane = t & 63, wid = t >> 6;  // 8 waves
  const int wm = wid & 1, wn = wid >> 1;
  const int lr = lane & 15, lh = lane >> 4;

  const int bid = blockIdx.x;            // 1024 = 128 rb x 8 cb
  const int xcd = bid & 7, ib = bid >> 3;
  const int rb = xcd*16 + (ib >> 3);     // XCD owns 16 contiguous row-bands
  const int cb = ib & 7;
  const int n0 = rb * 128, c0 = cb * 256;

  f32x4 acc[4][4] = {};

  const int js = (((lane & 3) ^ ((lane >> 3) & 3)) * 16);
  const uchar_t* srcP[3]; int dstO[3];
  #pragma unroll
  for (int q = 0; q < 3; ++q) {
    int id = wid*3 + q;
    if (id < 8) {
      int r = id*16 + (lane >> 2);
      srcP[q] = xq + (size_t)(n0 + r)*DF + js;
      dstO[q] = id*1024;
    } else {
      int cr = (id - 8)*16 + (lane >> 2);
      srcP[q] = Bq + (size_t)(c0 + cr)*DF + js;
      dstO[q] = 8192 + (id - 8)*1024;
    }
  }
  const int rsw = (lh ^ ((lr >> 1) & 3)) * 16;
  const int aO = (wm*64 + lr)*64 + rsw;            // + rt*1024
  const int bO = 8192 + (wn*64 + lr)*64 + rsw;     // + ct*1024

  #define STAGE11(slot, tt_) do { \
    _Pragma("unroll") \
    for (int q = 0; q < 3; ++q) \
      GLOAD16(srcP[q] + (tt_)*64, (char*)smem + (slot)*24576 + dstO[q] + ((lane)*16 & 1023)); \
  } while (0)

  STAGE11(0, 0);
  STAGE11(1, 1);

  for (int tt = 0; tt < 16; ++tt) {
    if (tt < 15) asm volatile("s_waitcnt vmcnt(3)" ::: "memory");
    else         asm volatile("s_waitcnt vmcnt(0)" ::: "memory");
    __builtin_amdgcn_s_barrier();
    if (tt + 2 <= 15) STAGE11((tt + 2) % 3, tt + 2);

    const char* lb = (const char*)smem + (tt % 3) * 24576;
    l64x2 a2[4], b2[4];
    #pragma unroll
    for (int rt = 0; rt < 4; ++rt) a2[rt] = *(const l64x2*)(lb + aO + rt*1024);
    #pragma unroll
    for (int ct = 0; ct < 4; ++ct) b2[ct] = *(const l64x2*)(lb + bO + ct*1024);

    __builtin_amdgcn_s_setprio(1);
    #pragma unroll
    for (int ct = 0; ct < 4; ++ct)
      #pragma unroll
      for (int rt = 0; rt < 4; ++rt)
        acc[rt][ct] = __builtin_amdgcn_mfma_f32_16x16x32_fp8_fp8(a2[rt][0], b2[ct][0], acc[rt][ct], 0,0,0);
    #pragma unroll
    for (int ct = 0; ct < 4; ++ct)
      #pragma unroll
      for (int rt = 0; rt < 4; ++rt)
        acc[rt][ct] = __builtin_amdgcn_mfma_f32_16x16x32_fp8_fp8(a2[rt][1], b2[ct][1], acc[rt][ct], 0,0,0);
    __builtin_amdgcn_s_setprio(0);
  }

  #pragma unroll
  for (int ct = 0; ct < 4; ++ct) {
    const int comp = cb*16 + wn*4 + ct;
    #pragma unroll
    for (int rt = 0; rt < 4; ++rt) {
      #pragma unroll
      for (int j = 0; j < 4; ++j) {
        float v = acc[rt][ct][j];
        float sq = v*v;
        DPPADD(sq, 0xB1);
        DPPADD(sq, 0x4E);
        DPPADD(sq, 0x124);
        DPPADD(sq, 0x128);
        if (lr == 0) {
          int row = n0 + wm*64 + rt*16 + lh*4 + j;
          size_t idx = (size_t)row * KCOMP + comp;
          out[idx] = out[idx] + 0.5f*sq;
        }
      }
    }
  }
}

// ===========================================================================
// Fallback path (round-2 kernels, needs ~4.8 MB ws) — used if ws too small
// ===========================================================================
#define FB_NG 8
#define FB_CG 288
#define FB_BN 128
#define FB_DT 32
#define FB_PITCH 40
#define FB_BMAT_ELEMS ((size_t)(FB_NG*FB_CG)*DF)
#define FB_CST_OFF (FB_BMAT_ELEMS*2)
#define FB_MUH_OFF (FB_CST_OFF + 512)

__global__ __launch_bounds__(256) void fb_pre(
    const float* __restrict__ PI, const float* __restrict__ MU,
    const float* __restrict__ A, const float* __restrict__ Dm,
    ushort_t* __restrict__ Bmat, float* __restrict__ cst, float* __restrict__ muh)
{
  const int k = blockIdx.x, t = threadIdx.x;
  const int tl = t >> 4, tm = t & 15;
  __shared__ float As[16][16], iDsh[16], MUsh[16];
  __shared__ float R[16][17], rinv[16], zsh[16], bsh[16];
  __shared__ float red[256];

  float accL = 0.f, accb = 0.f, slog = 0.f;
  for (int d0 = 0; d0 < DF; d0 += 16) {
    __syncthreads();
    As[tl][tm] = A[((size_t)k*DF + d0 + tl)*LF + tm];
    if (t < 16) {
      float dv = Dm[k*DF + d0 + t];
      iDsh[t] = 1.f/(dv*dv);
      MUsh[t] = MU[k*DF + d0 + t];
    }
    __syncthreads();
    #pragma unroll
    for (int dd = 0; dd < 16; ++dd)
      accL = fmaf(As[dd][tl]*iDsh[dd], As[dd][tm], accL);
    if (tm == 0) {
      #pragma unroll
      for (int dd = 0; dd < 16; ++dd)
        accb = fmaf(iDsh[dd]*MUsh[dd], As[dd][tl], accb);
    }
    if (t < 16) slog += logf(iDsh[t]);
  }
  __syncthreads();
  R[tl][tm] = accL + (tl == tm ? 1.f : 0.f);
  if (tm == 0) bsh[tl] = accb;
  red[t] = (t < 16) ? slog : 0.f;
  __syncthreads();
  float sumlogiD = 0.f;
  if (t == 0) { for (int i = 0; i < 16; ++i) sumlogiD += red[i]; }

  for (int j = 0; j < 16; ++j) {
    if (t == j) {
      float s = R[j][j];
      for (int i = 0; i < j; ++i) s -= R[j][i]*R[j][i];
      float rj = sqrtf(s);
      R[j][j] = rj; rinv[j] = 1.f/rj;
    }
    __syncthreads();
    if (t < 16 && t > j) {
      float s = R[t][j];
      for (int i = 0; i < j; ++i) s -= R[t][i]*R[j][i];
      R[t][j] = s * rinv[j];
    }
    __syncthreads();
  }

  float ldet = 0.f;
  if (t == 0) {
    #pragma unroll
    for (int j = 0; j < 16; ++j) ldet += 2.f*logf(R[j][j]);
    float w[16], z[16];
    #pragma unroll
    for (int j = 0; j < 16; ++j) {
      float s = bsh[j];
      #pragma unroll
      for (int i = 0; i < 16; ++i) if (i < j) s -= R[j][i]*w[i];
      w[j] = s*rinv[j];
    }
    #pragma unroll
    for (int j = 15; j >= 0; --j) {
      float s = w[j];
      #pragma unroll
      for (int i = 0; i < 16; ++i) if (i > j) s -= R[i][j]*z[i];
      z[j] = s*rinv[j];
      zsh[j] = z[j];
    }
  }
  __syncthreads();

  const int g = k >> 4, kl = k & 15;
  ushort_t* Bgp = Bmat + (size_t)g*FB_CG*DF;
  float muhp = 0.f;
  for (int itr = 0; itr < 4; ++itr) {
    int d = t + itr*256;
    float dv = Dm[k*DF + d];
    float iD = 1.f/(dv*dv);
    float mu = MU[k*DF + d];
    float v[16], gg[16];
    #pragma unroll
    for (int l = 0; l < 16; ++l) v[l] = iD * A[((size_t)k*DF + d)*LF + l];
    #pragma unroll
    for (int j = 0; j < 16; ++j) {
      float s = v[j];
      #pragma unroll
      for (int i = 0; i < 16; ++i) if (i < j) s -= R[j][i]*gg[i];
      gg[j] = s * rinv[j];
    }
    float h = iD*mu;
    #pragma unroll
    for (int l = 0; l < 16; ++l) h -= v[l]*zsh[l];
    muhp = fmaf(mu, h, muhp);
    #pragma unroll
    for (int l = 0; l < 16; ++l)
      Bgp[(size_t)(kl*16 + l)*DF + d] = f2bf(gg[l]);
    Bgp[(size_t)(256 + kl)*DF + d] = f2bf(h);
    Bgp[(size_t)(272 + kl)*DF + d] = f2bf(iD);
  }
  red[t] = muhp;
  __syncthreads();
  for (int s = 128; s > 0; s >>= 1) {
    if (t < s) red[t] += red[t + s];
    __syncthreads();
  }
  if (t == 0) {
    muh[k] = red[0];
    cst[k] = PI[k] - 0.5f*((float)DF*LOG2PI + ldet - sumlogiD);
  }
}

__global__ __launch_bounds__(512, 2) void fb_main(
    const float* __restrict__ x, const ushort_t* __restrict__ Bmat,
    const float* __restrict__ cst, const float* __restrict__ muh,
    float* __restrict__ out)
{
  __shared__ __align__(16) ushort_t smem[2*FB_BN*FB_PITCH + FB_CG*FB_PITCH];
  ushort_t* xs  = smem;
  ushort_t* x2s = smem + FB_BN*FB_PITCH;
  ushort_t* Bs  = smem + 2*FB_BN*FB_PITCH;

  const int t = threadIdx.x;
  const int lane = t & 63, wid = t >> 6;
  const int wr = wid & 3, wc = wid >> 2;
  const int lr = lane & 15, lh = lane >> 4;
  const int n0 = blockIdx.x * FB_BN;
  const int g  = blockIdx.y;

  f32x4 acc[2][9] = {};
  const int srow = t >> 2, sc = t & 3;

  int xoff[2];
  #pragma unroll
  for (int rt = 0; rt < 2; ++rt)
    xoff[rt] = (wr*32 + rt*16 + lr)*FB_PITCH + lh*8;
  int boff[9];
  #pragma unroll
  for (int ct = 0; ct < 9; ++ct)
    boff[ct] = (wc*144 + ct*16 + lr)*FB_PITCH + lh*8;

  for (int d0 = 0; d0 < DF; d0 += FB_DT) {
    __syncthreads();
    {
      const float* xp = x + (size_t)(n0 + srow)*DF + d0 + sc*8;
      float4 v0 = *(const float4*)xp;
      float4 v1 = *(const float4*)(xp + 4);
      float e[8] = {v0.x,v0.y,v0.z,v0.w,v1.x,v1.y,v1.z,v1.w};
      short8v xv, qv;
      #pragma unroll
      for (int i = 0; i < 8; ++i) {
        xv[i] = (short)f2bf(e[i]);
        qv[i] = (short)f2bf(e[i]*e[i]);
      }
      *(short8v*)&xs[srow*FB_PITCH + sc*8]  = xv;
      *(short8v*)&x2s[srow*FB_PITCH + sc*8] = qv;
    }
    for (int u = t; u < FB_CG*4; u += 512) {
      int col = u >> 2, c = u & 3;
      *(short8v*)&Bs[col*FB_PITCH + c*8] =
        *(const short8v*)&Bmat[((size_t)(g*FB_CG + col))*DF + d0 + c*8];
    }
    __syncthreads();

    short8v xf[2];
    #pragma unroll
    for (int rt = 0; rt < 2; ++rt) xf[rt] = *(short8v*)&xs[xoff[rt]];
    #pragma unroll
    for (int ct = 0; ct < 8; ++ct) {
      short8v bfr = *(short8v*)&Bs[boff[ct]];
      #pragma unroll
      for (int rt = 0; rt < 2; ++rt)
        acc[rt][ct] = __builtin_amdgcn_mfma_f32_16x16x32_bf16(xf[rt], bfr, acc[rt][ct], 0, 0, 0);
    }
    {
      short8v bfr = *(short8v*)&Bs[boff[8]];
      short8v a0 = xf[0], a1 = xf[1];
      if (wc) {
        a0 = *(short8v*)&x2s[xoff[0]];
        a1 = *(short8v*)&x2s[xoff[1]];
      }
      acc[0][8] = __builtin_amdgcn_mfma_f32_16x16x32_bf16(a0, bfr, acc[0][8], 0, 0, 0);
      acc[1][8] = __builtin_amdgcn_mfma_f32_16x16x32_bf16(a1, bfr, acc[1][8], 0, 0, 0);
    }
  }

  __syncthreads();
  float* s1v = (float*)smem;
  float* s2h = s1v + FB_BN*17;
  if (wc == 1) {
    #pragma unroll
    for (int rt = 0; rt < 2; ++rt)
      #pragma unroll
      for (int j = 0; j < 4; ++j) {
        int row = wr*32 + rt*16 + lh*4 + j;
        s2h[row*17 + lr] = acc[rt][7][j];
        s1v[row*17 + lr] = acc[rt][8][j];
      }
  }
  __syncthreads();

  const int nyt = wc ? 7 : 9;
  #pragma unroll
  for (int ct = 0; ct < 9; ++ct) {
    if (ct < nyt) {
      int comp = wc*9 + ct;
      int kk = g*16 + comp;
      float cstk = cst[kk], muhk = muh[kk];
      #pragma unroll
      for (int rt = 0; rt < 2; ++rt)
        #pragma unroll
        for (int j = 0; j < 4; ++j) {
          float yv = acc[rt][ct][j];
          float sq = yv*yv;
          sq += __shfl_xor(sq, 1);
          sq += __shfl_xor(sq, 2);
          sq += __shfl_xor(sq, 4);
          sq += __shfl_xor(sq, 8);
          int row = wr*32 + rt*16 + lh*4 + j;
          float s1 = s1v[row*17 + comp];
          float s2 = s2h[row*17 + comp];
          float res = cstk - 0.5f*(s1 - sq - 2.f*s2 + muhk);
          if (lr == 0) out[(size_t)(n0 + row)*KCOMP + kk] = res;
        }
    }
  }
}

// ===========================================================================
extern "C" void kernel_launch(void* const* d_in, const int* in_sizes, int n_in,
                              void* d_out, int out_size, void* d_ws, size_t ws_size,
                              hipStream_t stream) {
  const float* x  = (const float*)d_in[0];
  const float* PI = (const float*)d_in[1];
  const float* MU = (const float*)d_in[2];
  const float* A  = (const float*)d_in[3];
  const float* Dm = (const float*)d_in[4];
  float* out = (float*)d_out;

  if (ws_size >= FULL_NEED) {
    uchar_t* xq   = (uchar_t*)((char*)d_ws + XQ_OFF);
    uchar_t* Bq   = (uchar_t*)((char*)d_ws + BQ_OFF);
    ushort_t* Bsk = (ushort_t*)((char*)d_ws + BSK_OFF);
    float* csk    = (float*)((char*)d_ws + CSK_OFF);

    mfa_pre<<<dim3(KCOMP), dim3(256), 0, stream>>>(PI, MU, A, Dm, Bq, Bsk, csk);
    mfa_sk5<<<dim3(NPTS/64), dim3(512), 0, stream>>>(x, Bsk, csk, xq, out);
    mfa_gemm11<<<dim3((NPTS/128)*(2048/256)), dim3(512), 0, stream>>>(xq, Bq, out);
  } else {
    ushort_t* Bmat = (ushort_t*)d_ws;
    float* cstp = (float*)((char*)d_ws + FB_CST_OFF);
    float* muhp = (float*)((char*)d_ws + FB_MUH_OFF);
    fb_pre<<<dim3(KCOMP), dim3(256), 0, stream>>>(PI, MU, A, Dm, Bmat, cstp, muhp);
    fb_main<<<dim3(NPTS/FB_BN, FB_NG), dim3(512), 0, stream>>>(x, Bmat, cstp, muhp, out);
  }
}

// Round 14
// 129.536 us; speedup vs baseline: 1.8809x; 1.1505x over previous
//
#include <hip/hip_runtime.h>
#include <math.h>

typedef unsigned short ushort_t;
typedef unsigned char  uchar_t;
typedef __attribute__((ext_vector_type(8))) short short8v;
typedef __attribute__((ext_vector_type(4))) float f32x4;
typedef __attribute__((ext_vector_type(2))) long l64x2;

#define KCOMP 128
#define DF    1024
#define LF    16
#define NPTS  16384
#define LOG2PI 1.8378770664093453f

// ---------------- full-path ws layout (bytes) ----------------
#define XQ_OFF    ((size_t)0)
#define XQ_BYTES  ((size_t)NPTS*DF)              // 16,777,216 fp8 (K-permuted)
#define BQ_OFF    (XQ_OFF + XQ_BYTES)
#define BQ_BYTES  ((size_t)2048*DF)              // 2,097,152 fp8 (K-permuted)
#define BSK_OFF   (BQ_OFF + BQ_BYTES)
#define BSK_BYTES ((size_t)KCOMP*2*DF*2)         // 524,288 bf16
#define CSK_OFF   (BSK_OFF + BSK_BYTES)
#define FULL_NEED (CSK_OFF + 512)

__device__ __forceinline__ ushort_t f2bf(float f) {
  union { float f; unsigned u; } v; v.f = f;
  unsigned u = v.u;
  return (ushort_t)((u + 0x7FFFu + ((u >> 16) & 1u)) >> 16);
}

#define GLOAD16(gp, lp) __builtin_amdgcn_global_load_lds( \
  (const __attribute__((address_space(1))) unsigned int*)(gp), \
  (__attribute__((address_space(3))) unsigned int*)(lp), 16, 0, 0)

// DPP reduce-add within 16-lane rows (VALU only, no LDS)
#define DPPADD(x, ctrl) do { \
  int _yi = __builtin_amdgcn_update_dpp(0, __float_as_int(x), ctrl, 0xF, 0xF, true); \
  (x) += __int_as_float(_yi); } while (0)

// ---------------------------------------------------------------------------
// pre_v3: 128 blocks x 1024 thr. Stage ALL of A/iD/MU to LDS once (2 barriers
// vs 32); Gram Lm = I + A^T iD A split 4-way over d + LDS reduce; Cholesky;
// z-solve; then per-d (1 d per thread): G col-solve, h ->
// Bq fp8 (K-permuted) + Bsk bf16 [-2h ; iD] + csk.
// ---------------------------------------------------------------------------
__global__ __launch_bounds__(1024) void mfa_pre(
    const float* __restrict__ PI, const float* __restrict__ MU,
    const float* __restrict__ A, const float* __restrict__ Dm,
    uchar_t* __restrict__ Bq, ushort_t* __restrict__ Bsk,
    float* __restrict__ csk)
{
  const int k = blockIdx.x, t = threadIdx.x;      // t in [0,1024)
  __shared__ float As[DF*LF];      // 64 KB, As[d*16 + l]
  __shared__ float iDs[DF];        // 4 KB
  __shared__ float MUs[DF];        // 4 KB
  __shared__ float red[1024];      // 4 KB
  __shared__ float bpart[4][16];
  __shared__ float R[16][17];
  __shared__ float rinv_s[16], zsh[16], bsh[16];
  __shared__ float sc_sumlog, sc_c3;

  // ---- stage A (coalesced float4), iD, MU ----
  {
    const float4* Ag = (const float4*)(A + (size_t)k*DF*LF);
    float4* Al = (float4*)As;
    #pragma unroll
    for (int i = 0; i < 4; ++i) Al[t + i*1024] = Ag[t + i*1024];
    float dv = Dm[(size_t)k*DF + t];
    iDs[t] = 1.f/(dv*dv);
    MUs[t] = MU[(size_t)k*DF + t];
  }
  __syncthreads();

  // ---- Gram: entry e=(tl,tm), quad q covers d in [q*256, q*256+256) ----
  const int e = t & 255, q = t >> 8;
  const int tl = e >> 4, tm = e & 15;
  {
    float acc = 0.f;
    const int d0 = q*256;
    #pragma unroll 4
    for (int dd = 0; dd < 256; ++dd) {
      int d = d0 + dd;
      acc = fmaf(As[d*16+tl]*iDs[d], As[d*16+tm], acc);
    }
    red[t] = acc;
  }
  if (e < 16) {            // b_l partials (lanes 0-15 of wave q*4)
    float accb = 0.f;
    const int d0 = q*256;
    for (int dd = 0; dd < 256; ++dd) {
      int d = d0 + dd;
      accb = fmaf(iDs[d]*MUs[d], As[d*16+e], accb);
    }
    bpart[q][e] = accb;
  }
  __syncthreads();
  if (q == 0) {
    float s = red[e] + red[e+256] + red[e+512] + red[e+768];
    R[tl][tm] = s + (tl == tm ? 1.f : 0.f);
  }
  if (t < 16) bsh[t] = bpart[0][t] + bpart[1][t] + bpart[2][t] + bpart[3][t];
  __syncthreads();

  // ---- c3 = sum iD mu^2 ----
  red[t] = iDs[t]*MUs[t]*MUs[t];
  __syncthreads();
  if (t < 256) red[t] = red[t] + red[t+256] + red[t+512] + red[t+768];
  __syncthreads();
  if (t < 64) red[t] = red[t] + red[t+64] + red[t+128] + red[t+192];
  __syncthreads();
  if (t == 0) { float s = 0.f; for (int i = 0; i < 64; ++i) s += red[i]; sc_c3 = s; }
  __syncthreads();
  // ---- sumlog = sum log iD ----
  red[t] = logf(iDs[t]);
  __syncthreads();
  if (t < 256) red[t] = red[t] + red[t+256] + red[t+512] + red[t+768];
  __syncthreads();
  if (t < 64) red[t] = red[t] + red[t+64] + red[t+128] + red[t+192];
  __syncthreads();
  if (t == 0) { float s = 0.f; for (int i = 0; i < 64; ++i) s += red[i]; sc_sumlog = s; }

  // ---- Cholesky (lower), SPD diag-dominant ----
  for (int j = 0; j < 16; ++j) {
    __syncthreads();
    if (t == j) {
      float s = R[j][j];
      for (int i = 0; i < j; ++i) s -= R[j][i]*R[j][i];
      float rj = sqrtf(s);
      R[j][j] = rj; rinv_s[j] = 1.f/rj;
    }
    __syncthreads();
    if (t < 16 && t > j) {
      float s = R[t][j];
      for (int i = 0; i < j; ++i) s -= R[t][i]*R[j][i];
      R[t][j] = s * rinv_s[j];
    }
  }
  __syncthreads();
  if (t == 0) {
    float ldet = 0.f;
    for (int j = 0; j < 16; ++j) ldet += 2.f*logf(R[j][j]);
    float w[16], z[16];
    for (int j = 0; j < 16; ++j) {
      float s = bsh[j];
      for (int i = 0; i < j; ++i) s -= R[j][i]*w[i];
      w[j] = s*rinv_s[j];
    }
    for (int j = 15; j >= 0; --j) {
      float s = w[j];
      for (int i = j+1; i < 16; ++i) s -= R[i][j]*z[i];
      z[j] = s*rinv_s[j];
      zsh[j] = z[j];
    }
    float muh = sc_c3;
    for (int l = 0; l < 16; ++l) muh -= bsh[l]*zsh[l];
    csk[k] = PI[k] - 0.5f*((float)DF*LOG2PI + ldet - sc_sumlog) - 0.5f*muh;
  }
  __syncthreads();

  // ---- per-d outputs: each thread handles d = t (A from global, coalesced) ----
  {
    const int d = t;
    float iD = iDs[d];
    float mu = MUs[d];
    float v[16], gg[16];
    #pragma unroll
    for (int l = 0; l < 16; ++l) v[l] = iD * A[((size_t)k*DF + d)*LF + l];
    #pragma unroll
    for (int j = 0; j < 16; ++j) {
      float s = v[j];
      #pragma unroll
      for (int i = 0; i < 16; ++i) if (i < j) s -= R[j][i]*gg[i];
      gg[j] = s * rinv_s[j];
    }
    float h = iD*mu;
    #pragma unroll
    for (int l = 0; l < 16; ++l) h -= v[l]*zsh[l];
    const int dd = d & 63;
    const size_t poff = (size_t)(d & ~63) + ((dd >> 3) & 3)*16 + (dd >> 5)*8 + (dd & 7);
    #pragma unroll
    for (int l = 0; l < 16; ++l) {
      int r8 = __builtin_amdgcn_cvt_pk_fp8_f32(gg[l], gg[l], 0, false);
      Bq[(size_t)(k*16 + l)*DF + poff] = (uchar_t)(r8 & 0xFF);
    }
    Bsk[(size_t)k*2*DF + d]      = f2bf(-2.f*h);
    Bsk[(size_t)k*2*DF + DF + d] = f2bf(iD);
  }
}

// ---------------------------------------------------------------------------
// sk5 (R13-verified, unchanged): per 64-row block, 256 blocks x 512 thr.
// Convert x -> bf16/x^2 LDS + fp8 xq (K-permuted);
// out[n,c] = csk[c] - 0.5*( x.(-2h) + x^2.iD )  (bf16 MFMA).
// ---------------------------------------------------------------------------
__global__ __launch_bounds__(512) void mfa_sk5(
    const float* __restrict__ x, const ushort_t* __restrict__ Bsk,
    const float* __restrict__ csk, uchar_t* __restrict__ xq,
    float* __restrict__ out)
{
  __shared__ ushort_t xs[4096];     // [64][64] swizzled (16B-chunk ^ row&7)
  __shared__ ushort_t x2s[4096];
  __shared__ ushort_t Bs[16384];    // [256 vcols][64] swizzled (0-127 h, 128-255 iD)
  const int t = threadIdx.x, lane = t & 63, wid = t >> 6;
  const int wc = wid & 3, rgrp = wid >> 2;
  const int lr = lane & 15, lh = lane >> 4;
  const int n0 = blockIdx.x * 64;
  const int xr = t >> 3, c8 = t & 7;    // 64 rows x 8 chunks of 8 floats

  f32x4 acc[2][2] = {};

  float4 v0, v1;
  {
    const float* xp = x + (size_t)(n0 + xr)*DF + c8*8;
    v0 = ((const float4*)xp)[0]; v1 = ((const float4*)xp)[1];
  }

  for (int tt = 0; tt < 16; ++tt) {
    const int d0 = tt * 64;
    __syncthreads();                    // prev-iter LDS reads retired
    long xq_pack;
    {
      float e[8] = {v0.x,v0.y,v0.z,v0.w, v1.x,v1.y,v1.z,v1.w};
      short8v b, q;
      #pragma unroll
      for (int i = 0; i < 8; ++i) {
        b[i] = (short)f2bf(e[i]);
        q[i] = (short)f2bf(e[i]*e[i]);
      }
      const int ch = c8 ^ (xr & 7);
      *(short8v*)&xs[xr*64 + ch*8]  = b;
      *(short8v*)&x2s[xr*64 + ch*8] = q;
      int p0 = 0, p1 = 0;
      p0 = __builtin_amdgcn_cvt_pk_fp8_f32(e[0], e[1], p0, false);
      p0 = __builtin_amdgcn_cvt_pk_fp8_f32(e[2], e[3], p0, true);
      p1 = __builtin_amdgcn_cvt_pk_fp8_f32(e[4], e[5], p1, false);
      p1 = __builtin_amdgcn_cvt_pk_fp8_f32(e[6], e[7], p1, true);
      xq_pack = (long)(((unsigned long long)(unsigned)p1 << 32) | (unsigned)p0);
    }
    #pragma unroll
    for (int jj = 0; jj < 4; ++jj) {
      int id = wid*4 + jj;
      int vc = id*8 + (lane >> 3);
      int g = (lane & 7) ^ (vc & 7);
      const ushort_t* src = (vc < 128)
        ? Bsk + (size_t)vc*(2*DF) + d0 + g*8
        : Bsk + (size_t)(vc - 128)*(2*DF) + DF + d0 + g*8;
      GLOAD16(src, (char*)Bs + id*1024);
    }
    asm volatile("s_waitcnt vmcnt(0) lgkmcnt(0)" ::: "memory");
    __syncthreads();
    {
      const size_t perm = (size_t)(c8 & 3)*16 + (size_t)(c8 >> 2)*8;
      *(long*)&xq[(size_t)(n0 + xr)*DF + d0 + perm] = xq_pack;
    }
    if (tt < 15) {
      const float* xp = x + (size_t)(n0 + xr)*DF + (d0 + 64) + c8*8;
      v0 = ((const float4*)xp)[0]; v1 = ((const float4*)xp)[1];
    }
    __builtin_amdgcn_sched_barrier(0);
    #pragma unroll
    for (int ks = 0; ks < 2; ++ks) {
      const int cterm = ((ks*4 + lh) ^ (lr & 7)) * 8;
      short8v a_[2], a2_[2], bh[2], bi[2];
      #pragma unroll
      for (int rb = 0; rb < 2; ++rb) {
        int row = rgrp*32 + rb*16 + lr;
        a_[rb]  = *(const short8v*)&xs[row*64 + cterm];
        a2_[rb] = *(const short8v*)&x2s[row*64 + cterm];
      }
      #pragma unroll
      for (int cb = 0; cb < 2; ++cb) {
        int vh = wc*32 + cb*16 + lr;
        bh[cb] = *(const short8v*)&Bs[vh*64 + cterm];
        bi[cb] = *(const short8v*)&Bs[(128 + vh)*64 + cterm];
      }
      #pragma unroll
      for (int cb = 0; cb < 2; ++cb)
        #pragma unroll
        for (int rb = 0; rb < 2; ++rb) {
          acc[rb][cb] = __builtin_amdgcn_mfma_f32_16x16x32_bf16(a_[rb],  bh[cb], acc[rb][cb], 0,0,0);
          acc[rb][cb] = __builtin_amdgcn_mfma_f32_16x16x32_bf16(a2_[rb], bi[cb], acc[rb][cb], 0,0,0);
        }
    }
  }
  #pragma unroll
  for (int cb = 0; cb < 2; ++cb) {
    int comp = wc*32 + cb*16 + lr;
    float ck = csk[comp];
    #pragma unroll
    for (int rb = 0; rb < 2; ++rb)
      #pragma unroll
      for (int j = 0; j < 4; ++j) {
        int row = n0 + rgrp*32 + rb*16 + lh*4 + j;
        out[(size_t)row*KCOMP + comp] = ck - 0.5f*acc[rb][cb][j];
      }
  }
}

// ---------------------------------------------------------------------------
// gemm11 (R12-verified, unchanged): out += 0.5 * sum_l y_l^2 ;
// y = xq . Bq^T (fp8 e4m3, f32 acc). 3-slot LDS rotation, vmcnt(3) gate,
// 1 barrier/tile, C++ b128 reads (K-permuted pair layout), DPP epilogue.
// ---------------------------------------------------------------------------
__global__ __launch_bounds__(512, 4) void mfa_gemm11(
    const uchar_t* __restrict__ xq, const uchar_t* __restrict__ Bq,
    float* __restrict__ out)
{
  __shared__ uchar_t smem[73728];   // 3 slots x 24KB (A 8KB | B 16KB)
  const int t = threadIdx.x, lane = t & 63, wid = t >> 6;  // 8 waves
  const int wm = wid & 1, wn = wid >> 1;
  const int lr = lane & 15, lh = lane >> 4;

  const int bid = blockIdx.x;            // 1024 = 128 rb x 8 cb
  const int xcd = bid & 7, ib = bid >> 3;
  const int rb = xcd*16 + (ib >> 3);     // XCD owns 16 contiguous row-bands
  const int cb = ib & 7;
  const int n0 = rb * 128, c0 = cb * 256;

  f32x4 acc[4][4] = {};

  const int js = (((lane & 3) ^ ((lane >> 3) & 3)) * 16);
  const uchar_t* srcP[3]; int dstO[3];
  #pragma unroll
  for (int q = 0; q < 3; ++q) {
    int id = wid*3 + q;
    if (id < 8) {
      int r = id*16 + (lane >> 2);
      srcP[q] = xq + (size_t)(n0 + r)*DF + js;
      dstO[q] = id*1024;
    } else {
      int cr = (id - 8)*16 + (lane >> 2);
      srcP[q] = Bq + (size_t)(c0 + cr)*DF + js;
      dstO[q] = 8192 + (id - 8)*1024;
    }
  }
  const int rsw = (lh ^ ((lr >> 1) & 3)) * 16;
  const int aO = (wm*64 + lr)*64 + rsw;            // + rt*1024
  const int bO = 8192 + (wn*64 + lr)*64 + rsw;     // + ct*1024

  #define STAGE11(slot, tt_) do { \
    _Pragma("unroll") \
    for (int q = 0; q < 3; ++q) \
      GLOAD16(srcP[q] + (tt_)*64, (char*)smem + (slot)*24576 + dstO[q] + ((lane)*16 & 1023)); \
  } while (0)

  STAGE11(0, 0);
  STAGE11(1, 1);

  for (int tt = 0; tt < 16; ++tt) {
    if (tt < 15) asm volatile("s_waitcnt vmcnt(3)" ::: "memory");
    else         asm volatile("s_waitcnt vmcnt(0)" ::: "memory");
    __builtin_amdgcn_s_barrier();
    if (tt + 2 <= 15) STAGE11((tt + 2) % 3, tt + 2);

    const char* lb = (const char*)smem + (tt % 3) * 24576;
    l64x2 a2[4], b2[4];
    #pragma unroll
    for (int rt = 0; rt < 4; ++rt) a2[rt] = *(const l64x2*)(lb + aO + rt*1024);
    #pragma unroll
    for (int ct = 0; ct < 4; ++ct) b2[ct] = *(const l64x2*)(lb + bO + ct*1024);

    __builtin_amdgcn_s_setprio(1);
    #pragma unroll
    for (int ct = 0; ct < 4; ++ct)
      #pragma unroll
      for (int rt = 0; rt < 4; ++rt)
        acc[rt][ct] = __builtin_amdgcn_mfma_f32_16x16x32_fp8_fp8(a2[rt][0], b2[ct][0], acc[rt][ct], 0,0,0);
    #pragma unroll
    for (int ct = 0; ct < 4; ++ct)
      #pragma unroll
      for (int rt = 0; rt < 4; ++rt)
        acc[rt][ct] = __builtin_amdgcn_mfma_f32_16x16x32_fp8_fp8(a2[rt][1], b2[ct][1], acc[rt][ct], 0,0,0);
    __builtin_amdgcn_s_setprio(0);
  }

  #pragma unroll
  for (int ct = 0; ct < 4; ++ct) {
    const int comp = cb*16 + wn*4 + ct;
    #pragma unroll
    for (int rt = 0; rt < 4; ++rt) {
      #pragma unroll
      for (int j = 0; j < 4; ++j) {
        float v = acc[rt][ct][j];
        float sq = v*v;
        DPPADD(sq, 0xB1);
        DPPADD(sq, 0x4E);
        DPPADD(sq, 0x124);
        DPPADD(sq, 0x128);
        if (lr == 0) {
          int row = n0 + wm*64 + rt*16 + lh*4 + j;
          size_t idx = (size_t)row * KCOMP + comp;
          out[idx] = out[idx] + 0.5f*sq;
        }
      }
    }
  }
}

// ===========================================================================
// Fallback path (round-2 kernels, needs ~4.8 MB ws) — used if ws too small
// ===========================================================================
#define FB_NG 8
#define FB_CG 288
#define FB_BN 128
#define FB_DT 32
#define FB_PITCH 40
#define FB_BMAT_ELEMS ((size_t)(FB_NG*FB_CG)*DF)
#define FB_CST_OFF (FB_BMAT_ELEMS*2)
#define FB_MUH_OFF (FB_CST_OFF + 512)

__global__ __launch_bounds__(256) void fb_pre(
    const float* __restrict__ PI, const float* __restrict__ MU,
    const float* __restrict__ A, const float* __restrict__ Dm,
    ushort_t* __restrict__ Bmat, float* __restrict__ cst, float* __restrict__ muh)
{
  const int k = blockIdx.x, t = threadIdx.x;
  const int tl = t >> 4, tm = t & 15;
  __shared__ float As[16][16], iDsh[16], MUsh[16];
  __shared__ float R[16][17], rinv[16], zsh[16], bsh[16];
  __shared__ float red[256];

  float accL = 0.f, accb = 0.f, slog = 0.f;
  for (int d0 = 0; d0 < DF; d0 += 16) {
    __syncthreads();
    As[tl][tm] = A[((size_t)k*DF + d0 + tl)*LF + tm];
    if (t < 16) {
      float dv = Dm[k*DF + d0 + t];
      iDsh[t] = 1.f/(dv*dv);
      MUsh[t] = MU[k*DF + d0 + t];
    }
    __syncthreads();
    #pragma unroll
    for (int dd = 0; dd < 16; ++dd)
      accL = fmaf(As[dd][tl]*iDsh[dd], As[dd][tm], accL);
    if (tm == 0) {
      #pragma unroll
      for (int dd = 0; dd < 16; ++dd)
        accb = fmaf(iDsh[dd]*MUsh[dd], As[dd][tl], accb);
    }
    if (t < 16) slog += logf(iDsh[t]);
  }
  __syncthreads();
  R[tl][tm] = accL + (tl == tm ? 1.f : 0.f);
  if (tm == 0) bsh[tl] = accb;
  red[t] = (t < 16) ? slog : 0.f;
  __syncthreads();
  float sumlogiD = 0.f;
  if (t == 0) { for (int i = 0; i < 16; ++i) sumlogiD += red[i]; }

  for (int j = 0; j < 16; ++j) {
    if (t == j) {
      float s = R[j][j];
      for (int i = 0; i < j; ++i) s -= R[j][i]*R[j][i];
      float rj = sqrtf(s);
      R[j][j] = rj; rinv[j] = 1.f/rj;
    }
    __syncthreads();
    if (t < 16 && t > j) {
      float s = R[t][j];
      for (int i = 0; i < j; ++i) s -= R[t][i]*R[j][i];
      R[t][j] = s * rinv[j];
    }
    __syncthreads();
  }

  float ldet = 0.f;
  if (t == 0) {
    #pragma unroll
    for (int j = 0; j < 16; ++j) ldet += 2.f*logf(R[j][j]);
    float w[16], z[16];
    #pragma unroll
    for (int j = 0; j < 16; ++j) {
      float s = bsh[j];
      #pragma unroll
      for (int i = 0; i < 16; ++i) if (i < j) s -= R[j][i]*w[i];
      w[j] = s*rinv[j];
    }
    #pragma unroll
    for (int j = 15; j >= 0; --j) {
      float s = w[j];
      #pragma unroll
      for (int i = 0; i < 16; ++i) if (i > j) s -= R[i][j]*z[i];
      z[j] = s*rinv[j];
      zsh[j] = z[j];
    }
  }
  __syncthreads();

  const int g = k >> 4, kl = k & 15;
  ushort_t* Bgp = Bmat + (size_t)g*FB_CG*DF;
  float muhp = 0.f;
  for (int itr = 0; itr < 4; ++itr) {
    int d = t + itr*256;
    float dv = Dm[k*DF + d];
    float iD = 1.f/(dv*dv);
    float mu = MU[k*DF + d];
    float v[16], gg[16];
    #pragma unroll
    for (int l = 0; l < 16; ++l) v[l] = iD * A[((size_t)k*DF + d)*LF + l];
    #pragma unroll
    for (int j = 0; j < 16; ++j) {
      float s = v[j];
      #pragma unroll
      for (int i = 0; i < 16; ++i) if (i < j) s -= R[j][i]*gg[i];
      gg[j] = s * rinv[j];
    }
    float h = iD*mu;
    #pragma unroll
    for (int l = 0; l < 16; ++l) h -= v[l]*zsh[l];
    muhp = fmaf(mu, h, muhp);
    #pragma unroll
    for (int l = 0; l < 16; ++l)
      Bgp[(size_t)(kl*16 + l)*DF + d] = f2bf(gg[l]);
    Bgp[(size_t)(256 + kl)*DF + d] = f2bf(h);
    Bgp[(size_t)(272 + kl)*DF + d] = f2bf(iD);
  }
  red[t] = muhp;
  __syncthreads();
  for (int s = 128; s > 0; s >>= 1) {
    if (t < s) red[t] += red[t + s];
    __syncthreads();
  }
  if (t == 0) {
    muh[k] = red[0];
    cst[k] = PI[k] - 0.5f*((float)DF*LOG2PI + ldet - sumlogiD);
  }
}

__global__ __launch_bounds__(512, 2) void fb_main(
    const float* __restrict__ x, const ushort_t* __restrict__ Bmat,
    const float* __restrict__ cst, const float* __restrict__ muh,
    float* __restrict__ out)
{
  __shared__ __align__(16) ushort_t smem[2*FB_BN*FB_PITCH + FB_CG*FB_PITCH];
  ushort_t* xs  = smem;
  ushort_t* x2s = smem + FB_BN*FB_PITCH;
  ushort_t* Bs  = smem + 2*FB_BN*FB_PITCH;

  const int t = threadIdx.x;
  const int lane = t & 63, wid = t >> 6;
  const int wr = wid & 3, wc = wid >> 2;
  const int lr = lane & 15, lh = lane >> 4;
  const int n0 = blockIdx.x * FB_BN;
  const int g  = blockIdx.y;

  f32x4 acc[2][9] = {};
  const int srow = t >> 2, sc = t & 3;

  int xoff[2];
  #pragma unroll
  for (int rt = 0; rt < 2; ++rt)
    xoff[rt] = (wr*32 + rt*16 + lr)*FB_PITCH + lh*8;
  int boff[9];
  #pragma unroll
  for (int ct = 0; ct < 9; ++ct)
    boff[ct] = (wc*144 + ct*16 + lr)*FB_PITCH + lh*8;

  for (int d0 = 0; d0 < DF; d0 += FB_DT) {
    __syncthreads();
    {
      const float* xp = x + (size_t)(n0 + srow)*DF + d0 + sc*8;
      float4 v0 = *(const float4*)xp;
      float4 v1 = *(const float4*)(xp + 4);
      float e[8] = {v0.x,v0.y,v0.z,v0.w,v1.x,v1.y,v1.z,v1.w};
      short8v xv, qv;
      #pragma unroll
      for (int i = 0; i < 8; ++i) {
        xv[i] = (short)f2bf(e[i]);
        qv[i] = (short)f2bf(e[i]*e[i]);
      }
      *(short8v*)&xs[srow*FB_PITCH + sc*8]  = xv;
      *(short8v*)&x2s[srow*FB_PITCH + sc*8] = qv;
    }
    for (int u = t; u < FB_CG*4; u += 512) {
      int col = u >> 2, c = u & 3;
      *(short8v*)&Bs[col*FB_PITCH + c*8] =
        *(const short8v*)&Bmat[((size_t)(g*FB_CG + col))*DF + d0 + c*8];
    }
    __syncthreads();

    short8v xf[2];
    #pragma unroll
    for (int rt = 0; rt < 2; ++rt) xf[rt] = *(short8v*)&xs[xoff[rt]];
    #pragma unroll
    for (int ct = 0; ct < 8; ++ct) {
      short8v bfr = *(short8v*)&Bs[boff[ct]];
      #pragma unroll
      for (int rt = 0; rt < 2; ++rt)
        acc[rt][ct] = __builtin_amdgcn_mfma_f32_16x16x32_bf16(xf[rt], bfr, acc[rt][ct], 0, 0, 0);
    }
    {
      short8v bfr = *(short8v*)&Bs[boff[8]];
      short8v a0 = xf[0], a1 = xf[1];
      if (wc) {
        a0 = *(short8v*)&x2s[xoff[0]];
        a1 = *(short8v*)&x2s[xoff[1]];
      }
      acc[0][8] = __builtin_amdgcn_mfma_f32_16x16x32_bf16(a0, bfr, acc[0][8], 0, 0, 0);
      acc[1][8] = __builtin_amdgcn_mfma_f32_16x16x32_bf16(a1, bfr, acc[1][8], 0, 0, 0);
    }
  }

  __syncthreads();
  float* s1v = (float*)smem;
  float* s2h = s1v + FB_BN*17;
  if (wc == 1) {
    #pragma unroll
    for (int rt = 0; rt < 2; ++rt)
      #pragma unroll
      for (int j = 0; j < 4; ++j) {
        int row = wr*32 + rt*16 + lh*4 + j;
        s2h[row*17 + lr] = acc[rt][7][j];
        s1v[row*17 + lr] = acc[rt][8][j];
      }
  }
  __syncthreads();

  const int nyt = wc ? 7 : 9;
  #pragma unroll
  for (int ct = 0; ct < 9; ++ct) {
    if (ct < nyt) {
      int comp = wc*9 + ct;
      int kk = g*16 + comp;
      float cstk = cst[kk], muhk = muh[kk];
      #pragma unroll
      for (int rt = 0; rt < 2; ++rt)
        #pragma unroll
        for (int j = 0; j < 4; ++j) {
          float yv = acc[rt][ct][j];
          float sq = yv*yv;
          sq += __shfl_xor(sq, 1);
          sq += __shfl_xor(sq, 2);
          sq += __shfl_xor(sq, 4);
          sq += __shfl_xor(sq, 8);
          int row = wr*32 + rt*16 + lh*4 + j;
          float s1 = s1v[row*17 + comp];
          float s2 = s2h[row*17 + comp];
          float res = cstk - 0.5f*(s1 - sq - 2.f*s2 + muhk);
          if (lr == 0) out[(size_t)(n0 + row)*KCOMP + kk] = res;
        }
    }
  }
}

// ===========================================================================
extern "C" void kernel_launch(void* const* d_in, const int* in_sizes, int n_in,
                              void* d_out, int out_size, void* d_ws, size_t ws_size,
                              hipStream_t stream) {
  const float* x  = (const float*)d_in[0];
  const float* PI = (const float*)d_in[1];
  const float* MU = (const float*)d_in[2];
  const float* A  = (const float*)d_in[3];
  const float* Dm = (const float*)d_in[4];
  float* out = (float*)d_out;

  if (ws_size >= FULL_NEED) {
    uchar_t* xq   = (uchar_t*)((char*)d_ws + XQ_OFF);
    uchar_t* Bq   = (uchar_t*)((char*)d_ws + BQ_OFF);
    ushort_t* Bsk = (ushort_t*)((char*)d_ws + BSK_OFF);
    float* csk    = (float*)((char*)d_ws + CSK_OFF);

    mfa_pre<<<dim3(KCOMP), dim3(1024), 0, stream>>>(PI, MU, A, Dm, Bq, Bsk, csk);
    mfa_sk5<<<dim3(NPTS/64), dim3(512), 0, stream>>>(x, Bsk, csk, xq, out);
    mfa_gemm11<<<dim3((NPTS/128)*(2048/256)), dim3(512), 0, stream>>>(xq, Bq, out);
  } else {
    ushort_t* Bmat = (ushort_t*)d_ws;
    float* cstp = (float*)((char*)d_ws + FB_CST_OFF);
    float* muhp = (float*)((char*)d_ws + FB_MUH_OFF);
    fb_pre<<<dim3(KCOMP), dim3(256), 0, stream>>>(PI, MU, A, Dm, Bmat, cstp, muhp);
    fb_main<<<dim3(NPTS/FB_BN, FB_NG), dim3(512), 0, stream>>>(x, Bmat, cstp, muhp, out);
  }
}

// Round 15
// 127.887 us; speedup vs baseline: 1.9052x; 1.0129x over previous
//
#include <hip/hip_runtime.h>
#include <math.h>

typedef unsigned short ushort_t;
typedef unsigned char  uchar_t;
typedef __attribute__((ext_vector_type(8))) short short8v;
typedef __attribute__((ext_vector_type(4))) float f32x4;
typedef __attribute__((ext_vector_type(2))) long l64x2;

#define KCOMP 128
#define DF    1024
#define LF    16
#define NPTS  16384
#define LOG2PI 1.8378770664093453f

// ---------------- full-path ws layout (bytes) ----------------
#define XQ_OFF    ((size_t)0)
#define XQ_BYTES  ((size_t)NPTS*DF)              // 16,777,216 fp8 (K-permuted)
#define BQ_OFF    (XQ_OFF + XQ_BYTES)
#define BQ_BYTES  ((size_t)2048*DF)              // 2,097,152 fp8 (K-permuted)
#define BSK_OFF   (BQ_OFF + BQ_BYTES)
#define BSK_BYTES ((size_t)KCOMP*2*DF*2)         // 524,288 bf16
#define CSK_OFF   (BSK_OFF + BSK_BYTES)
#define FULL_NEED (CSK_OFF + 512)

__device__ __forceinline__ ushort_t f2bf(float f) {
  union { float f; unsigned u; } v; v.f = f;
  unsigned u = v.u;
  return (ushort_t)((u + 0x7FFFu + ((u >> 16) & 1u)) >> 16);
}

#define GLOAD16(gp, lp) __builtin_amdgcn_global_load_lds( \
  (const __attribute__((address_space(1))) unsigned int*)(gp), \
  (__attribute__((address_space(3))) unsigned int*)(lp), 16, 0, 0)

// DPP reduce-add within 16-lane rows (VALU only, no LDS)
#define DPPADD(x, ctrl) do { \
  int _yi = __builtin_amdgcn_update_dpp(0, __float_as_int(x), ctrl, 0xF, 0xF, true); \
  (x) += __int_as_float(_yi); } while (0)

// ---------------------------------------------------------------------------
// pre_v3 (R14-verified): 128 blocks x 1024 thr. Stage A/iD/MU to LDS once;
// Gram 4-way + reduce; Cholesky; z; per-d (1/thread): G col-solve, h ->
// Bq fp8 (K-permuted) + Bsk bf16 [-2h ; iD] + csk.
// ---------------------------------------------------------------------------
__global__ __launch_bounds__(1024) void mfa_pre(
    const float* __restrict__ PI, const float* __restrict__ MU,
    const float* __restrict__ A, const float* __restrict__ Dm,
    uchar_t* __restrict__ Bq, ushort_t* __restrict__ Bsk,
    float* __restrict__ csk)
{
  const int k = blockIdx.x, t = threadIdx.x;      // t in [0,1024)
  __shared__ float As[DF*LF];      // 64 KB, As[d*16 + l]
  __shared__ float iDs[DF];        // 4 KB
  __shared__ float MUs[DF];        // 4 KB
  __shared__ float red[1024];      // 4 KB
  __shared__ float bpart[4][16];
  __shared__ float R[16][17];
  __shared__ float rinv_s[16], zsh[16], bsh[16];
  __shared__ float sc_sumlog, sc_c3;

  {
    const float4* Ag = (const float4*)(A + (size_t)k*DF*LF);
    float4* Al = (float4*)As;
    #pragma unroll
    for (int i = 0; i < 4; ++i) Al[t + i*1024] = Ag[t + i*1024];
    float dv = Dm[(size_t)k*DF + t];
    iDs[t] = 1.f/(dv*dv);
    MUs[t] = MU[(size_t)k*DF + t];
  }
  __syncthreads();

  const int e = t & 255, q = t >> 8;
  const int tl = e >> 4, tm = e & 15;
  {
    float acc = 0.f;
    const int d0 = q*256;
    #pragma unroll 4
    for (int dd = 0; dd < 256; ++dd) {
      int d = d0 + dd;
      acc = fmaf(As[d*16+tl]*iDs[d], As[d*16+tm], acc);
    }
    red[t] = acc;
  }
  if (e < 16) {
    float accb = 0.f;
    const int d0 = q*256;
    for (int dd = 0; dd < 256; ++dd) {
      int d = d0 + dd;
      accb = fmaf(iDs[d]*MUs[d], As[d*16+e], accb);
    }
    bpart[q][e] = accb;
  }
  __syncthreads();
  if (q == 0) {
    float s = red[e] + red[e+256] + red[e+512] + red[e+768];
    R[tl][tm] = s + (tl == tm ? 1.f : 0.f);
  }
  if (t < 16) bsh[t] = bpart[0][t] + bpart[1][t] + bpart[2][t] + bpart[3][t];
  __syncthreads();

  red[t] = iDs[t]*MUs[t]*MUs[t];
  __syncthreads();
  if (t < 256) red[t] = red[t] + red[t+256] + red[t+512] + red[t+768];
  __syncthreads();
  if (t < 64) red[t] = red[t] + red[t+64] + red[t+128] + red[t+192];
  __syncthreads();
  if (t == 0) { float s = 0.f; for (int i = 0; i < 64; ++i) s += red[i]; sc_c3 = s; }
  __syncthreads();
  red[t] = logf(iDs[t]);
  __syncthreads();
  if (t < 256) red[t] = red[t] + red[t+256] + red[t+512] + red[t+768];
  __syncthreads();
  if (t < 64) red[t] = red[t] + red[t+64] + red[t+128] + red[t+192];
  __syncthreads();
  if (t == 0) { float s = 0.f; for (int i = 0; i < 64; ++i) s += red[i]; sc_sumlog = s; }

  for (int j = 0; j < 16; ++j) {
    __syncthreads();
    if (t == j) {
      float s = R[j][j];
      for (int i = 0; i < j; ++i) s -= R[j][i]*R[j][i];
      float rj = sqrtf(s);
      R[j][j] = rj; rinv_s[j] = 1.f/rj;
    }
    __syncthreads();
    if (t < 16 && t > j) {
      float s = R[t][j];
      for (int i = 0; i < j; ++i) s -= R[t][i]*R[j][i];
      R[t][j] = s * rinv_s[j];
    }
  }
  __syncthreads();
  if (t == 0) {
    float ldet = 0.f;
    for (int j = 0; j < 16; ++j) ldet += 2.f*logf(R[j][j]);
    float w[16], z[16];
    for (int j = 0; j < 16; ++j) {
      float s = bsh[j];
      for (int i = 0; i < j; ++i) s -= R[j][i]*w[i];
      w[j] = s*rinv_s[j];
    }
    for (int j = 15; j >= 0; --j) {
      float s = w[j];
      for (int i = j+1; i < 16; ++i) s -= R[i][j]*z[i];
      z[j] = s*rinv_s[j];
      zsh[j] = z[j];
    }
    float muh = sc_c3;
    for (int l = 0; l < 16; ++l) muh -= bsh[l]*zsh[l];
    csk[k] = PI[k] - 0.5f*((float)DF*LOG2PI + ldet - sc_sumlog) - 0.5f*muh;
  }
  __syncthreads();

  {
    const int d = t;
    float iD = iDs[d];
    float mu = MUs[d];
    float v[16], gg[16];
    #pragma unroll
    for (int l = 0; l < 16; ++l) v[l] = iD * A[((size_t)k*DF + d)*LF + l];
    #pragma unroll
    for (int j = 0; j < 16; ++j) {
      float s = v[j];
      #pragma unroll
      for (int i = 0; i < 16; ++i) if (i < j) s -= R[j][i]*gg[i];
      gg[j] = s * rinv_s[j];
    }
    float h = iD*mu;
    #pragma unroll
    for (int l = 0; l < 16; ++l) h -= v[l]*zsh[l];
    const int dd = d & 63;
    const size_t poff = (size_t)(d & ~63) + ((dd >> 3) & 3)*16 + (dd >> 5)*8 + (dd & 7);
    #pragma unroll
    for (int l = 0; l < 16; ++l) {
      int r8 = __builtin_amdgcn_cvt_pk_fp8_f32(gg[l], gg[l], 0, false);
      Bq[(size_t)(k*16 + l)*DF + poff] = (uchar_t)(r8 & 0xFF);
    }
    Bsk[(size_t)k*2*DF + d]      = f2bf(-2.f*h);
    Bsk[(size_t)k*2*DF + DF + d] = f2bf(iD);
  }
}

// ---------------------------------------------------------------------------
// sk6: per 32-row block, 512 blocks x 256 thr (4 waves, wave wc = all 32 rows
// x comps [wc*32, wc*32+32)).  2 blocks/CU -> drains overlapped by co-resident
// block. Convert x -> bf16/x^2 LDS + fp8 xq (K-permuted, post-drain store);
// out[n,c] = csk[c] - 0.5*( x.(-2h) + x^2.iD )  (bf16 MFMA).
// Built from sk2q staging + sk5 compute (both verified), rows = 32.
// ---------------------------------------------------------------------------
__global__ __launch_bounds__(256) void mfa_sk6(
    const float* __restrict__ x, const ushort_t* __restrict__ Bsk,
    const float* __restrict__ csk, uchar_t* __restrict__ xq,
    float* __restrict__ out)
{
  __shared__ ushort_t xs[2048];     // [32][64] swizzled (8-elem chunk ^ row&7)
  __shared__ ushort_t x2s[2048];
  __shared__ ushort_t Bs[16384];    // [256 vcols][64] swizzled (0-127 h, 128-255 iD)
  const int t = threadIdx.x, lane = t & 63, wid = t >> 6;
  const int wc = wid;               // comp band (4 waves)
  const int lr = lane & 15, lh = lane >> 4;
  const int n0 = blockIdx.x * 32;
  const int xr = t >> 3, c8 = t & 7;    // 32 rows x 8 chunks of 8 floats

  f32x4 acc[2][2] = {};

  float4 v0, v1;
  {
    const float* xp = x + (size_t)(n0 + xr)*DF + c8*8;
    v0 = ((const float4*)xp)[0]; v1 = ((const float4*)xp)[1];
  }

  for (int tt = 0; tt < 16; ++tt) {
    const int d0 = tt * 64;
    __syncthreads();                    // prev-iter LDS reads retired
    long xq_pack;
    {
      float e[8] = {v0.x,v0.y,v0.z,v0.w, v1.x,v1.y,v1.z,v1.w};
      short8v b, qv;
      #pragma unroll
      for (int i = 0; i < 8; ++i) {
        b[i]  = (short)f2bf(e[i]);
        qv[i] = (short)f2bf(e[i]*e[i]);
      }
      const int ch = c8 ^ (xr & 7);
      *(short8v*)&xs[xr*64 + ch*8]  = b;
      *(short8v*)&x2s[xr*64 + ch*8] = qv;
      int p0 = 0, p1 = 0;
      p0 = __builtin_amdgcn_cvt_pk_fp8_f32(e[0], e[1], p0, false);
      p0 = __builtin_amdgcn_cvt_pk_fp8_f32(e[2], e[3], p0, true);
      p1 = __builtin_amdgcn_cvt_pk_fp8_f32(e[4], e[5], p1, false);
      p1 = __builtin_amdgcn_cvt_pk_fp8_f32(e[6], e[7], p1, true);
      xq_pack = (long)(((unsigned long long)(unsigned)p1 << 32) | (unsigned)p0);
    }
    // ---- stage B tile (32KB): 32 ids, 8 per wave (sk2q pattern) ----
    #pragma unroll
    for (int j = 0; j < 8; ++j) {
      int id = wid*8 + j;
      int vc = id*8 + (lane >> 3);
      int g = (lane & 7) ^ (vc & 7);
      const ushort_t* src = (vc < 128)
        ? Bsk + (size_t)vc*(2*DF) + d0 + g*8
        : Bsk + (size_t)(vc - 128)*(2*DF) + DF + d0 + g*8;
      GLOAD16(src, (char*)Bs + id*1024);
    }
    asm volatile("s_waitcnt vmcnt(0) lgkmcnt(0)" ::: "memory");
    __syncthreads();
    // ---- post-drain: xq store (fire-and-forget) + next-x prefetch ----
    {
      const size_t perm = (size_t)(c8 & 3)*16 + (size_t)(c8 >> 2)*8;
      *(long*)&xq[(size_t)(n0 + xr)*DF + d0 + perm] = xq_pack;
    }
    if (tt < 15) {
      const float* xp = x + (size_t)(n0 + xr)*DF + (d0 + 64) + c8*8;
      v0 = ((const float4*)xp)[0]; v1 = ((const float4*)xp)[1];
    }
    __builtin_amdgcn_sched_barrier(0);
    // ---- compute: wave covers rows 0..32, comps wc*32..+32 ----
    #pragma unroll
    for (int ks = 0; ks < 2; ++ks) {
      const int cterm = ((ks*4 + lh) ^ (lr & 7)) * 8;
      short8v a_[2], a2_[2], bh[2], bi[2];
      #pragma unroll
      for (int rb = 0; rb < 2; ++rb) {
        int row = rb*16 + lr;
        a_[rb]  = *(const short8v*)&xs[row*64 + cterm];
        a2_[rb] = *(const short8v*)&x2s[row*64 + cterm];
      }
      #pragma unroll
      for (int cb = 0; cb < 2; ++cb) {
        int vh = wc*32 + cb*16 + lr;
        bh[cb] = *(const short8v*)&Bs[vh*64 + cterm];
        bi[cb] = *(const short8v*)&Bs[(128 + vh)*64 + cterm];
      }
      #pragma unroll
      for (int cb = 0; cb < 2; ++cb)
        #pragma unroll
        for (int rb = 0; rb < 2; ++rb) {
          acc[rb][cb] = __builtin_amdgcn_mfma_f32_16x16x32_bf16(a_[rb],  bh[cb], acc[rb][cb], 0,0,0);
          acc[rb][cb] = __builtin_amdgcn_mfma_f32_16x16x32_bf16(a2_[rb], bi[cb], acc[rb][cb], 0,0,0);
        }
    }
  }
  // ---- epilogue ----
  #pragma unroll
  for (int cb = 0; cb < 2; ++cb) {
    int comp = wc*32 + cb*16 + lr;
    float ck = csk[comp];
    #pragma unroll
    for (int rb = 0; rb < 2; ++rb)
      #pragma unroll
      for (int j = 0; j < 4; ++j) {
        int row = n0 + rb*16 + lh*4 + j;
        out[(size_t)row*KCOMP + comp] = ck - 0.5f*acc[rb][cb][j];
      }
  }
}

// ---------------------------------------------------------------------------
// gemm11 (R12-verified; only change: %3 slot math -> incremental indices):
// out += 0.5 * sum_l y_l^2 ; y = xq . Bq^T (fp8 e4m3, f32 acc).
// 3-slot LDS rotation, vmcnt(3) gate, 1 barrier/tile, C++ b128 reads
// (K-permuted pair layout), DPP epilogue.
// ---------------------------------------------------------------------------
__global__ __launch_bounds__(512, 4) void mfa_gemm11(
    const uchar_t* __restrict__ xq, const uchar_t* __restrict__ Bq,
    float* __restrict__ out)
{
  __shared__ uchar_t smem[73728];   // 3 slots x 24KB (A 8KB | B 16KB)
  const int t = threadIdx.x, lane = t & 63, wid = t >> 6;  // 8 waves
  const int wm = wid & 1, wn = wid >> 1;
  const int lr = lane & 15, lh = lane >> 4;

  const int bid = blockIdx.x;            // 1024 = 128 rb x 8 cb
  const int xcd = bid & 7, ib = bid >> 3;
  const int rb = xcd*16 + (ib >> 3);     // XCD owns 16 contiguous row-bands
  const int cb = ib & 7;
  const int n0 = rb * 128, c0 = cb * 256;

  f32x4 acc[4][4] = {};

  const int js = (((lane & 3) ^ ((lane >> 3) & 3)) * 16);
  const uchar_t* srcP[3]; int dstO[3];
  #pragma unroll
  for (int q = 0; q < 3; ++q) {
    int id = wid*3 + q;
    if (id < 8) {
      int r = id*16 + (lane >> 2);
      srcP[q] = xq + (size_t)(n0 + r)*DF + js;
      dstO[q] = id*1024;
    } else {
      int cr = (id - 8)*16 + (lane >> 2);
      srcP[q] = Bq + (size_t)(c0 + cr)*DF + js;
      dstO[q] = 8192 + (id - 8)*1024;
    }
  }
  const int rsw = (lh ^ ((lr >> 1) & 3)) * 16;
  const int aO = (wm*64 + lr)*64 + rsw;            // + rt*1024
  const int bO = 8192 + (wn*64 + lr)*64 + rsw;     // + ct*1024

  #define STAGE11(slot, tt_) do { \
    _Pragma("unroll") \
    for (int q = 0; q < 3; ++q) \
      GLOAD16(srcP[q] + (tt_)*64, (char*)smem + (slot)*24576 + dstO[q] + ((lane)*16 & 1023)); \
  } while (0)

  STAGE11(0, 0);
  STAGE11(1, 1);

  int slot_r = 0;    // slot holding tile tt
  int slot_s = 2;    // slot to restage with tile tt+2
  for (int tt = 0; tt < 16; ++tt) {
    if (tt < 15) asm volatile("s_waitcnt vmcnt(3)" ::: "memory");
    else         asm volatile("s_waitcnt vmcnt(0)" ::: "memory");
    __builtin_amdgcn_s_barrier();
    if (tt + 2 <= 15) STAGE11(slot_s, tt + 2);

    const char* lb = (const char*)smem + slot_r * 24576;
    l64x2 a2[4], b2[4];
    #pragma unroll
    for (int rt = 0; rt < 4; ++rt) a2[rt] = *(const l64x2*)(lb + aO + rt*1024);
    #pragma unroll
    for (int ct = 0; ct < 4; ++ct) b2[ct] = *(const l64x2*)(lb + bO + ct*1024);

    __builtin_amdgcn_s_setprio(1);
    #pragma unroll
    for (int ct = 0; ct < 4; ++ct)
      #pragma unroll
      for (int rt = 0; rt < 4; ++rt)
        acc[rt][ct] = __builtin_amdgcn_mfma_f32_16x16x32_fp8_fp8(a2[rt][0], b2[ct][0], acc[rt][ct], 0,0,0);
    #pragma unroll
    for (int ct = 0; ct < 4; ++ct)
      #pragma unroll
      for (int rt = 0; rt < 4; ++rt)
        acc[rt][ct] = __builtin_amdgcn_mfma_f32_16x16x32_fp8_fp8(a2[rt][1], b2[ct][1], acc[rt][ct], 0,0,0);
    __builtin_amdgcn_s_setprio(0);

    slot_r = (slot_r == 2) ? 0 : slot_r + 1;
    slot_s = (slot_s == 2) ? 0 : slot_s + 1;
  }

  #pragma unroll
  for (int ct = 0; ct < 4; ++ct) {
    const int comp = cb*16 + wn*4 + ct;
    #pragma unroll
    for (int rt = 0; rt < 4; ++rt) {
      #pragma unroll
      for (int j = 0; j < 4; ++j) {
        float v = acc[rt][ct][j];
        float sq = v*v;
        DPPADD(sq, 0xB1);
        DPPADD(sq, 0x4E);
        DPPADD(sq, 0x124);
        DPPADD(sq, 0x128);
        if (lr == 0) {
          int row = n0 + wm*64 + rt*16 + lh*4 + j;
          size_t idx = (size_t)row * KCOMP + comp;
          out[idx] = out[idx] + 0.5f*sq;
        }
      }
    }
  }
}

// ===========================================================================
// Fallback path (round-2 kernels, needs ~4.8 MB ws) — used if ws too small
// ===========================================================================
#define FB_NG 8
#define FB_CG 288
#define FB_BN 128
#define FB_DT 32
#define FB_PITCH 40
#define FB_BMAT_ELEMS ((size_t)(FB_NG*FB_CG)*DF)
#define FB_CST_OFF (FB_BMAT_ELEMS*2)
#define FB_MUH_OFF (FB_CST_OFF + 512)

__global__ __launch_bounds__(256) void fb_pre(
    const float* __restrict__ PI, const float* __restrict__ MU,
    const float* __restrict__ A, const float* __restrict__ Dm,
    ushort_t* __restrict__ Bmat, float* __restrict__ cst, float* __restrict__ muh)
{
  const int k = blockIdx.x, t = threadIdx.x;
  const int tl = t >> 4, tm = t & 15;
  __shared__ float As[16][16], iDsh[16], MUsh[16];
  __shared__ float R[16][17], rinv[16], zsh[16], bsh[16];
  __shared__ float red[256];

  float accL = 0.f, accb = 0.f, slog = 0.f;
  for (int d0 = 0; d0 < DF; d0 += 16) {
    __syncthreads();
    As[tl][tm] = A[((size_t)k*DF + d0 + tl)*LF + tm];
    if (t < 16) {
      float dv = Dm[k*DF + d0 + t];
      iDsh[t] = 1.f/(dv*dv);
      MUsh[t] = MU[k*DF + d0 + t];
    }
    __syncthreads();
    #pragma unroll
    for (int dd = 0; dd < 16; ++dd)
      accL = fmaf(As[dd][tl]*iDsh[dd], As[dd][tm], accL);
    if (tm == 0) {
      #pragma unroll
      for (int dd = 0; dd < 16; ++dd)
        accb = fmaf(iDsh[dd]*MUsh[dd], As[dd][tl], accb);
    }
    if (t < 16) slog += logf(iDsh[t]);
  }
  __syncthreads();
  R[tl][tm] = accL + (tl == tm ? 1.f : 0.f);
  if (tm == 0) bsh[tl] = accb;
  red[t] = (t < 16) ? slog : 0.f;
  __syncthreads();
  float sumlogiD = 0.f;
  if (t == 0) { for (int i = 0; i < 16; ++i) sumlogiD += red[i]; }

  for (int j = 0; j < 16; ++j) {
    if (t == j) {
      float s = R[j][j];
      for (int i = 0; i < j; ++i) s -= R[j][i]*R[j][i];
      float rj = sqrtf(s);
      R[j][j] = rj; rinv[j] = 1.f/rj;
    }
    __syncthreads();
    if (t < 16 && t > j) {
      float s = R[t][j];
      for (int i = 0; i < j; ++i) s -= R[t][i]*R[j][i];
      R[t][j] = s * rinv[j];
    }
    __syncthreads();
  }

  float ldet = 0.f;
  if (t == 0) {
    #pragma unroll
    for (int j = 0; j < 16; ++j) ldet += 2.f*logf(R[j][j]);
    float w[16], z[16];
    #pragma unroll
    for (int j = 0; j < 16; ++j) {
      float s = bsh[j];
      #pragma unroll
      for (int i = 0; i < 16; ++i) if (i < j) s -= R[j][i]*w[i];
      w[j] = s*rinv[j];
    }
    #pragma unroll
    for (int j = 15; j >= 0; --j) {
      float s = w[j];
      #pragma unroll
      for (int i = 0; i < 16; ++i) if (i > j) s -= R[i][j]*z[i];
      z[j] = s*rinv[j];
      zsh[j] = z[j];
    }
  }
  __syncthreads();

  const int g = k >> 4, kl = k & 15;
  ushort_t* Bgp = Bmat + (size_t)g*FB_CG*DF;
  float muhp = 0.f;
  for (int itr = 0; itr < 4; ++itr) {
    int d = t + itr*256;
    float dv = Dm[k*DF + d];
    float iD = 1.f/(dv*dv);
    float mu = MU[k*DF + d];
    float v[16], gg[16];
    #pragma unroll
    for (int l = 0; l < 16; ++l) v[l] = iD * A[((size_t)k*DF + d)*LF + l];
    #pragma unroll
    for (int j = 0; j < 16; ++j) {
      float s = v[j];
      #pragma unroll
      for (int i = 0; i < 16; ++i) if (i < j) s -= R[j][i]*gg[i];
      gg[j] = s * rinv[j];
    }
    float h = iD*mu;
    #pragma unroll
    for (int l = 0; l < 16; ++l) h -= v[l]*zsh[l];
    muhp = fmaf(mu, h, muhp);
    #pragma unroll
    for (int l = 0; l < 16; ++l)
      Bgp[(size_t)(kl*16 + l)*DF + d] = f2bf(gg[l]);
    Bgp[(size_t)(256 + kl)*DF + d] = f2bf(h);
    Bgp[(size_t)(272 + kl)*DF + d] = f2bf(iD);
  }
  red[t] = muhp;
  __syncthreads();
  for (int s = 128; s > 0; s >>= 1) {
    if (t < s) red[t] += red[t + s];
    __syncthreads();
  }
  if (t == 0) {
    muh[k] = red[0];
    cst[k] = PI[k] - 0.5f*((float)DF*LOG2PI + ldet - sumlogiD);
  }
}

__global__ __launch_bounds__(512, 2) void fb_main(
    const float* __restrict__ x, const ushort_t* __restrict__ Bmat,
    const float* __restrict__ cst, const float* __restrict__ muh,
    float* __restrict__ out)
{
  __shared__ __align__(16) ushort_t smem[2*FB_BN*FB_PITCH + FB_CG*FB_PITCH];
  ushort_t* xs  = smem;
  ushort_t* x2s = smem + FB_BN*FB_PITCH;
  ushort_t* Bs  = smem + 2*FB_BN*FB_PITCH;

  const int t = threadIdx.x;
  const int lane = t & 63, wid = t >> 6;
  const int wr = wid & 3, wc = wid >> 2;
  const int lr = lane & 15, lh = lane >> 4;
  const int n0 = blockIdx.x * FB_BN;
  const int g  = blockIdx.y;

  f32x4 acc[2][9] = {};
  const int srow = t >> 2, sc = t & 3;

  int xoff[2];
  #pragma unroll
  for (int rt = 0; rt < 2; ++rt)
    xoff[rt] = (wr*32 + rt*16 + lr)*FB_PITCH + lh*8;
  int boff[9];
  #pragma unroll
  for (int ct = 0; ct < 9; ++ct)
    boff[ct] = (wc*144 + ct*16 + lr)*FB_PITCH + lh*8;

  for (int d0 = 0; d0 < DF; d0 += FB_DT) {
    __syncthreads();
    {
      const float* xp = x + (size_t)(n0 + srow)*DF + d0 + sc*8;
      float4 v0 = *(const float4*)xp;
      float4 v1 = *(const float4*)(xp + 4);
      float e[8] = {v0.x,v0.y,v0.z,v0.w,v1.x,v1.y,v1.z,v1.w};
      short8v xv, qv;
      #pragma unroll
      for (int i = 0; i < 8; ++i) {
        xv[i] = (short)f2bf(e[i]);
        qv[i] = (short)f2bf(e[i]*e[i]);
      }
      *(short8v*)&xs[srow*FB_PITCH + sc*8]  = xv;
      *(short8v*)&x2s[srow*FB_PITCH + sc*8] = qv;
    }
    for (int u = t; u < FB_CG*4; u += 512) {
      int col = u >> 2, c = u & 3;
      *(short8v*)&Bs[col*FB_PITCH + c*8] =
        *(const short8v*)&Bmat[((size_t)(g*FB_CG + col))*DF + d0 + c*8];
    }
    __syncthreads();

    short8v xf[2];
    #pragma unroll
    for (int rt = 0; rt < 2; ++rt) xf[rt] = *(short8v*)&xs[xoff[rt]];
    #pragma unroll
    for (int ct = 0; ct < 8; ++ct) {
      short8v bfr = *(short8v*)&Bs[boff[ct]];
      #pragma unroll
      for (int rt = 0; rt < 2; ++rt)
        acc[rt][ct] = __builtin_amdgcn_mfma_f32_16x16x32_bf16(xf[rt], bfr, acc[rt][ct], 0, 0, 0);
    }
    {
      short8v bfr = *(short8v*)&Bs[boff[8]];
      short8v a0 = xf[0], a1 = xf[1];
      if (wc) {
        a0 = *(short8v*)&x2s[xoff[0]];
        a1 = *(short8v*)&x2s[xoff[1]];
      }
      acc[0][8] = __builtin_amdgcn_mfma_f32_16x16x32_bf16(a0, bfr, acc[0][8], 0, 0, 0);
      acc[1][8] = __builtin_amdgcn_mfma_f32_16x16x32_bf16(a1, bfr, acc[1][8], 0, 0, 0);
    }
  }

  __syncthreads();
  float* s1v = (float*)smem;
  float* s2h = s1v + FB_BN*17;
  if (wc == 1) {
    #pragma unroll
    for (int rt = 0; rt < 2; ++rt)
      #pragma unroll
      for (int j = 0; j < 4; ++j) {
        int row = wr*32 + rt*16 + lh*4 + j;
        s2h[row*17 + lr] = acc[rt][7][j];
        s1v[row*17 + lr] = acc[rt][8][j];
      }
  }
  __syncthreads();

  const int nyt = wc ? 7 : 9;
  #pragma unroll
  for (int ct = 0; ct < 9; ++ct) {
    if (ct < nyt) {
      int comp = wc*9 + ct;
      int kk = g*16 + comp;
      float cstk = cst[kk], muhk = muh[kk];
      #pragma unroll
      for (int rt = 0; rt < 2; ++rt)
        #pragma unroll
        for (int j = 0; j < 4; ++j) {
          float yv = acc[rt][ct][j];
          float sq = yv*yv;
          sq += __shfl_xor(sq, 1);
          sq += __shfl_xor(sq, 2);
          sq += __shfl_xor(sq, 4);
          sq += __shfl_xor(sq, 8);
          int row = wr*32 + rt*16 + lh*4 + j;
          float s1 = s1v[row*17 + comp];
          float s2 = s2h[row*17 + comp];
          float res = cstk - 0.5f*(s1 - sq - 2.f*s2 + muhk);
          if (lr == 0) out[(size_t)(n0 + row)*KCOMP + kk] = res;
        }
    }
  }
}

// ===========================================================================
extern "C" void kernel_launch(void* const* d_in, const int* in_sizes, int n_in,
                              void* d_out, int out_size, void* d_ws, size_t ws_size,
                              hipStream_t stream) {
  const float* x  = (const float*)d_in[0];
  const float* PI = (const float*)d_in[1];
  const float* MU = (const float*)d_in[2];
  const float* A  = (const float*)d_in[3];
  const float* Dm = (const float*)d_in[4];
  float* out = (float*)d_out;

  if (ws_size >= FULL_NEED) {
    uchar_t* xq   = (uchar_t*)((char*)d_ws + XQ_OFF);
    uchar_t* Bq   = (uchar_t*)((char*)d_ws + BQ_OFF);
    ushort_t* Bsk = (ushort_t*)((char*)d_ws + BSK_OFF);
    float* csk    = (float*)((char*)d_ws + CSK_OFF);

    mfa_pre<<<dim3(KCOMP), dim3(1024), 0, stream>>>(PI, MU, A, Dm, Bq, Bsk, csk);
    mfa_sk6<<<dim3(NPTS/32), dim3(256), 0, stream>>>(x, Bsk, csk, xq, out);
    mfa_gemm11<<<dim3((NPTS/128)*(2048/256)), dim3(512), 0, stream>>>(xq, Bq, out);
  } else {
    ushort_t* Bmat = (ushort_t*)d_ws;
    float* cstp = (float*)((char*)d_ws + FB_CST_OFF);
    float* muhp = (float*)((char*)d_ws + FB_MUH_OFF);
    fb_pre<<<dim3(KCOMP), dim3(256), 0, stream>>>(PI, MU, A, Dm, Bmat, cstp, muhp);
    fb_main<<<dim3(NPTS/FB_BN, FB_NG), dim3(512), 0, stream>>>(x, Bmat, cstp, muhp, out);
  }
}